// Round 4
// baseline (912.596 us; speedup 1.0000x reference)
//
#include <hip/hip_runtime.h>

// ======================================================================
// VQ-VAE forward, all-MFMA. B=32, CIN=3, IMG=128, D=256, K=512.
// NHWC bf16 activations. M=64 px per block for all 256-ch convs (halves
// L2 B-fragment traffic vs M=32). LDS row stride 132/264 shorts (16B
// aligned, <=2-way bank aliasing = free). Weights frag-ordered
// Wf[khkw][cch][n][32]. MFMA 16x16x32 bf16: A[m=lane&15][k=quad*8+j],
// B[n][k], D col=lane&15, row=quad*4+reg (HW-verified mappings).
// R3: mdeconv1 = 4 same-parity oy rows (2x B-frag reuse, 32 MFMA per
// 12-load batch) with BOTH ox parities per block (par loop inside).
// R2's single-parity blocks caused 4.9x write amplification (328 MB vs
// 67 ideal) -> HBM-write-bound at 3.6 TB/s. Dense per-block writes
// (R1 pattern, 1.7x) + halved grid (512 = 2 blocks/CU).
// ======================================================================

typedef __attribute__((ext_vector_type(8))) short bf16x8;
typedef __attribute__((ext_vector_type(4))) float f32x4;
#define MFMA_B16(a, b, c) __builtin_amdgcn_mfma_f32_16x16x32_bf16(a, b, c, 0, 0, 0)

__device__ inline unsigned short f2b(float f) {
    unsigned int u = __float_as_uint(f);
    unsigned int r = u + 0x7fffu + ((u >> 16) & 1u);
    return (unsigned short)(r >> 16);
}
__device__ inline float b2f(unsigned short u) {
    return __uint_as_float(((unsigned int)u) << 16);
}

// ======================================================================
// batched bf16 frag-order weight permute for the 10 conv/deconv weights.
// dst[(((kh*KW+kw)*8 + cch)*256 + n)*32 + q] = bf16(src[n*so + (cch*32+q)*si + kh*sh + kw*sw])
// ======================================================================
struct PermfArgs {
    const float* src[10];
    int kw[10];
    int so[10], si[10], sh[10], sw[10];
    int cum[11];
};

__global__ void permf_all_k(PermfArgs a, unsigned short* __restrict__ dst)
{
    int gid = blockIdx.x * 256 + threadIdx.x;
    if (gid >= a.cum[10]) return;
    int seg = 0;
    while (seg < 9 && gid >= a.cum[seg + 1]) ++seg;
    int l = gid - a.cum[seg];
    int q = l & 31;
    int n = (l >> 5) & 255;
    int rest = l >> 13;
    int cch = rest & 7;
    int khkw = rest >> 3;
    int kh = khkw / a.kw[seg], kw = khkw % a.kw[seg];
    int ci = cch * 32 + q;
    dst[gid] = f2b(a.src[seg][n * a.so[seg] + ci * a.si[seg] + kh * a.sh[seg] + kw * a.sw[seg]]);
}

// ======================================================================
// misc prep: deconv2 frag weights, codebook frag, conv1 frag weights,
// codebook norms, loss-acc zero. 753 blocks x 256.
// ======================================================================
__global__ void misc_prep_k(const float* __restrict__ dt2_w, unsigned short* __restrict__ wg,
                            const float* __restrict__ embed, unsigned short* __restrict__ embF,
                            const float* __restrict__ e_w1, unsigned short* __restrict__ wgc,
                            float* __restrict__ nrm, float* __restrict__ lacc)
{
    int blk = blockIdx.x, tid = threadIdx.x;
    if (blk < 48) {                       // deconv2 weights, N=48: n=(kh*4+kw)*3+oc
        int idx = blk * 256 + tid;        // < 12288
        int q = idx & 31;
        int n = (idx >> 5) % 48;
        int cch = idx / (48 * 32);
        int ci = cch * 32 + q;
        int oc = n % 3, khkw = n / 3;
        int kh = khkw >> 2, kw = khkw & 3;
        wg[idx] = f2b(dt2_w[ci * 48 + oc * 16 + kh * 4 + kw]);
    } else if (blk < 560) {               // codebook frag: dst[(cch*512+n)*32+q]
        int idx = (blk - 48) * 256 + tid; // < 131072
        int q = idx & 31;
        int n = (idx >> 5) & 511;
        int cch = idx >> 14;
        embF[idx] = f2b(embed[n * 256 + cch * 32 + q]);
    } else if (blk < 624) {               // conv1 im2col weights, K=48 pad 64
        int idx = (blk - 560) * 256 + tid;  // < 16384
        int q = idx & 31;
        int n = (idx >> 5) & 255;
        int kt = idx >> 13;
        int k = kt * 32 + q;
        float v = 0.f;
        if (k < 48) {
            int ci = k >> 4, kh = (k >> 2) & 3, kwv = k & 3;
            v = e_w1[n * 48 + ci * 16 + kh * 4 + kwv];
        }
        wgc[idx] = f2b(v);
    } else if (blk < 752) {               // codebook row norms, 4 rows/block
        int row = (blk - 624) * 4 + (tid >> 6);
        int lane = tid & 63;
        float s = 0.f;
        #pragma unroll
        for (int c = 0; c < 256; c += 64) {
            float v = embed[row * 256 + c + lane];
            s += v * v;
        }
        #pragma unroll
        for (int off = 1; off < 64; off <<= 1) s += __shfl_xor(s, off);
        if (lane == 0) nrm[row] = s;
    } else {
        if (tid == 0) lacc[0] = 0.f;
    }
}

__global__ void lossfin_k(const float* __restrict__ lacc, float* __restrict__ out)
{
    if (threadIdx.x == 0) {
        float m = lacc[0] * (1.0f / 32768.0f);
        out[1572864] = m;
        out[1572865] = m;
    }
}

// ======================================================================
// conv1m: MFMA im2col conv1. x NCHW fp32 -> NHWC bf16 (B,64,64,256),
// k4 s2 p1, ReLU. grid = B*64 (one output row, 64 px). K=48 pad 64.
// ======================================================================
__global__ void __launch_bounds__(256, 4)
conv1m_k(const float* __restrict__ x, const unsigned short* __restrict__ wgc,
         unsigned short* __restrict__ out)
{
    int bh = blockIdx.x;             // b*64 + oh
    int b = bh >> 6, oh = bh & 63;
    int tid = threadIdx.x;
    int lane = tid & 63, wv = tid >> 6;
    int m = lane & 15, quad = lane >> 4;
    __shared__ float xrow[3][4][130];
    __shared__ __align__(16) unsigned short imc[64 * 72];   // stride 72 (144B, 16B-aligned)
    for (int s = tid; s < 1560; s += 256) {
        int col = s % 130;
        int t = s / 130;
        int r = t & 3;
        int c = t >> 2;
        int ih = 2 * oh - 1 + r, iw = col - 1;
        float v = 0.f;
        if ((unsigned)ih < 128u && (unsigned)iw < 128u)
            v = x[(((b * 3 + c) << 7) + ih) * 128 + iw];
        xrow[c][r][col] = v;
    }
    __syncthreads();
    for (int s = tid; s < 4096; s += 256) {
        int px = s >> 6, k = s & 63;
        float v = 0.f;
        if (k < 48) {
            int ci = k >> 4, kh = (k >> 2) & 3, kw = k & 3;
            v = xrow[ci][kh][2 * px + kw];
        }
        imc[px * 72 + k] = f2b(v);
    }
    __syncthreads();
    f32x4 acc[16];
    f32x4 z = {0.f, 0.f, 0.f, 0.f};
    #pragma unroll
    for (int i = 0; i < 16; ++i) acc[i] = z;
    bf16x8 a0 = *(const bf16x8*)&imc[((wv << 4) + m) * 72 + (quad << 3)];
    bf16x8 a1 = *(const bf16x8*)&imc[((wv << 4) + m) * 72 + 32 + (quad << 3)];
    #pragma unroll
    for (int nt = 0; nt < 16; ++nt) {
        bf16x8 b0 = *(const bf16x8*)&wgc[(nt * 16 + m) * 32 + (quad << 3)];
        bf16x8 b1 = *(const bf16x8*)&wgc[(256 + nt * 16 + m) * 32 + (quad << 3)];
        acc[nt] = MFMA_B16(a0, b0, acc[nt]);
        acc[nt] = MFMA_B16(a1, b1, acc[nt]);
    }
    #pragma unroll
    for (int nt = 0; nt < 16; ++nt)
        #pragma unroll
        for (int r = 0; r < 4; ++r) {
            int px = (wv << 4) + quad * 4 + r;
            out[(((bh << 6) + px) << 8) + nt * 16 + (lane & 15)] = f2b(fmaxf(acc[nt][r], 0.f));
        }
}

// ======================================================================
// mconv2: k4 s2 p1, (B,64,64,256)->(B,32,32,256), ReLU. M=64 (2 out rows).
// grid = B*16. Channel-split staging (128 ch/phase), parity-split cols.
// ======================================================================
__global__ void __launch_bounds__(256, 3)
mconv2_k(const unsigned short* __restrict__ in, const unsigned short* __restrict__ wf,
         unsigned short* __restrict__ out)
{
    int blk = blockIdx.x;
    int bb = blk >> 4, j = blk & 15;      // out rows 2j, 2j+1
    int lane = threadIdx.x & 63;
    int n0 = (threadIdx.x >> 6) << 6;
    int m = lane & 15, quad = lane >> 4;
    __shared__ __align__(16) unsigned short win[2 * 66 * 132];  // 34.8 KB
    f32x4 acc[2][2][4];
    f32x4 z = {0.f, 0.f, 0.f, 0.f};
    #pragma unroll
    for (int a = 0; a < 2; ++a)
        #pragma unroll
        for (int i = 0; i < 2; ++i)
            #pragma unroll
            for (int t = 0; t < 4; ++t) acc[a][i][t] = z;

    for (int c0 = 0; c0 < 256; c0 += 128) {
        for (int kh = 0; kh < 4; ++kh) {
            __syncthreads();
            for (int s = threadIdx.x; s < 2 * 66 * 16; s += 256) {
                int c16 = s & 15;
                int t2 = s >> 4;
                int col = t2 % 66;
                int rr = t2 / 66;
                int ih = 4 * j - 1 + kh + 2 * rr, iw = col - 1;
                int4 v = make_int4(0, 0, 0, 0);
                if ((unsigned)ih < 64u && (unsigned)iw < 64u)
                    v = *(const int4*)&in[((((bb << 6) + ih) << 6) + iw) * 256 + c0 + (c16 << 3)];
                int cs = (col >> 1) + (col & 1) * 33;
                *(int4*)&win[(rr * 66 + cs) * 132 + (c16 << 3)] = v;
            }
            __syncthreads();
            #pragma unroll
            for (int kw = 0; kw < 4; ++kw) {
                int csoff = (kw >> 1) + (kw & 1) * 33;
                #pragma unroll
                for (int cch = 0; cch < 4; ++cch) {
                    bf16x8 a00 = *(const bf16x8*)&win[(m + csoff) * 132 + (cch << 5) + (quad << 3)];
                    bf16x8 a01 = *(const bf16x8*)&win[(m + 16 + csoff) * 132 + (cch << 5) + (quad << 3)];
                    bf16x8 a10 = *(const bf16x8*)&win[(66 + m + csoff) * 132 + (cch << 5) + (quad << 3)];
                    bf16x8 a11 = *(const bf16x8*)&win[(66 + m + 16 + csoff) * 132 + (cch << 5) + (quad << 3)];
                    int cg = (c0 >> 5) + cch;
                    int wbase = ((((kh << 2) + kw) * 8 + cg) * 256 + n0 + m) * 32 + (quad << 3);
                    bf16x8 b0 = *(const bf16x8*)&wf[wbase];
                    bf16x8 b1 = *(const bf16x8*)&wf[wbase + 16 * 32];
                    bf16x8 b2 = *(const bf16x8*)&wf[wbase + 32 * 32];
                    bf16x8 b3 = *(const bf16x8*)&wf[wbase + 48 * 32];
                    acc[0][0][0] = MFMA_B16(a00, b0, acc[0][0][0]);
                    acc[0][0][1] = MFMA_B16(a00, b1, acc[0][0][1]);
                    acc[0][0][2] = MFMA_B16(a00, b2, acc[0][0][2]);
                    acc[0][0][3] = MFMA_B16(a00, b3, acc[0][0][3]);
                    acc[0][1][0] = MFMA_B16(a01, b0, acc[0][1][0]);
                    acc[0][1][1] = MFMA_B16(a01, b1, acc[0][1][1]);
                    acc[0][1][2] = MFMA_B16(a01, b2, acc[0][1][2]);
                    acc[0][1][3] = MFMA_B16(a01, b3, acc[0][1][3]);
                    acc[1][0][0] = MFMA_B16(a10, b0, acc[1][0][0]);
                    acc[1][0][1] = MFMA_B16(a10, b1, acc[1][0][1]);
                    acc[1][0][2] = MFMA_B16(a10, b2, acc[1][0][2]);
                    acc[1][0][3] = MFMA_B16(a10, b3, acc[1][0][3]);
                    acc[1][1][0] = MFMA_B16(a11, b0, acc[1][1][0]);
                    acc[1][1][1] = MFMA_B16(a11, b1, acc[1][1][1]);
                    acc[1][1][2] = MFMA_B16(a11, b2, acc[1][1][2]);
                    acc[1][1][3] = MFMA_B16(a11, b3, acc[1][1][3]);
                }
            }
        }
    }
    #pragma unroll
    for (int row = 0; row < 2; ++row) {
        int oh = 2 * j + row;
        #pragma unroll
        for (int mt = 0; mt < 2; ++mt)
            #pragma unroll
            for (int nt = 0; nt < 4; ++nt)
                #pragma unroll
                for (int r = 0; r < 4; ++r) {
                    int px = mt * 16 + quad * 4 + r;
                    int col = n0 + nt * 16 + m;
                    out[((((bb << 5) + oh) << 5) + px) * 256 + col] = f2b(fmaxf(acc[row][mt][nt][r], 0.f));
                }
    }
}

// ======================================================================
// mconv3: 3x3 s1 p1 + ReLU, (B,32,32,256)->(B,32,32,256). M=64. grid B*16.
// Channel-split staging: 4 input rows x 34 cols x 128 ch per phase.
// ======================================================================
__global__ void __launch_bounds__(256, 3)
mconv3_k(const unsigned short* __restrict__ in, const unsigned short* __restrict__ wf,
         unsigned short* __restrict__ out)
{
    int blk = blockIdx.x;
    int bb = blk >> 4, j = blk & 15;      // out rows 2j, 2j+1
    int lane = threadIdx.x & 63;
    int n0 = (threadIdx.x >> 6) << 6;
    int m = lane & 15, quad = lane >> 4;
    __shared__ __align__(16) unsigned short win[4 * 34 * 132];  // 35.9 KB
    f32x4 acc[2][2][4];
    f32x4 z = {0.f, 0.f, 0.f, 0.f};
    #pragma unroll
    for (int a = 0; a < 2; ++a)
        #pragma unroll
        for (int i = 0; i < 2; ++i)
            #pragma unroll
            for (int t = 0; t < 4; ++t) acc[a][i][t] = z;

    for (int c0 = 0; c0 < 256; c0 += 128) {
        __syncthreads();
        for (int s = threadIdx.x; s < 4 * 34 * 16; s += 256) {
            int c16 = s & 15;
            int t2 = s >> 4;
            int col = t2 % 34;
            int rr = t2 / 34;
            int ih = 2 * j - 1 + rr, iw = col - 1;
            int4 v = make_int4(0, 0, 0, 0);
            if ((unsigned)ih < 32u && (unsigned)iw < 32u)
                v = *(const int4*)&in[((((bb << 5) + ih) << 5) + iw) * 256 + c0 + (c16 << 3)];
            *(int4*)&win[(rr * 34 + col) * 132 + (c16 << 3)] = v;
        }
        __syncthreads();
        for (int kh = 0; kh < 3; ++kh) {
            #pragma unroll
            for (int kw = 0; kw < 3; ++kw) {
                #pragma unroll
                for (int cch = 0; cch < 4; ++cch) {
                    const unsigned short* ba = &win[(kh * 34 + m + kw) * 132 + (cch << 5) + (quad << 3)];
                    bf16x8 a00 = *(const bf16x8*)ba;
                    bf16x8 a01 = *(const bf16x8*)(ba + 16 * 132);
                    bf16x8 a10 = *(const bf16x8*)(ba + 34 * 132);
                    bf16x8 a11 = *(const bf16x8*)(ba + 50 * 132);
                    int cg = (c0 >> 5) + cch;
                    int wbase = (((kh * 3 + kw) * 8 + cg) * 256 + n0 + m) * 32 + (quad << 3);
                    bf16x8 b0 = *(const bf16x8*)&wf[wbase];
                    bf16x8 b1 = *(const bf16x8*)&wf[wbase + 16 * 32];
                    bf16x8 b2 = *(const bf16x8*)&wf[wbase + 32 * 32];
                    bf16x8 b3 = *(const bf16x8*)&wf[wbase + 48 * 32];
                    acc[0][0][0] = MFMA_B16(a00, b0, acc[0][0][0]);
                    acc[0][0][1] = MFMA_B16(a00, b1, acc[0][0][1]);
                    acc[0][0][2] = MFMA_B16(a00, b2, acc[0][0][2]);
                    acc[0][0][3] = MFMA_B16(a00, b3, acc[0][0][3]);
                    acc[0][1][0] = MFMA_B16(a01, b0, acc[0][1][0]);
                    acc[0][1][1] = MFMA_B16(a01, b1, acc[0][1][1]);
                    acc[0][1][2] = MFMA_B16(a01, b2, acc[0][1][2]);
                    acc[0][1][3] = MFMA_B16(a01, b3, acc[0][1][3]);
                    acc[1][0][0] = MFMA_B16(a10, b0, acc[1][0][0]);
                    acc[1][0][1] = MFMA_B16(a10, b1, acc[1][0][1]);
                    acc[1][0][2] = MFMA_B16(a10, b2, acc[1][0][2]);
                    acc[1][0][3] = MFMA_B16(a10, b3, acc[1][0][3]);
                    acc[1][1][0] = MFMA_B16(a11, b0, acc[1][1][0]);
                    acc[1][1][1] = MFMA_B16(a11, b1, acc[1][1][1]);
                    acc[1][1][2] = MFMA_B16(a11, b2, acc[1][1][2]);
                    acc[1][1][3] = MFMA_B16(a11, b3, acc[1][1][3]);
                }
            }
        }
    }
    #pragma unroll
    for (int row = 0; row < 2; ++row) {
        int oh = 2 * j + row;
        #pragma unroll
        for (int mt = 0; mt < 2; ++mt)
            #pragma unroll
            for (int nt = 0; nt < 4; ++nt)
                #pragma unroll
                for (int r = 0; r < 4; ++r) {
                    int px = mt * 16 + quad * 4 + r;
                    int col = n0 + nt * 16 + m;
                    out[((((bb << 5) + oh) << 5) + px) * 256 + col] = f2b(fmaxf(acc[row][mt][nt][r], 0.f));
                }
    }
}

// ======================================================================
// m1x1: 1x1 + residual. M=64. grid = B*16 (=512). Dual bf16/fp32 output.
// ======================================================================
__global__ void __launch_bounds__(256, 3)
m1x1_k(const unsigned short* __restrict__ in, const unsigned short* __restrict__ wf,
       const unsigned short* __restrict__ res, unsigned short* __restrict__ outb,
       float* __restrict__ outf, int f32out)
{
    int blk = blockIdx.x;
    int lane = threadIdx.x & 63;
    int n0 = (threadIdx.x >> 6) << 6;
    int m = lane & 15, quad = lane >> 4;
    __shared__ __align__(16) unsigned short win[64 * 264];   // 33.8 KB
    f32x4 acc[4][4];
    f32x4 z = {0.f, 0.f, 0.f, 0.f};
    #pragma unroll
    for (int i = 0; i < 4; ++i)
        #pragma unroll
        for (int t = 0; t < 4; ++t) acc[i][t] = z;

    int rowbase = blk << 14;   // 64 px * 256
    for (int s = threadIdx.x; s < 64 * 32; s += 256) {
        int c8 = s & 31, col = s >> 5;
        *(int4*)&win[col * 264 + (c8 << 3)] = *(const int4*)&in[rowbase + (col << 8) + (c8 << 3)];
    }
    __syncthreads();
    #pragma unroll
    for (int cch = 0; cch < 8; ++cch) {
        bf16x8 a0 = *(const bf16x8*)&win[m * 264 + (cch << 5) + (quad << 3)];
        bf16x8 a1 = *(const bf16x8*)&win[(m + 16) * 264 + (cch << 5) + (quad << 3)];
        bf16x8 a2 = *(const bf16x8*)&win[(m + 32) * 264 + (cch << 5) + (quad << 3)];
        bf16x8 a3 = *(const bf16x8*)&win[(m + 48) * 264 + (cch << 5) + (quad << 3)];
        int wbase = (cch * 256 + n0 + m) * 32 + (quad << 3);
        bf16x8 b0 = *(const bf16x8*)&wf[wbase];
        bf16x8 b1 = *(const bf16x8*)&wf[wbase + 16 * 32];
        bf16x8 b2 = *(const bf16x8*)&wf[wbase + 32 * 32];
        bf16x8 b3 = *(const bf16x8*)&wf[wbase + 48 * 32];
        acc[0][0] = MFMA_B16(a0, b0, acc[0][0]);
        acc[0][1] = MFMA_B16(a0, b1, acc[0][1]);
        acc[0][2] = MFMA_B16(a0, b2, acc[0][2]);
        acc[0][3] = MFMA_B16(a0, b3, acc[0][3]);
        acc[1][0] = MFMA_B16(a1, b0, acc[1][0]);
        acc[1][1] = MFMA_B16(a1, b1, acc[1][1]);
        acc[1][2] = MFMA_B16(a1, b2, acc[1][2]);
        acc[1][3] = MFMA_B16(a1, b3, acc[1][3]);
        acc[2][0] = MFMA_B16(a2, b0, acc[2][0]);
        acc[2][1] = MFMA_B16(a2, b1, acc[2][1]);
        acc[2][2] = MFMA_B16(a2, b2, acc[2][2]);
        acc[2][3] = MFMA_B16(a2, b3, acc[2][3]);
        acc[3][0] = MFMA_B16(a3, b0, acc[3][0]);
        acc[3][1] = MFMA_B16(a3, b1, acc[3][1]);
        acc[3][2] = MFMA_B16(a3, b2, acc[3][2]);
        acc[3][3] = MFMA_B16(a3, b3, acc[3][3]);
    }
    #pragma unroll
    for (int mt = 0; mt < 4; ++mt)
        #pragma unroll
        for (int nt = 0; nt < 4; ++nt)
            #pragma unroll
            for (int r = 0; r < 4; ++r) {
                int px = mt * 16 + quad * 4 + r;
                int col = n0 + nt * 16 + m;
                int idx = rowbase + (px << 8) + col;
                float v = acc[mt][nt][r] + b2f(res[idx]);
                outb[idx] = f2b(v);
                if (f32out) outf[idx] = v;
            }
}

// ======================================================================
// mdeconv1: ConvTranspose2d(256->256,k4,s2,p1)+bias+ReLU.
// R3: 4 same-parity oy rows (oy_a,+2,+4,+6) AND both ox parities per
// block (par loop inside -> dense row writes, R1's 1.7x write behavior).
// 5 input rows staged per (par,c0) phase; 2nd par re-stage is L2-warm.
// Per (t,u,cch): 8 A x 4 B = 32 MFMA. grid = B*2pp*8 = 512 (2 blk/CU).
// ======================================================================
__global__ void __launch_bounds__(256, 2)
mdeconv1_k(const unsigned short* __restrict__ in, const unsigned short* __restrict__ wf,
           const float* __restrict__ bias, unsigned short* __restrict__ out)
{
    int blk = blockIdx.x;
    int bb  = blk >> 4;
    int rem = blk & 15;
    int pp  = rem >> 3;                 // oy parity
    int i   = rem & 7;
    int oy_a = pp + 8 * i;              // rows oy_a, +2, +4, +6
    int p = (oy_a + 1) & 1;             // kh parity (shared by all 4 rows)
    int r0a = (oy_a + 1 - p) >> 1;
    int rbase = r0a - 1;                // staged input rows rbase..rbase+4
    int lane = threadIdx.x & 63;
    int n0 = (threadIdx.x >> 6) << 6;
    int m = lane & 15, quad = lane >> 4;
    __shared__ __align__(16) unsigned short win[5 * 34 * 136];   // 46.2 KB

    for (int par = 0; par < 2; ++par) {
        f32x4 acc[4][2][4];
        f32x4 z = {0.f, 0.f, 0.f, 0.f};
        #pragma unroll
        for (int r = 0; r < 4; ++r)
            #pragma unroll
            for (int i2 = 0; i2 < 2; ++i2)
                #pragma unroll
                for (int t = 0; t < 4; ++t) acc[r][i2][t] = z;

        for (int c0 = 0; c0 < 256; c0 += 128) {
            __syncthreads();
            for (int s = threadIdx.x; s < 5 * 34 * 16; s += 256) {
                int c16 = s & 15;
                int t2 = s >> 4;
                int col = t2 % 34;
                int rr = t2 / 34;
                int ih = rbase + rr, iw = col - 1;
                int4 v = make_int4(0, 0, 0, 0);
                if ((unsigned)ih < 32u && (unsigned)iw < 32u)
                    v = *(const int4*)&in[((((bb << 5) + ih) << 5) + iw) * 256 + c0 + (c16 << 3)];
                *(int4*)&win[(rr * 34 + col) * 136 + (c16 << 3)] = v;
            }
            __syncthreads();

            #pragma unroll
            for (int t = 0; t < 2; ++t) {
                int kh = p + 2 * t;
                #pragma unroll
                for (int u = 0; u < 2; ++u) {
                    int kw = (1 - par) + 2 * u;
                    int ixoff = par - u + 1;
                    #pragma unroll
                    for (int cch = 0; cch < 4; ++cch) {
                        bf16x8 a[4][2];
                        #pragma unroll
                        for (int r = 0; r < 4; ++r) {
                            const unsigned short* ba =
                                &win[((1 - t + r) * 34 + m + ixoff) * 136 + (cch << 5) + (quad << 3)];
                            a[r][0] = *(const bf16x8*)ba;
                            a[r][1] = *(const bf16x8*)(ba + 16 * 136);
                        }
                        int cgl = (c0 >> 5) + cch;
                        int wbase = ((((kh << 2) + kw) * 8 + cgl) * 256 + n0 + m) * 32 + (quad << 3);
                        bf16x8 b0 = *(const bf16x8*)&wf[wbase];
                        bf16x8 b1 = *(const bf16x8*)&wf[wbase + 16 * 32];
                        bf16x8 b2 = *(const bf16x8*)&wf[wbase + 32 * 32];
                        bf16x8 b3 = *(const bf16x8*)&wf[wbase + 48 * 32];
                        #pragma unroll
                        for (int r = 0; r < 4; ++r) {
                            acc[r][0][0] = MFMA_B16(a[r][0], b0, acc[r][0][0]);
                            acc[r][0][1] = MFMA_B16(a[r][0], b1, acc[r][0][1]);
                            acc[r][0][2] = MFMA_B16(a[r][0], b2, acc[r][0][2]);
                            acc[r][0][3] = MFMA_B16(a[r][0], b3, acc[r][0][3]);
                            acc[r][1][0] = MFMA_B16(a[r][1], b0, acc[r][1][0]);
                            acc[r][1][1] = MFMA_B16(a[r][1], b1, acc[r][1][1]);
                            acc[r][1][2] = MFMA_B16(a[r][1], b2, acc[r][1][2]);
                            acc[r][1][3] = MFMA_B16(a[r][1], b3, acc[r][1][3]);
                        }
                    }
                }
            }
        }

        #pragma unroll
        for (int r = 0; r < 4; ++r) {
            int oy = oy_a + 2 * r;
            #pragma unroll
            for (int mt = 0; mt < 2; ++mt)
                #pragma unroll
                for (int nt = 0; nt < 4; ++nt) {
                    int col = n0 + nt * 16 + m;
                    float bs = bias[col];
                    #pragma unroll
                    for (int rr = 0; rr < 4; ++rr) {
                        int ox = 2 * (mt * 16 + quad * 4 + rr) + par;
                        float v = fmaxf(acc[r][mt][nt][rr] + bs, 0.f);
                        out[((((bb << 6) + oy) << 6) + ox) * 256 + col] = f2b(v);
                    }
                }
        }
    }
}

// ======================================================================
// vqm: MFMA VQ + exact fp32 gather/loss. grid = B*32.
// ======================================================================
__global__ void __launch_bounds__(256, 2)
vqm_k(const unsigned short* __restrict__ zeb, const float* __restrict__ zef,
      const unsigned short* __restrict__ embF, const float* __restrict__ embed,
      const float* __restrict__ nrm, unsigned short* __restrict__ zq,
      float* __restrict__ lacc)
{
    int bh = blockIdx.x;
    int tid = threadIdx.x;
    int lane = tid & 63;
    int wv = tid >> 6;
    int m = lane & 15, quad = lane >> 4;
    __shared__ __align__(16) unsigned short win[32 * 264];
    __shared__ float bvv[4][32];
    __shared__ int   bii[4][32];
    __shared__ int   bidx[32];
    int rowbase = bh << 13;
    for (int s = tid; s < 32 * 32; s += 256) {
        int c8 = s & 31, px = s >> 5;
        *(int4*)&win[px * 264 + (c8 << 3)] = *(const int4*)&zeb[rowbase + (px << 8) + (c8 << 3)];
    }
    __syncthreads();

    f32x4 acc[2][8];
    f32x4 z = {0.f, 0.f, 0.f, 0.f};
    #pragma unroll
    for (int i = 0; i < 2; ++i)
        #pragma unroll
        for (int j = 0; j < 8; ++j) acc[i][j] = z;

    #pragma unroll
    for (int cch = 0; cch < 8; ++cch) {
        bf16x8 a0 = *(const bf16x8*)&win[m * 264 + (cch << 5) + (quad << 3)];
        bf16x8 a1 = *(const bf16x8*)&win[(m + 16) * 264 + (cch << 5) + (quad << 3)];
        #pragma unroll
        for (int nt = 0; nt < 8; ++nt) {
            bf16x8 b = *(const bf16x8*)&embF[((cch << 9) + (wv << 7) + (nt << 4) + m) * 32 + (quad << 3)];
            acc[0][nt] = MFMA_B16(a0, b, acc[0][nt]);
            acc[1][nt] = MFMA_B16(a1, b, acc[1][nt]);
        }
    }

    float nv[8];
    #pragma unroll
    for (int nt = 0; nt < 8; ++nt) nv[nt] = nrm[(wv << 7) + (nt << 4) + m];

    #pragma unroll
    for (int mt = 0; mt < 2; ++mt)
        #pragma unroll
        for (int r = 0; r < 4; ++r) {
            float bv = 1e30f;
            int bi = 0x7fffffff;
            #pragma unroll
            for (int nt = 0; nt < 8; ++nt) {
                float d = nv[nt] - 2.f * acc[mt][nt][r];
                int n = (wv << 7) + (nt << 4) + m;
                if (d < bv || (d == bv && n < bi)) { bv = d; bi = n; }
            }
            #pragma unroll
            for (int off = 1; off < 16; off <<= 1) {
                float ov = __shfl_xor(bv, off);
                int oi = __shfl_xor(bi, off);
                if (ov < bv || (ov == bv && oi < bi)) { bv = ov; bi = oi; }
            }
            if (m == 0) {
                int px = mt * 16 + quad * 4 + r;
                bvv[wv][px] = bv;
                bii[wv][px] = bi;
            }
        }
    __syncthreads();
    if (tid < 32) {
        float bv = bvv[0][tid];
        int bi = bii[0][tid];
        #pragma unroll
        for (int w2 = 1; w2 < 4; ++w2) {
            float ov = bvv[w2][tid];
            int oi = bii[w2][tid];
            if (ov < bv || (ov == bv && oi < bi)) { bv = ov; bi = oi; }
        }
        bidx[tid] = bi;
    }
    __syncthreads();

    float lsum = 0.f;
    #pragma unroll
    for (int j = 0; j < 8; ++j) {
        int px = (wv << 3) + j;
        int bi = bidx[px];
        int pix = (bh << 5) + px;
        const float4 e = *(const float4*)&embed[bi * 256 + (lane << 2)];
        const float4 zv = *(const float4*)&zef[(pix << 8) + (lane << 2)];
        ushort4 eq;
        eq.x = f2b(e.x); eq.y = f2b(e.y); eq.z = f2b(e.z); eq.w = f2b(e.w);
        *(ushort4*)&zq[(pix << 8) + (lane << 2)] = eq;
        float dx = zv.x - e.x, dy = zv.y - e.y, dz = zv.z - e.z, dw = zv.w - e.w;
        lsum += dx * dx + dy * dy + dz * dz + dw * dw;
    }
    #pragma unroll
    for (int off = 1; off < 64; off <<= 1) lsum += __shfl_xor(lsum, off);
    if (lane == 0) atomicAdd(lacc, lsum);
}

// ======================================================================
// mdec2a: deconv2 pass 1 — Y[B*64*64, 48] = X[.,256] x Wg[256,48]
// ======================================================================
__global__ void __launch_bounds__(256, 4)
mdec2a_k(const unsigned short* __restrict__ in, const unsigned short* __restrict__ wg,
         float* __restrict__ Y)
{
    int tid = threadIdx.x;
    int lane = tid & 63;
    int wv = tid >> 6;
    int m = lane & 15, quad = lane >> 4;
    __shared__ __align__(16) unsigned short win[64 * 264];
    int pxbase = blockIdx.x << 6;
    for (int s = tid; s < 64 * 32; s += 256) {
        int c8 = s & 31, px = s >> 5;
        *(int4*)&win[px * 264 + (c8 << 3)] = *(const int4*)&in[((pxbase + px) << 8) + (c8 << 3)];
    }
    __syncthreads();
    f32x4 acc[3];
    f32x4 z = {0.f, 0.f, 0.f, 0.f};
    acc[0] = z; acc[1] = z; acc[2] = z;
    #pragma unroll
    for (int cch = 0; cch < 8; ++cch) {
        bf16x8 a = *(const bf16x8*)&win[((wv << 4) + m) * 264 + (cch << 5) + (quad << 3)];
        #pragma unroll
        for (int nt = 0; nt < 3; ++nt) {
            bf16x8 b = *(const bf16x8*)&wg[(cch * 48 + nt * 16 + m) * 32 + (quad << 3)];
            acc[nt] = MFMA_B16(a, b, acc[nt]);
        }
    }
    #pragma unroll
    for (int nt = 0; nt < 3; ++nt)
        #pragma unroll
        for (int r = 0; r < 4; ++r) {
            int px = pxbase + (wv << 4) + quad * 4 + r;
            Y[px * 48 + nt * 16 + m] = acc[nt][r];
        }
}

// ======================================================================
// dec2b: deconv2 pass 2 — gather taps, +bias, sigmoid, NCHW out.
// ======================================================================
__global__ void dec2b_k(const float* __restrict__ Y, const float* __restrict__ bias,
                        float* __restrict__ out)
{
    int idx = blockIdx.x * 256 + threadIdx.x;    // < 524288
    int b = idx >> 14;
    int rem = idx & 16383;
    int oy = rem >> 7;
    int ox = rem & 127;
    int p = (oy + 1) & 1;
    int q = (ox + 1) & 1;
    float acc0 = bias[0], acc1 = bias[1], acc2 = bias[2];
    #pragma unroll
    for (int t = 0; t < 2; ++t) {
        int kh = p + 2 * t;
        int ih = (oy + 1 - kh) >> 1;
        if ((unsigned)ih >= 64u) continue;
        #pragma unroll
        for (int u = 0; u < 2; ++u) {
            int kw = q + 2 * u;
            int iw = (ox + 1 - kw) >> 1;
            if ((unsigned)iw >= 64u) continue;
            int base = ((((b << 6) + ih) << 6) + iw) * 48 + ((kh << 2) + kw) * 3;
            acc0 += Y[base];
            acc1 += Y[base + 1];
            acc2 += Y[base + 2];
        }
    }
    int obase = (b * 3 << 14) + (oy << 7) + ox;
    out[obase]           = 1.f / (1.f + expf(-acc0));
    out[obase + 16384]   = 1.f / (1.f + expf(-acc1));
    out[obase + 32768]   = 1.f / (1.f + expf(-acc2));
}

// ======================================================================
extern "C" void kernel_launch(void* const* d_in, const int* in_sizes, int n_in,
                              void* d_out, int out_size, void* d_ws, size_t ws_size,
                              hipStream_t stream)
{
    (void)in_sizes; (void)n_in; (void)out_size; (void)ws_size;
    const float* x      = (const float*)d_in[0];
    const float* embed  = (const float*)d_in[1];
    const float* e_w1   = (const float*)d_in[2];
    const float* e_w2   = (const float*)d_in[3];
    const float* e_r1a  = (const float*)d_in[4];
    const float* e_r1b  = (const float*)d_in[5];
    const float* e_r2a  = (const float*)d_in[6];
    const float* e_r2b  = (const float*)d_in[7];
    const float* d_r1a  = (const float*)d_in[8];
    const float* d_r1b  = (const float*)d_in[9];
    const float* d_r2a  = (const float*)d_in[10];
    const float* d_r2b  = (const float*)d_in[11];
    const float* dt1_w  = (const float*)d_in[12];
    const float* dt1_b  = (const float*)d_in[13];
    const float* dt2_w  = (const float*)d_in[14];
    const float* dt2_b  = (const float*)d_in[15];
    float* outp = (float*)d_out;

    // ---- workspace layout ----
    char* base = (char*)d_ws;
    size_t off = 0;
    auto alloc = [&](size_t bytes) { char* p = base + off; off += (bytes + 255) & ~size_t(255); return p; };
    unsigned short* A0b = (unsigned short*)alloc(67108864);  // (B,64,64,256) bf16
    float*          A1f = (float*)alloc(33554432);           // ze fp32; later Y
    unsigned short* L0  = (unsigned short*)alloc(16777216);
    unsigned short* L1  = (unsigned short*)alloc(16777216);
    unsigned short* L2  = (unsigned short*)alloc(16777216);
    unsigned short* Wf  = (unsigned short*)alloc(9437184);   // 10 frag-ordered weights
    unsigned short* Wg  = (unsigned short*)alloc(24576);     // deconv2 frag weights
    unsigned short* EmbF = (unsigned short*)alloc(262144);   // codebook frag bf16
    unsigned short* WgC = (unsigned short*)alloc(32768);     // conv1 frag weights
    float* Nrm  = (float*)alloc(2048);
    float* Lacc = (float*)alloc(64);
    float* Y = A1f;   // alias: ze dead after vqm_k

    // frag-weight segment offsets inside Wf (element counts)
    unsigned short* Wf_ew2  = Wf;
    unsigned short* Wf_er1a = Wf + 1048576;
    unsigned short* Wf_er1b = Wf + 1638400;
    unsigned short* Wf_er2a = Wf + 1703936;
    unsigned short* Wf_er2b = Wf + 2293760;
    unsigned short* Wf_dr1a = Wf + 2359296;
    unsigned short* Wf_dr1b = Wf + 2949120;
    unsigned short* Wf_dr2a = Wf + 3014656;
    unsigned short* Wf_dr2b = Wf + 3604480;
    unsigned short* Wf_dt1  = Wf + 3670016;

    PermfArgs pa;
    const float* srcs[10] = {e_w2, e_r1a, e_r1b, e_r2a, e_r2b, d_r1a, d_r1b, d_r2a, d_r2b, dt1_w};
    int kws[10] = {4, 3, 1, 3, 1, 3, 1, 3, 1, 4};
    int sos[10] = {4096, 2304, 256, 2304, 256, 2304, 256, 2304, 256, 16};
    int sis[10] = {16, 9, 1, 9, 1, 9, 1, 9, 1, 4096};
    int shs[10] = {4, 3, 0, 3, 0, 3, 0, 3, 0, 4};
    int sws[10] = {1, 1, 0, 1, 0, 1, 0, 1, 0, 1};
    int cums[11] = {0, 1048576, 1638400, 1703936, 2293760, 2359296,
                    2949120, 3014656, 3604480, 3670016, 4718592};
    for (int k = 0; k < 10; ++k) {
        pa.src[k] = srcs[k]; pa.kw[k] = kws[k]; pa.so[k] = sos[k];
        pa.si[k] = sis[k]; pa.sh[k] = shs[k]; pa.sw[k] = sws[k];
        pa.cum[k] = cums[k];
    }
    pa.cum[10] = cums[10];

    permf_all_k<<<18432, 256, 0, stream>>>(pa, Wf);
    misc_prep_k<<<753, 256, 0, stream>>>(dt2_w, Wg, embed, EmbF, e_w1, WgC, Nrm, Lacc);

    // ---- encoder ----
    conv1m_k<<<32 * 64, 256, 0, stream>>>(x, WgC, A0b);
    mconv2_k<<<32 * 16, 256, 0, stream>>>(A0b, Wf_ew2, L1);                  // h
    mconv3_k<<<32 * 16, 256, 0, stream>>>(L1, Wf_er1a, L2);
    m1x1_k<<<32 * 16, 256, 0, stream>>>(L2, Wf_er1b, L1, L0, nullptr, 0);    // r1 -> L0
    mconv3_k<<<32 * 16, 256, 0, stream>>>(L0, Wf_er2a, L2);
    m1x1_k<<<32 * 16, 256, 0, stream>>>(L2, Wf_er2b, L0, L1, A1f, 1);        // ze: bf16->L1, fp32->A1f

    // ---- VQ ----
    vqm_k<<<32 * 32, 256, 0, stream>>>(L1, A1f, EmbF, embed, Nrm, L1, Lacc);

    // ---- decoder ----
    mconv3_k<<<32 * 16, 256, 0, stream>>>(L1, Wf_dr1a, L2);
    m1x1_k<<<32 * 16, 256, 0, stream>>>(L2, Wf_dr1b, L1, L0, nullptr, 0);    // d1 -> L0
    mconv3_k<<<32 * 16, 256, 0, stream>>>(L0, Wf_dr2a, L2);
    m1x1_k<<<32 * 16, 256, 0, stream>>>(L2, Wf_dr2b, L0, L1, nullptr, 0);    // d2 -> L1
    mdeconv1_k<<<32 * 16, 256, 0, stream>>>(L1, Wf_dt1, dt1_b, A0b);
    mdec2a_k<<<2048, 256, 0, stream>>>(A0b, Wg, Y);
    dec2b_k<<<2048, 256, 0, stream>>>(Y, dt2_b, outp);
    lossfin_k<<<1, 64, 0, stream>>>(Lacc, outp);
}

// Round 9
// 766.814 us; speedup vs baseline: 1.1901x; 1.1901x over previous
//
#include <hip/hip_runtime.h>

// ======================================================================
// VQ-VAE forward, all-MFMA. B=32, CIN=3, IMG=128, D=256, K=512.
// NHWC bf16 activations. M=64 px per block for all 256-ch convs. LDS row
// stride 132/264 shorts (16B aligned, <=2-way bank aliasing = free).
// Weights frag-ordered Wf[khkw][cch][n][32]. MFMA 16x16x32 bf16:
// A[m=lane&15][k=quad*8+j], B[n][k], D col=lane&15, row=quad*4+reg.
// R4: mdeconv1 R1 2-row structure + LDS-transpose epilogue (full-512B
// dwordx4 stores) -> 848->815us, recon replay-stable.
// R6: loss made DETERMINISTIC: vqm writes 4096 wave-partials to Lpart
// (no atomics); lossfin does fixed-order 256-thread tree reduction.
// R4's single-cell fp32 atomicAdd drifted +-ulp(1e7)~4 across replays,
// tripping the post-timing check on output 1 (loss) at thr 3.0.
// ======================================================================

typedef __attribute__((ext_vector_type(8))) short bf16x8;
typedef __attribute__((ext_vector_type(4))) float f32x4;
#define MFMA_B16(a, b, c) __builtin_amdgcn_mfma_f32_16x16x32_bf16(a, b, c, 0, 0, 0)

__device__ inline unsigned short f2b(float f) {
    unsigned int u = __float_as_uint(f);
    unsigned int r = u + 0x7fffu + ((u >> 16) & 1u);
    return (unsigned short)(r >> 16);
}
__device__ inline float b2f(unsigned short u) {
    return __uint_as_float(((unsigned int)u) << 16);
}

// ======================================================================
// batched bf16 frag-order weight permute for the 10 conv/deconv weights.
// dst[(((kh*KW+kw)*8 + cch)*256 + n)*32 + q] = bf16(src[n*so + (cch*32+q)*si + kh*sh + kw*sw])
// ======================================================================
struct PermfArgs {
    const float* src[10];
    int kw[10];
    int so[10], si[10], sh[10], sw[10];
    int cum[11];
};

__global__ void permf_all_k(PermfArgs a, unsigned short* __restrict__ dst)
{
    int gid = blockIdx.x * 256 + threadIdx.x;
    if (gid >= a.cum[10]) return;
    int seg = 0;
    while (seg < 9 && gid >= a.cum[seg + 1]) ++seg;
    int l = gid - a.cum[seg];
    int q = l & 31;
    int n = (l >> 5) & 255;
    int rest = l >> 13;
    int cch = rest & 7;
    int khkw = rest >> 3;
    int kh = khkw / a.kw[seg], kw = khkw % a.kw[seg];
    int ci = cch * 32 + q;
    dst[gid] = f2b(a.src[seg][n * a.so[seg] + ci * a.si[seg] + kh * a.sh[seg] + kw * a.sw[seg]]);
}

// ======================================================================
// misc prep: deconv2 frag weights, codebook frag, conv1 frag weights,
// codebook norms. 752 blocks x 256.
// ======================================================================
__global__ void misc_prep_k(const float* __restrict__ dt2_w, unsigned short* __restrict__ wg,
                            const float* __restrict__ embed, unsigned short* __restrict__ embF,
                            const float* __restrict__ e_w1, unsigned short* __restrict__ wgc,
                            float* __restrict__ nrm)
{
    int blk = blockIdx.x, tid = threadIdx.x;
    if (blk < 48) {                       // deconv2 weights, N=48: n=(kh*4+kw)*3+oc
        int idx = blk * 256 + tid;        // < 12288
        int q = idx & 31;
        int n = (idx >> 5) % 48;
        int cch = idx / (48 * 32);
        int ci = cch * 32 + q;
        int oc = n % 3, khkw = n / 3;
        int kh = khkw >> 2, kw = khkw & 3;
        wg[idx] = f2b(dt2_w[ci * 48 + oc * 16 + kh * 4 + kw]);
    } else if (blk < 560) {               // codebook frag: dst[(cch*512+n)*32+q]
        int idx = (blk - 48) * 256 + tid; // < 131072
        int q = idx & 31;
        int n = (idx >> 5) & 511;
        int cch = idx >> 14;
        embF[idx] = f2b(embed[n * 256 + cch * 32 + q]);
    } else if (blk < 624) {               // conv1 im2col weights, K=48 pad 64
        int idx = (blk - 560) * 256 + tid;  // < 16384
        int q = idx & 31;
        int n = (idx >> 5) & 255;
        int kt = idx >> 13;
        int k = kt * 32 + q;
        float v = 0.f;
        if (k < 48) {
            int ci = k >> 4, kh = (k >> 2) & 3, kwv = k & 3;
            v = e_w1[n * 48 + ci * 16 + kh * 4 + kwv];
        }
        wgc[idx] = f2b(v);
    } else {                              // codebook row norms, 4 rows/block
        int row = (blk - 624) * 4 + (tid >> 6);
        int lane = tid & 63;
        float s = 0.f;
        #pragma unroll
        for (int c = 0; c < 256; c += 64) {
            float v = embed[row * 256 + c + lane];
            s += v * v;
        }
        #pragma unroll
        for (int off = 1; off < 64; off <<= 1) s += __shfl_xor(s, off);
        if (lane == 0) nrm[row] = s;
    }
}

// ======================================================================
// lossfin: deterministic fixed-order reduction of 4096 wave-partials.
// 1 block x 256 threads; 16 contiguous loads/thread + LDS tree.
// ======================================================================
__global__ void lossfin_k(const float* __restrict__ lpart, float* __restrict__ out)
{
    __shared__ float red[256];
    int tid = threadIdx.x;
    float s = 0.f;
    #pragma unroll
    for (int i = 0; i < 16; ++i) s += lpart[tid * 16 + i];
    red[tid] = s;
    __syncthreads();
    for (int off = 128; off > 0; off >>= 1) {
        if (tid < off) red[tid] += red[tid + off];
        __syncthreads();
    }
    if (tid == 0) {
        float m = red[0] * (1.0f / 32768.0f);
        out[1572864] = m;
        out[1572865] = m;
    }
}

// ======================================================================
// conv1m: MFMA im2col conv1. x NCHW fp32 -> NHWC bf16 (B,64,64,256),
// k4 s2 p1, ReLU. grid = B*64 (one output row, 64 px). K=48 pad 64.
// ======================================================================
__global__ void __launch_bounds__(256, 4)
conv1m_k(const float* __restrict__ x, const unsigned short* __restrict__ wgc,
         unsigned short* __restrict__ out)
{
    int bh = blockIdx.x;             // b*64 + oh
    int b = bh >> 6, oh = bh & 63;
    int tid = threadIdx.x;
    int lane = tid & 63, wv = tid >> 6;
    int m = lane & 15, quad = lane >> 4;
    __shared__ float xrow[3][4][130];
    __shared__ __align__(16) unsigned short imc[64 * 72];   // stride 72 (144B, 16B-aligned)
    for (int s = tid; s < 1560; s += 256) {
        int col = s % 130;
        int t = s / 130;
        int r = t & 3;
        int c = t >> 2;
        int ih = 2 * oh - 1 + r, iw = col - 1;
        float v = 0.f;
        if ((unsigned)ih < 128u && (unsigned)iw < 128u)
            v = x[(((b * 3 + c) << 7) + ih) * 128 + iw];
        xrow[c][r][col] = v;
    }
    __syncthreads();
    for (int s = tid; s < 4096; s += 256) {
        int px = s >> 6, k = s & 63;
        float v = 0.f;
        if (k < 48) {
            int ci = k >> 4, kh = (k >> 2) & 3, kw = k & 3;
            v = xrow[ci][kh][2 * px + kw];
        }
        imc[px * 72 + k] = f2b(v);
    }
    __syncthreads();
    f32x4 acc[16];
    f32x4 z = {0.f, 0.f, 0.f, 0.f};
    #pragma unroll
    for (int i = 0; i < 16; ++i) acc[i] = z;
    bf16x8 a0 = *(const bf16x8*)&imc[((wv << 4) + m) * 72 + (quad << 3)];
    bf16x8 a1 = *(const bf16x8*)&imc[((wv << 4) + m) * 72 + 32 + (quad << 3)];
    #pragma unroll
    for (int nt = 0; nt < 16; ++nt) {
        bf16x8 b0 = *(const bf16x8*)&wgc[(nt * 16 + m) * 32 + (quad << 3)];
        bf16x8 b1 = *(const bf16x8*)&wgc[(256 + nt * 16 + m) * 32 + (quad << 3)];
        acc[nt] = MFMA_B16(a0, b0, acc[nt]);
        acc[nt] = MFMA_B16(a1, b1, acc[nt]);
    }
    #pragma unroll
    for (int nt = 0; nt < 16; ++nt)
        #pragma unroll
        for (int r = 0; r < 4; ++r) {
            int px = (wv << 4) + quad * 4 + r;
            out[(((bh << 6) + px) << 8) + nt * 16 + (lane & 15)] = f2b(fmaxf(acc[nt][r], 0.f));
        }
}

// ======================================================================
// mconv2: k4 s2 p1, (B,64,64,256)->(B,32,32,256), ReLU. M=64 (2 out rows).
// grid = B*16. Channel-split staging (128 ch/phase), parity-split cols.
// ======================================================================
__global__ void __launch_bounds__(256, 3)
mconv2_k(const unsigned short* __restrict__ in, const unsigned short* __restrict__ wf,
         unsigned short* __restrict__ out)
{
    int blk = blockIdx.x;
    int bb = blk >> 4, j = blk & 15;      // out rows 2j, 2j+1
    int lane = threadIdx.x & 63;
    int n0 = (threadIdx.x >> 6) << 6;
    int m = lane & 15, quad = lane >> 4;
    __shared__ __align__(16) unsigned short win[2 * 66 * 132];  // 34.8 KB
    f32x4 acc[2][2][4];
    f32x4 z = {0.f, 0.f, 0.f, 0.f};
    #pragma unroll
    for (int a = 0; a < 2; ++a)
        #pragma unroll
        for (int i = 0; i < 2; ++i)
            #pragma unroll
            for (int t = 0; t < 4; ++t) acc[a][i][t] = z;

    for (int c0 = 0; c0 < 256; c0 += 128) {
        for (int kh = 0; kh < 4; ++kh) {
            __syncthreads();
            for (int s = threadIdx.x; s < 2 * 66 * 16; s += 256) {
                int c16 = s & 15;
                int t2 = s >> 4;
                int col = t2 % 66;
                int rr = t2 / 66;
                int ih = 4 * j - 1 + kh + 2 * rr, iw = col - 1;
                int4 v = make_int4(0, 0, 0, 0);
                if ((unsigned)ih < 64u && (unsigned)iw < 64u)
                    v = *(const int4*)&in[((((bb << 6) + ih) << 6) + iw) * 256 + c0 + (c16 << 3)];
                int cs = (col >> 1) + (col & 1) * 33;
                *(int4*)&win[(rr * 66 + cs) * 132 + (c16 << 3)] = v;
            }
            __syncthreads();
            #pragma unroll
            for (int kw = 0; kw < 4; ++kw) {
                int csoff = (kw >> 1) + (kw & 1) * 33;
                #pragma unroll
                for (int cch = 0; cch < 4; ++cch) {
                    bf16x8 a00 = *(const bf16x8*)&win[(m + csoff) * 132 + (cch << 5) + (quad << 3)];
                    bf16x8 a01 = *(const bf16x8*)&win[(m + 16 + csoff) * 132 + (cch << 5) + (quad << 3)];
                    bf16x8 a10 = *(const bf16x8*)&win[(66 + m + csoff) * 132 + (cch << 5) + (quad << 3)];
                    bf16x8 a11 = *(const bf16x8*)&win[(66 + m + 16 + csoff) * 132 + (cch << 5) + (quad << 3)];
                    int cg = (c0 >> 5) + cch;
                    int wbase = ((((kh << 2) + kw) * 8 + cg) * 256 + n0 + m) * 32 + (quad << 3);
                    bf16x8 b0 = *(const bf16x8*)&wf[wbase];
                    bf16x8 b1 = *(const bf16x8*)&wf[wbase + 16 * 32];
                    bf16x8 b2 = *(const bf16x8*)&wf[wbase + 32 * 32];
                    bf16x8 b3 = *(const bf16x8*)&wf[wbase + 48 * 32];
                    acc[0][0][0] = MFMA_B16(a00, b0, acc[0][0][0]);
                    acc[0][0][1] = MFMA_B16(a00, b1, acc[0][0][1]);
                    acc[0][0][2] = MFMA_B16(a00, b2, acc[0][0][2]);
                    acc[0][0][3] = MFMA_B16(a00, b3, acc[0][0][3]);
                    acc[0][1][0] = MFMA_B16(a01, b0, acc[0][1][0]);
                    acc[0][1][1] = MFMA_B16(a01, b1, acc[0][1][1]);
                    acc[0][1][2] = MFMA_B16(a01, b2, acc[0][1][2]);
                    acc[0][1][3] = MFMA_B16(a01, b3, acc[0][1][3]);
                    acc[1][0][0] = MFMA_B16(a10, b0, acc[1][0][0]);
                    acc[1][0][1] = MFMA_B16(a10, b1, acc[1][0][1]);
                    acc[1][0][2] = MFMA_B16(a10, b2, acc[1][0][2]);
                    acc[1][0][3] = MFMA_B16(a10, b3, acc[1][0][3]);
                    acc[1][1][0] = MFMA_B16(a11, b0, acc[1][1][0]);
                    acc[1][1][1] = MFMA_B16(a11, b1, acc[1][1][1]);
                    acc[1][1][2] = MFMA_B16(a11, b2, acc[1][1][2]);
                    acc[1][1][3] = MFMA_B16(a11, b3, acc[1][1][3]);
                }
            }
        }
    }
    #pragma unroll
    for (int row = 0; row < 2; ++row) {
        int oh = 2 * j + row;
        #pragma unroll
        for (int mt = 0; mt < 2; ++mt)
            #pragma unroll
            for (int nt = 0; nt < 4; ++nt)
                #pragma unroll
                for (int r = 0; r < 4; ++r) {
                    int px = mt * 16 + quad * 4 + r;
                    int col = n0 + nt * 16 + m;
                    out[((((bb << 5) + oh) << 5) + px) * 256 + col] = f2b(fmaxf(acc[row][mt][nt][r], 0.f));
                }
    }
}

// ======================================================================
// mconv3: 3x3 s1 p1 + ReLU, (B,32,32,256)->(B,32,32,256). M=64. grid B*16.
// Channel-split staging: 4 input rows x 34 cols x 128 ch per phase.
// ======================================================================
__global__ void __launch_bounds__(256, 3)
mconv3_k(const unsigned short* __restrict__ in, const unsigned short* __restrict__ wf,
         unsigned short* __restrict__ out)
{
    int blk = blockIdx.x;
    int bb = blk >> 4, j = blk & 15;      // out rows 2j, 2j+1
    int lane = threadIdx.x & 63;
    int n0 = (threadIdx.x >> 6) << 6;
    int m = lane & 15, quad = lane >> 4;
    __shared__ __align__(16) unsigned short win[4 * 34 * 132];  // 35.9 KB
    f32x4 acc[2][2][4];
    f32x4 z = {0.f, 0.f, 0.f, 0.f};
    #pragma unroll
    for (int a = 0; a < 2; ++a)
        #pragma unroll
        for (int i = 0; i < 2; ++i)
            #pragma unroll
            for (int t = 0; t < 4; ++t) acc[a][i][t] = z;

    for (int c0 = 0; c0 < 256; c0 += 128) {
        __syncthreads();
        for (int s = threadIdx.x; s < 4 * 34 * 16; s += 256) {
            int c16 = s & 15;
            int t2 = s >> 4;
            int col = t2 % 34;
            int rr = t2 / 34;
            int ih = 2 * j - 1 + rr, iw = col - 1;
            int4 v = make_int4(0, 0, 0, 0);
            if ((unsigned)ih < 32u && (unsigned)iw < 32u)
                v = *(const int4*)&in[((((bb << 5) + ih) << 5) + iw) * 256 + c0 + (c16 << 3)];
            *(int4*)&win[(rr * 34 + col) * 132 + (c16 << 3)] = v;
        }
        __syncthreads();
        for (int kh = 0; kh < 3; ++kh) {
            #pragma unroll
            for (int kw = 0; kw < 3; ++kw) {
                #pragma unroll
                for (int cch = 0; cch < 4; ++cch) {
                    const unsigned short* ba = &win[(kh * 34 + m + kw) * 132 + (cch << 5) + (quad << 3)];
                    bf16x8 a00 = *(const bf16x8*)ba;
                    bf16x8 a01 = *(const bf16x8*)(ba + 16 * 132);
                    bf16x8 a10 = *(const bf16x8*)(ba + 34 * 132);
                    bf16x8 a11 = *(const bf16x8*)(ba + 50 * 132);
                    int cg = (c0 >> 5) + cch;
                    int wbase = (((kh * 3 + kw) * 8 + cg) * 256 + n0 + m) * 32 + (quad << 3);
                    bf16x8 b0 = *(const bf16x8*)&wf[wbase];
                    bf16x8 b1 = *(const bf16x8*)&wf[wbase + 16 * 32];
                    bf16x8 b2 = *(const bf16x8*)&wf[wbase + 32 * 32];
                    bf16x8 b3 = *(const bf16x8*)&wf[wbase + 48 * 32];
                    acc[0][0][0] = MFMA_B16(a00, b0, acc[0][0][0]);
                    acc[0][0][1] = MFMA_B16(a00, b1, acc[0][0][1]);
                    acc[0][0][2] = MFMA_B16(a00, b2, acc[0][0][2]);
                    acc[0][0][3] = MFMA_B16(a00, b3, acc[0][0][3]);
                    acc[0][1][0] = MFMA_B16(a01, b0, acc[0][1][0]);
                    acc[0][1][1] = MFMA_B16(a01, b1, acc[0][1][1]);
                    acc[0][1][2] = MFMA_B16(a01, b2, acc[0][1][2]);
                    acc[0][1][3] = MFMA_B16(a01, b3, acc[0][1][3]);
                    acc[1][0][0] = MFMA_B16(a10, b0, acc[1][0][0]);
                    acc[1][0][1] = MFMA_B16(a10, b1, acc[1][0][1]);
                    acc[1][0][2] = MFMA_B16(a10, b2, acc[1][0][2]);
                    acc[1][0][3] = MFMA_B16(a10, b3, acc[1][0][3]);
                    acc[1][1][0] = MFMA_B16(a11, b0, acc[1][1][0]);
                    acc[1][1][1] = MFMA_B16(a11, b1, acc[1][1][1]);
                    acc[1][1][2] = MFMA_B16(a11, b2, acc[1][1][2]);
                    acc[1][1][3] = MFMA_B16(a11, b3, acc[1][1][3]);
                }
            }
        }
    }
    #pragma unroll
    for (int row = 0; row < 2; ++row) {
        int oh = 2 * j + row;
        #pragma unroll
        for (int mt = 0; mt < 2; ++mt)
            #pragma unroll
            for (int nt = 0; nt < 4; ++nt)
                #pragma unroll
                for (int r = 0; r < 4; ++r) {
                    int px = mt * 16 + quad * 4 + r;
                    int col = n0 + nt * 16 + m;
                    out[((((bb << 5) + oh) << 5) + px) * 256 + col] = f2b(fmaxf(acc[row][mt][nt][r], 0.f));
                }
    }
}

// ======================================================================
// m1x1: 1x1 + residual. M=64. grid = B*16 (=512). Dual bf16/fp32 output.
// ======================================================================
__global__ void __launch_bounds__(256, 3)
m1x1_k(const unsigned short* __restrict__ in, const unsigned short* __restrict__ wf,
       const unsigned short* __restrict__ res, unsigned short* __restrict__ outb,
       float* __restrict__ outf, int f32out)
{
    int blk = blockIdx.x;
    int lane = threadIdx.x & 63;
    int n0 = (threadIdx.x >> 6) << 6;
    int m = lane & 15, quad = lane >> 4;
    __shared__ __align__(16) unsigned short win[64 * 264];   // 33.8 KB
    f32x4 acc[4][4];
    f32x4 z = {0.f, 0.f, 0.f, 0.f};
    #pragma unroll
    for (int i = 0; i < 4; ++i)
        #pragma unroll
        for (int t = 0; t < 4; ++t) acc[i][t] = z;

    int rowbase = blk << 14;   // 64 px * 256
    for (int s = threadIdx.x; s < 64 * 32; s += 256) {
        int c8 = s & 31, col = s >> 5;
        *(int4*)&win[col * 264 + (c8 << 3)] = *(const int4*)&in[rowbase + (col << 8) + (c8 << 3)];
    }
    __syncthreads();
    #pragma unroll
    for (int cch = 0; cch < 8; ++cch) {
        bf16x8 a0 = *(const bf16x8*)&win[m * 264 + (cch << 5) + (quad << 3)];
        bf16x8 a1 = *(const bf16x8*)&win[(m + 16) * 264 + (cch << 5) + (quad << 3)];
        bf16x8 a2 = *(const bf16x8*)&win[(m + 32) * 264 + (cch << 5) + (quad << 3)];
        bf16x8 a3 = *(const bf16x8*)&win[(m + 48) * 264 + (cch << 5) + (quad << 3)];
        int wbase = (cch * 256 + n0 + m) * 32 + (quad << 3);
        bf16x8 b0 = *(const bf16x8*)&wf[wbase];
        bf16x8 b1 = *(const bf16x8*)&wf[wbase + 16 * 32];
        bf16x8 b2 = *(const bf16x8*)&wf[wbase + 32 * 32];
        bf16x8 b3 = *(const bf16x8*)&wf[wbase + 48 * 32];
        acc[0][0] = MFMA_B16(a0, b0, acc[0][0]);
        acc[0][1] = MFMA_B16(a0, b1, acc[0][1]);
        acc[0][2] = MFMA_B16(a0, b2, acc[0][2]);
        acc[0][3] = MFMA_B16(a0, b3, acc[0][3]);
        acc[1][0] = MFMA_B16(a1, b0, acc[1][0]);
        acc[1][1] = MFMA_B16(a1, b1, acc[1][1]);
        acc[1][2] = MFMA_B16(a1, b2, acc[1][2]);
        acc[1][3] = MFMA_B16(a1, b3, acc[1][3]);
        acc[2][0] = MFMA_B16(a2, b0, acc[2][0]);
        acc[2][1] = MFMA_B16(a2, b1, acc[2][1]);
        acc[2][2] = MFMA_B16(a2, b2, acc[2][2]);
        acc[2][3] = MFMA_B16(a2, b3, acc[2][3]);
        acc[3][0] = MFMA_B16(a3, b0, acc[3][0]);
        acc[3][1] = MFMA_B16(a3, b1, acc[3][1]);
        acc[3][2] = MFMA_B16(a3, b2, acc[3][2]);
        acc[3][3] = MFMA_B16(a3, b3, acc[3][3]);
    }
    #pragma unroll
    for (int mt = 0; mt < 4; ++mt)
        #pragma unroll
        for (int nt = 0; nt < 4; ++nt)
            #pragma unroll
            for (int r = 0; r < 4; ++r) {
                int px = mt * 16 + quad * 4 + r;
                int col = n0 + nt * 16 + m;
                int idx = rowbase + (px << 8) + col;
                float v = acc[mt][nt][r] + b2f(res[idx]);
                outb[idx] = f2b(v);
                if (f32out) outf[idx] = v;
            }
}

// ======================================================================
// mdeconv1: ConvTranspose2d(256->256,k4,s2,p1)+bias+ReLU. R1 structure:
// two same-parity oy rows share kh-taps/B-frags, par loop inside, grid
// = B*2*16 = 1024. R4: epilogue via LDS transpose buffer tb[16*264] ->
// each (row,mt) chunk written as 16 px x full 512B dwordx4 stores (one
// instruction per 64B line; replaces 128 scalar 2B stores/thread).
// ======================================================================
__global__ void __launch_bounds__(256, 3)
mdeconv1_k(const unsigned short* __restrict__ in, const unsigned short* __restrict__ wf,
           const float* __restrict__ bias, unsigned short* __restrict__ out)
{
    int blk = blockIdx.x;
    int bb = blk >> 5;
    int rem = blk & 31;
    int pp = rem >> 4;                  // oy parity
    int i = rem & 15;
    int oy_a = pp + 4 * i;              // rows oy_a, oy_a+2
    int p = (oy_a + 1) & 1;
    int r0a = (oy_a + 1 - p) >> 1;
    int rbase = r0a - 1;                // need input rows rbase..rbase+2
    int tid = threadIdx.x;
    int lane = tid & 63;
    int n0 = (tid >> 6) << 6;
    int m = lane & 15, quad = lane >> 4;
    __shared__ __align__(16) unsigned short win[3 * 34 * 264];   // 53.9 KB
    __shared__ __align__(16) unsigned short tb[16 * 264];        // 8.4 KB transpose buf

    for (int s = tid; s < 3 * 34 * 32; s += 256) {
        int c8 = s & 31;
        int t2 = s >> 5;
        int col = t2 % 34;
        int rr = t2 / 34;
        int ih = rbase + rr, iw = col - 1;
        int4 v = make_int4(0, 0, 0, 0);
        if ((unsigned)ih < 32u && (unsigned)iw < 32u)
            v = *(const int4*)&in[((((bb << 5) + ih) << 5) + iw) * 256 + (c8 << 3)];
        *(int4*)&win[(rr * 34 + col) * 264 + (c8 << 3)] = v;
    }
    __syncthreads();

    for (int par = 0; par < 2; ++par) {
        f32x4 acc[2][2][4];
        f32x4 z = {0.f, 0.f, 0.f, 0.f};
        #pragma unroll
        for (int a = 0; a < 2; ++a)
            #pragma unroll
            for (int i2 = 0; i2 < 2; ++i2)
                #pragma unroll
                for (int t = 0; t < 4; ++t) acc[a][i2][t] = z;

        #pragma unroll
        for (int t = 0; t < 2; ++t) {
            int kh = p + 2 * t;
            #pragma unroll
            for (int u = 0; u < 2; ++u) {
                int kw = (1 - par) + 2 * u;
                int ixoff = par - u + 1;
                #pragma unroll
                for (int cch = 0; cch < 8; ++cch) {
                    const unsigned short* baA = &win[((1 - t) * 34 + m + ixoff) * 264 + (cch << 5) + (quad << 3)];
                    const unsigned short* baB = baA + 34 * 264;
                    bf16x8 a00 = *(const bf16x8*)baA;
                    bf16x8 a01 = *(const bf16x8*)(baA + 16 * 264);
                    bf16x8 a10 = *(const bf16x8*)baB;
                    bf16x8 a11 = *(const bf16x8*)(baB + 16 * 264);
                    int wbase = ((((kh << 2) + kw) * 8 + cch) * 256 + n0 + m) * 32 + (quad << 3);
                    bf16x8 b0 = *(const bf16x8*)&wf[wbase];
                    bf16x8 b1 = *(const bf16x8*)&wf[wbase + 16 * 32];
                    bf16x8 b2 = *(const bf16x8*)&wf[wbase + 32 * 32];
                    bf16x8 b3 = *(const bf16x8*)&wf[wbase + 48 * 32];
                    acc[0][0][0] = MFMA_B16(a00, b0, acc[0][0][0]);
                    acc[0][0][1] = MFMA_B16(a00, b1, acc[0][0][1]);
                    acc[0][0][2] = MFMA_B16(a00, b2, acc[0][0][2]);
                    acc[0][0][3] = MFMA_B16(a00, b3, acc[0][0][3]);
                    acc[0][1][0] = MFMA_B16(a01, b0, acc[0][1][0]);
                    acc[0][1][1] = MFMA_B16(a01, b1, acc[0][1][1]);
                    acc[0][1][2] = MFMA_B16(a01, b2, acc[0][1][2]);
                    acc[0][1][3] = MFMA_B16(a01, b3, acc[0][1][3]);
                    acc[1][0][0] = MFMA_B16(a10, b0, acc[1][0][0]);
                    acc[1][0][1] = MFMA_B16(a10, b1, acc[1][0][1]);
                    acc[1][0][2] = MFMA_B16(a10, b2, acc[1][0][2]);
                    acc[1][0][3] = MFMA_B16(a10, b3, acc[1][0][3]);
                    acc[1][1][0] = MFMA_B16(a11, b0, acc[1][1][0]);
                    acc[1][1][1] = MFMA_B16(a11, b1, acc[1][1][1]);
                    acc[1][1][2] = MFMA_B16(a11, b2, acc[1][1][2]);
                    acc[1][1][3] = MFMA_B16(a11, b3, acc[1][1][3]);
                }
            }
        }

        // ---- epilogue: per-(row,mt) LDS transpose -> full-line stores ----
        #pragma unroll
        for (int row = 0; row < 2; ++row) {
            int oy = oy_a + 2 * row;
            #pragma unroll
            for (int mt = 0; mt < 2; ++mt) {
                __syncthreads();   // tb free (prev chunk fully read)
                #pragma unroll
                for (int nt = 0; nt < 4; ++nt) {
                    float bs = bias[n0 + nt * 16 + m];
                    #pragma unroll
                    for (int rr = 0; rr < 4; ++rr) {
                        float v = fmaxf(acc[row][mt][nt][rr] + bs, 0.f);
                        tb[(quad * 4 + rr) * 264 + n0 + nt * 16 + m] = f2b(v);
                    }
                }
                __syncthreads();   // tb ready
                #pragma unroll
                for (int k = 0; k < 2; ++k) {
                    int s = tid + k * 256;
                    int pxl = s >> 5;          // 0..15
                    int c8 = s & 31;
                    int ox = 2 * (mt * 16 + pxl) + par;
                    *(int4*)&out[((((bb << 6) + oy) << 6) + ox) * 256 + (c8 << 3)] =
                        *(const int4*)&tb[pxl * 264 + (c8 << 3)];
                }
            }
        }
    }
}

// ======================================================================
// vqm: MFMA VQ + exact fp32 gather/loss. grid = B*32. Loss partials go
// to lpart[bh*4+wv] (deterministic; no atomics — R6 fix).
// ======================================================================
__global__ void __launch_bounds__(256, 2)
vqm_k(const unsigned short* __restrict__ zeb, const float* __restrict__ zef,
      const unsigned short* __restrict__ embF, const float* __restrict__ embed,
      const float* __restrict__ nrm, unsigned short* __restrict__ zq,
      float* __restrict__ lpart)
{
    int bh = blockIdx.x;
    int tid = threadIdx.x;
    int lane = tid & 63;
    int wv = tid >> 6;
    int m = lane & 15, quad = lane >> 4;
    __shared__ __align__(16) unsigned short win[32 * 264];
    __shared__ float bvv[4][32];
    __shared__ int   bii[4][32];
    __shared__ int   bidx[32];
    int rowbase = bh << 13;
    for (int s = tid; s < 32 * 32; s += 256) {
        int c8 = s & 31, px = s >> 5;
        *(int4*)&win[px * 264 + (c8 << 3)] = *(const int4*)&zeb[rowbase + (px << 8) + (c8 << 3)];
    }
    __syncthreads();

    f32x4 acc[2][8];
    f32x4 z = {0.f, 0.f, 0.f, 0.f};
    #pragma unroll
    for (int i = 0; i < 2; ++i)
        #pragma unroll
        for (int j = 0; j < 8; ++j) acc[i][j] = z;

    #pragma unroll
    for (int cch = 0; cch < 8; ++cch) {
        bf16x8 a0 = *(const bf16x8*)&win[m * 264 + (cch << 5) + (quad << 3)];
        bf16x8 a1 = *(const bf16x8*)&win[(m + 16) * 264 + (cch << 5) + (quad << 3)];
        #pragma unroll
        for (int nt = 0; nt < 8; ++nt) {
            bf16x8 b = *(const bf16x8*)&embF[((cch << 9) + (wv << 7) + (nt << 4) + m) * 32 + (quad << 3)];
            acc[0][nt] = MFMA_B16(a0, b, acc[0][nt]);
            acc[1][nt] = MFMA_B16(a1, b, acc[1][nt]);
        }
    }

    float nv[8];
    #pragma unroll
    for (int nt = 0; nt < 8; ++nt) nv[nt] = nrm[(wv << 7) + (nt << 4) + m];

    #pragma unroll
    for (int mt = 0; mt < 2; ++mt)
        #pragma unroll
        for (int r = 0; r < 4; ++r) {
            float bv = 1e30f;
            int bi = 0x7fffffff;
            #pragma unroll
            for (int nt = 0; nt < 8; ++nt) {
                float d = nv[nt] - 2.f * acc[mt][nt][r];
                int n = (wv << 7) + (nt << 4) + m;
                if (d < bv || (d == bv && n < bi)) { bv = d; bi = n; }
            }
            #pragma unroll
            for (int off = 1; off < 16; off <<= 1) {
                float ov = __shfl_xor(bv, off);
                int oi = __shfl_xor(bi, off);
                if (ov < bv || (ov == bv && oi < bi)) { bv = ov; bi = oi; }
            }
            if (m == 0) {
                int px = mt * 16 + quad * 4 + r;
                bvv[wv][px] = bv;
                bii[wv][px] = bi;
            }
        }
    __syncthreads();
    if (tid < 32) {
        float bv = bvv[0][tid];
        int bi = bii[0][tid];
        #pragma unroll
        for (int w2 = 1; w2 < 4; ++w2) {
            float ov = bvv[w2][tid];
            int oi = bii[w2][tid];
            if (ov < bv || (ov == bv && oi < bi)) { bv = ov; bi = oi; }
        }
        bidx[tid] = bi;
    }
    __syncthreads();

    float lsum = 0.f;
    #pragma unroll
    for (int j = 0; j < 8; ++j) {
        int px = (wv << 3) + j;
        int bi = bidx[px];
        int pix = (bh << 5) + px;
        const float4 e = *(const float4*)&embed[bi * 256 + (lane << 2)];
        const float4 zv = *(const float4*)&zef[(pix << 8) + (lane << 2)];
        ushort4 eq;
        eq.x = f2b(e.x); eq.y = f2b(e.y); eq.z = f2b(e.z); eq.w = f2b(e.w);
        *(ushort4*)&zq[(pix << 8) + (lane << 2)] = eq;
        float dx = zv.x - e.x, dy = zv.y - e.y, dz = zv.z - e.z, dw = zv.w - e.w;
        lsum += dx * dx + dy * dy + dz * dz + dw * dw;
    }
    #pragma unroll
    for (int off = 1; off < 64; off <<= 1) lsum += __shfl_xor(lsum, off);
    if (lane == 0) lpart[(bh << 2) + wv] = lsum;
}

// ======================================================================
// mdec2a: deconv2 pass 1 — Y[B*64*64, 48] = X[.,256] x Wg[256,48]
// ======================================================================
__global__ void __launch_bounds__(256, 4)
mdec2a_k(const unsigned short* __restrict__ in, const unsigned short* __restrict__ wg,
         float* __restrict__ Y)
{
    int tid = threadIdx.x;
    int lane = tid & 63;
    int wv = tid >> 6;
    int m = lane & 15, quad = lane >> 4;
    __shared__ __align__(16) unsigned short win[64 * 264];
    int pxbase = blockIdx.x << 6;
    for (int s = tid; s < 64 * 32; s += 256) {
        int c8 = s & 31, px = s >> 5;
        *(int4*)&win[px * 264 + (c8 << 3)] = *(const int4*)&in[((pxbase + px) << 8) + (c8 << 3)];
    }
    __syncthreads();
    f32x4 acc[3];
    f32x4 z = {0.f, 0.f, 0.f, 0.f};
    acc[0] = z; acc[1] = z; acc[2] = z;
    #pragma unroll
    for (int cch = 0; cch < 8; ++cch) {
        bf16x8 a = *(const bf16x8*)&win[((wv << 4) + m) * 264 + (cch << 5) + (quad << 3)];
        #pragma unroll
        for (int nt = 0; nt < 3; ++nt) {
            bf16x8 b = *(const bf16x8*)&wg[(cch * 48 + nt * 16 + m) * 32 + (quad << 3)];
            acc[nt] = MFMA_B16(a, b, acc[nt]);
        }
    }
    #pragma unroll
    for (int nt = 0; nt < 3; ++nt)
        #pragma unroll
        for (int r = 0; r < 4; ++r) {
            int px = pxbase + (wv << 4) + quad * 4 + r;
            Y[px * 48 + nt * 16 + m] = acc[nt][r];
        }
}

// ======================================================================
// dec2b: deconv2 pass 2 — gather taps, +bias, sigmoid, NCHW out.
// ======================================================================
__global__ void dec2b_k(const float* __restrict__ Y, const float* __restrict__ bias,
                        float* __restrict__ out)
{
    int idx = blockIdx.x * 256 + threadIdx.x;    // < 524288
    int b = idx >> 14;
    int rem = idx & 16383;
    int oy = rem >> 7;
    int ox = rem & 127;
    int p = (oy + 1) & 1;
    int q = (ox + 1) & 1;
    float acc0 = bias[0], acc1 = bias[1], acc2 = bias[2];
    #pragma unroll
    for (int t = 0; t < 2; ++t) {
        int kh = p + 2 * t;
        int ih = (oy + 1 - kh) >> 1;
        if ((unsigned)ih >= 64u) continue;
        #pragma unroll
        for (int u = 0; u < 2; ++u) {
            int kw = q + 2 * u;
            int iw = (ox + 1 - kw) >> 1;
            if ((unsigned)iw >= 64u) continue;
            int base = ((((b << 6) + ih) << 6) + iw) * 48 + ((kh << 2) + kw) * 3;
            acc0 += Y[base];
            acc1 += Y[base + 1];
            acc2 += Y[base + 2];
        }
    }
    int obase = (b * 3 << 14) + (oy << 7) + ox;
    out[obase]           = 1.f / (1.f + expf(-acc0));
    out[obase + 16384]   = 1.f / (1.f + expf(-acc1));
    out[obase + 32768]   = 1.f / (1.f + expf(-acc2));
}

// ======================================================================
extern "C" void kernel_launch(void* const* d_in, const int* in_sizes, int n_in,
                              void* d_out, int out_size, void* d_ws, size_t ws_size,
                              hipStream_t stream)
{
    (void)in_sizes; (void)n_in; (void)out_size; (void)ws_size;
    const float* x      = (const float*)d_in[0];
    const float* embed  = (const float*)d_in[1];
    const float* e_w1   = (const float*)d_in[2];
    const float* e_w2   = (const float*)d_in[3];
    const float* e_r1a  = (const float*)d_in[4];
    const float* e_r1b  = (const float*)d_in[5];
    const float* e_r2a  = (const float*)d_in[6];
    const float* e_r2b  = (const float*)d_in[7];
    const float* d_r1a  = (const float*)d_in[8];
    const float* d_r1b  = (const float*)d_in[9];
    const float* d_r2a  = (const float*)d_in[10];
    const float* d_r2b  = (const float*)d_in[11];
    const float* dt1_w  = (const float*)d_in[12];
    const float* dt1_b  = (const float*)d_in[13];
    const float* dt2_w  = (const float*)d_in[14];
    const float* dt2_b  = (const float*)d_in[15];
    float* outp = (float*)d_out;

    // ---- workspace layout ----
    char* base = (char*)d_ws;
    size_t off = 0;
    auto alloc = [&](size_t bytes) { char* p = base + off; off += (bytes + 255) & ~size_t(255); return p; };
    unsigned short* A0b = (unsigned short*)alloc(67108864);  // (B,64,64,256) bf16
    float*          A1f = (float*)alloc(33554432);           // ze fp32; later Y
    unsigned short* L0  = (unsigned short*)alloc(16777216);
    unsigned short* L1  = (unsigned short*)alloc(16777216);
    unsigned short* L2  = (unsigned short*)alloc(16777216);
    unsigned short* Wf  = (unsigned short*)alloc(9437184);   // 10 frag-ordered weights
    unsigned short* Wg  = (unsigned short*)alloc(24576);     // deconv2 frag weights
    unsigned short* EmbF = (unsigned short*)alloc(262144);   // codebook frag bf16
    unsigned short* WgC = (unsigned short*)alloc(32768);     // conv1 frag weights
    float* Nrm  = (float*)alloc(2048);
    float* Lpart = (float*)alloc(16384);                     // 4096 loss partials
    float* Y = A1f;   // alias: ze dead after vqm_k

    // frag-weight segment offsets inside Wf (element counts)
    unsigned short* Wf_ew2  = Wf;
    unsigned short* Wf_er1a = Wf + 1048576;
    unsigned short* Wf_er1b = Wf + 1638400;
    unsigned short* Wf_er2a = Wf + 1703936;
    unsigned short* Wf_er2b = Wf + 2293760;
    unsigned short* Wf_dr1a = Wf + 2359296;
    unsigned short* Wf_dr1b = Wf + 2949120;
    unsigned short* Wf_dr2a = Wf + 3014656;
    unsigned short* Wf_dr2b = Wf + 3604480;
    unsigned short* Wf_dt1  = Wf + 3670016;

    PermfArgs pa;
    const float* srcs[10] = {e_w2, e_r1a, e_r1b, e_r2a, e_r2b, d_r1a, d_r1b, d_r2a, d_r2b, dt1_w};
    int kws[10] = {4, 3, 1, 3, 1, 3, 1, 3, 1, 4};
    int sos[10] = {4096, 2304, 256, 2304, 256, 2304, 256, 2304, 256, 16};
    int sis[10] = {16, 9, 1, 9, 1, 9, 1, 9, 1, 4096};
    int shs[10] = {4, 3, 0, 3, 0, 3, 0, 3, 0, 4};
    int sws[10] = {1, 1, 0, 1, 0, 1, 0, 1, 0, 1};
    int cums[11] = {0, 1048576, 1638400, 1703936, 2293760, 2359296,
                    2949120, 3014656, 3604480, 3670016, 4718592};
    for (int k = 0; k < 10; ++k) {
        pa.src[k] = srcs[k]; pa.kw[k] = kws[k]; pa.so[k] = sos[k];
        pa.si[k] = sis[k]; pa.sh[k] = shs[k]; pa.sw[k] = sws[k];
        pa.cum[k] = cums[k];
    }
    pa.cum[10] = cums[10];

    permf_all_k<<<18432, 256, 0, stream>>>(pa, Wf);
    misc_prep_k<<<752, 256, 0, stream>>>(dt2_w, Wg, embed, EmbF, e_w1, WgC, Nrm);

    // ---- encoder ----
    conv1m_k<<<32 * 64, 256, 0, stream>>>(x, WgC, A0b);
    mconv2_k<<<32 * 16, 256, 0, stream>>>(A0b, Wf_ew2, L1);                  // h
    mconv3_k<<<32 * 16, 256, 0, stream>>>(L1, Wf_er1a, L2);
    m1x1_k<<<32 * 16, 256, 0, stream>>>(L2, Wf_er1b, L1, L0, nullptr, 0);    // r1 -> L0
    mconv3_k<<<32 * 16, 256, 0, stream>>>(L0, Wf_er2a, L2);
    m1x1_k<<<32 * 16, 256, 0, stream>>>(L2, Wf_er2b, L0, L1, A1f, 1);        // ze: bf16->L1, fp32->A1f

    // ---- VQ ----
    vqm_k<<<32 * 32, 256, 0, stream>>>(L1, A1f, EmbF, embed, Nrm, L1, Lpart);

    // ---- decoder ----
    mconv3_k<<<32 * 16, 256, 0, stream>>>(L1, Wf_dr1a, L2);
    m1x1_k<<<32 * 16, 256, 0, stream>>>(L2, Wf_dr1b, L1, L0, nullptr, 0);    // d1 -> L0
    mconv3_k<<<32 * 16, 256, 0, stream>>>(L0, Wf_dr2a, L2);
    m1x1_k<<<32 * 16, 256, 0, stream>>>(L2, Wf_dr2b, L0, L1, nullptr, 0);    // d2 -> L1
    mdeconv1_k<<<32 * 32, 256, 0, stream>>>(L1, Wf_dt1, dt1_b, A0b);
    mdec2a_k<<<2048, 256, 0, stream>>>(A0b, Wg, Y);
    dec2b_k<<<2048, 256, 0, stream>>>(Y, dt2_b, outp);
    lossfin_k<<<1, 256, 0, stream>>>(Lpart, outp);
}

// Round 10
// 740.226 us; speedup vs baseline: 1.2329x; 1.0359x over previous
//
#include <hip/hip_runtime.h>

// ======================================================================
// VQ-VAE forward, all-MFMA. B=32, CIN=3, IMG=128, D=256, K=512.
// NHWC bf16 activations. M=64 px per block for all 256-ch convs. LDS row
// stride 132/264 shorts. Weights frag-ordered Wf[khkw][cch][n][32].
// MFMA 16x16x32 bf16: A[m=lane&15][k=quad*8+j], B[n][k], D col=lane&15,
// row=quad*4+reg.
// R4: mdeconv1 tb-epilogue (full-line dwordx4 stores) -> out of top-5.
// R6: deterministic loss (Lpart + fixed-order tree). 848 -> 766.8 us.
// R9: residual block FUSED: res3_k = mconv3 -> LDS handoff (ReLU'd
// conv3 out as [64][264] aliased into the 35.9KB staging buffer) ->
// m1x1 + residual add. Kills 4 m1x1 launches + 4x 33.6MB global
// round-trips of the intermediate tensor. LDS unchanged -> 3 blk/CU.
// ======================================================================

typedef __attribute__((ext_vector_type(8))) short bf16x8;
typedef __attribute__((ext_vector_type(4))) float f32x4;
#define MFMA_B16(a, b, c) __builtin_amdgcn_mfma_f32_16x16x32_bf16(a, b, c, 0, 0, 0)

__device__ inline unsigned short f2b(float f) {
    unsigned int u = __float_as_uint(f);
    unsigned int r = u + 0x7fffu + ((u >> 16) & 1u);
    return (unsigned short)(r >> 16);
}
__device__ inline float b2f(unsigned short u) {
    return __uint_as_float(((unsigned int)u) << 16);
}

// ======================================================================
// batched bf16 frag-order weight permute for the 10 conv/deconv weights.
// ======================================================================
struct PermfArgs {
    const float* src[10];
    int kw[10];
    int so[10], si[10], sh[10], sw[10];
    int cum[11];
};

__global__ void permf_all_k(PermfArgs a, unsigned short* __restrict__ dst)
{
    int gid = blockIdx.x * 256 + threadIdx.x;
    if (gid >= a.cum[10]) return;
    int seg = 0;
    while (seg < 9 && gid >= a.cum[seg + 1]) ++seg;
    int l = gid - a.cum[seg];
    int q = l & 31;
    int n = (l >> 5) & 255;
    int rest = l >> 13;
    int cch = rest & 7;
    int khkw = rest >> 3;
    int kh = khkw / a.kw[seg], kw = khkw % a.kw[seg];
    int ci = cch * 32 + q;
    dst[gid] = f2b(a.src[seg][n * a.so[seg] + ci * a.si[seg] + kh * a.sh[seg] + kw * a.sw[seg]]);
}

// ======================================================================
// misc prep: deconv2 frag weights, codebook frag, conv1 frag weights,
// codebook norms. 752 blocks x 256.
// ======================================================================
__global__ void misc_prep_k(const float* __restrict__ dt2_w, unsigned short* __restrict__ wg,
                            const float* __restrict__ embed, unsigned short* __restrict__ embF,
                            const float* __restrict__ e_w1, unsigned short* __restrict__ wgc,
                            float* __restrict__ nrm)
{
    int blk = blockIdx.x, tid = threadIdx.x;
    if (blk < 48) {
        int idx = blk * 256 + tid;        // < 12288
        int q = idx & 31;
        int n = (idx >> 5) % 48;
        int cch = idx / (48 * 32);
        int ci = cch * 32 + q;
        int oc = n % 3, khkw = n / 3;
        int kh = khkw >> 2, kw = khkw & 3;
        wg[idx] = f2b(dt2_w[ci * 48 + oc * 16 + kh * 4 + kw]);
    } else if (blk < 560) {
        int idx = (blk - 48) * 256 + tid; // < 131072
        int q = idx & 31;
        int n = (idx >> 5) & 511;
        int cch = idx >> 14;
        embF[idx] = f2b(embed[n * 256 + cch * 32 + q]);
    } else if (blk < 624) {
        int idx = (blk - 560) * 256 + tid;  // < 16384
        int q = idx & 31;
        int n = (idx >> 5) & 255;
        int kt = idx >> 13;
        int k = kt * 32 + q;
        float v = 0.f;
        if (k < 48) {
            int ci = k >> 4, kh = (k >> 2) & 3, kwv = k & 3;
            v = e_w1[n * 48 + ci * 16 + kh * 4 + kwv];
        }
        wgc[idx] = f2b(v);
    } else {
        int row = (blk - 624) * 4 + (tid >> 6);
        int lane = tid & 63;
        float s = 0.f;
        #pragma unroll
        for (int c = 0; c < 256; c += 64) {
            float v = embed[row * 256 + c + lane];
            s += v * v;
        }
        #pragma unroll
        for (int off = 1; off < 64; off <<= 1) s += __shfl_xor(s, off);
        if (lane == 0) nrm[row] = s;
    }
}

// ======================================================================
// lossfin: deterministic fixed-order reduction of 4096 wave-partials.
// ======================================================================
__global__ void lossfin_k(const float* __restrict__ lpart, float* __restrict__ out)
{
    __shared__ float red[256];
    int tid = threadIdx.x;
    float s = 0.f;
    #pragma unroll
    for (int i = 0; i < 16; ++i) s += lpart[tid * 16 + i];
    red[tid] = s;
    __syncthreads();
    for (int off = 128; off > 0; off >>= 1) {
        if (tid < off) red[tid] += red[tid + off];
        __syncthreads();
    }
    if (tid == 0) {
        float m = red[0] * (1.0f / 32768.0f);
        out[1572864] = m;
        out[1572865] = m;
    }
}

// ======================================================================
// conv1m: MFMA im2col conv1. x NCHW fp32 -> NHWC bf16 (B,64,64,256),
// k4 s2 p1, ReLU. grid = B*64.
// ======================================================================
__global__ void __launch_bounds__(256, 4)
conv1m_k(const float* __restrict__ x, const unsigned short* __restrict__ wgc,
         unsigned short* __restrict__ out)
{
    int bh = blockIdx.x;             // b*64 + oh
    int b = bh >> 6, oh = bh & 63;
    int tid = threadIdx.x;
    int lane = tid & 63, wv = tid >> 6;
    int m = lane & 15, quad = lane >> 4;
    __shared__ float xrow[3][4][130];
    __shared__ __align__(16) unsigned short imc[64 * 72];
    for (int s = tid; s < 1560; s += 256) {
        int col = s % 130;
        int t = s / 130;
        int r = t & 3;
        int c = t >> 2;
        int ih = 2 * oh - 1 + r, iw = col - 1;
        float v = 0.f;
        if ((unsigned)ih < 128u && (unsigned)iw < 128u)
            v = x[(((b * 3 + c) << 7) + ih) * 128 + iw];
        xrow[c][r][col] = v;
    }
    __syncthreads();
    for (int s = tid; s < 4096; s += 256) {
        int px = s >> 6, k = s & 63;
        float v = 0.f;
        if (k < 48) {
            int ci = k >> 4, kh = (k >> 2) & 3, kw = k & 3;
            v = xrow[ci][kh][2 * px + kw];
        }
        imc[px * 72 + k] = f2b(v);
    }
    __syncthreads();
    f32x4 acc[16];
    f32x4 z = {0.f, 0.f, 0.f, 0.f};
    #pragma unroll
    for (int i = 0; i < 16; ++i) acc[i] = z;
    bf16x8 a0 = *(const bf16x8*)&imc[((wv << 4) + m) * 72 + (quad << 3)];
    bf16x8 a1 = *(const bf16x8*)&imc[((wv << 4) + m) * 72 + 32 + (quad << 3)];
    #pragma unroll
    for (int nt = 0; nt < 16; ++nt) {
        bf16x8 b0 = *(const bf16x8*)&wgc[(nt * 16 + m) * 32 + (quad << 3)];
        bf16x8 b1 = *(const bf16x8*)&wgc[(256 + nt * 16 + m) * 32 + (quad << 3)];
        acc[nt] = MFMA_B16(a0, b0, acc[nt]);
        acc[nt] = MFMA_B16(a1, b1, acc[nt]);
    }
    #pragma unroll
    for (int nt = 0; nt < 16; ++nt)
        #pragma unroll
        for (int r = 0; r < 4; ++r) {
            int px = (wv << 4) + quad * 4 + r;
            out[(((bh << 6) + px) << 8) + nt * 16 + (lane & 15)] = f2b(fmaxf(acc[nt][r], 0.f));
        }
}

// ======================================================================
// mconv2: k4 s2 p1, (B,64,64,256)->(B,32,32,256), ReLU. M=64. grid B*16.
// ======================================================================
__global__ void __launch_bounds__(256, 3)
mconv2_k(const unsigned short* __restrict__ in, const unsigned short* __restrict__ wf,
         unsigned short* __restrict__ out)
{
    int blk = blockIdx.x;
    int bb = blk >> 4, j = blk & 15;
    int lane = threadIdx.x & 63;
    int n0 = (threadIdx.x >> 6) << 6;
    int m = lane & 15, quad = lane >> 4;
    __shared__ __align__(16) unsigned short win[2 * 66 * 132];  // 34.8 KB
    f32x4 acc[2][2][4];
    f32x4 z = {0.f, 0.f, 0.f, 0.f};
    #pragma unroll
    for (int a = 0; a < 2; ++a)
        #pragma unroll
        for (int i = 0; i < 2; ++i)
            #pragma unroll
            for (int t = 0; t < 4; ++t) acc[a][i][t] = z;

    for (int c0 = 0; c0 < 256; c0 += 128) {
        for (int kh = 0; kh < 4; ++kh) {
            __syncthreads();
            for (int s = threadIdx.x; s < 2 * 66 * 16; s += 256) {
                int c16 = s & 15;
                int t2 = s >> 4;
                int col = t2 % 66;
                int rr = t2 / 66;
                int ih = 4 * j - 1 + kh + 2 * rr, iw = col - 1;
                int4 v = make_int4(0, 0, 0, 0);
                if ((unsigned)ih < 64u && (unsigned)iw < 64u)
                    v = *(const int4*)&in[((((bb << 6) + ih) << 6) + iw) * 256 + c0 + (c16 << 3)];
                int cs = (col >> 1) + (col & 1) * 33;
                *(int4*)&win[(rr * 66 + cs) * 132 + (c16 << 3)] = v;
            }
            __syncthreads();
            #pragma unroll
            for (int kw = 0; kw < 4; ++kw) {
                int csoff = (kw >> 1) + (kw & 1) * 33;
                #pragma unroll
                for (int cch = 0; cch < 4; ++cch) {
                    bf16x8 a00 = *(const bf16x8*)&win[(m + csoff) * 132 + (cch << 5) + (quad << 3)];
                    bf16x8 a01 = *(const bf16x8*)&win[(m + 16 + csoff) * 132 + (cch << 5) + (quad << 3)];
                    bf16x8 a10 = *(const bf16x8*)&win[(66 + m + csoff) * 132 + (cch << 5) + (quad << 3)];
                    bf16x8 a11 = *(const bf16x8*)&win[(66 + m + 16 + csoff) * 132 + (cch << 5) + (quad << 3)];
                    int cg = (c0 >> 5) + cch;
                    int wbase = ((((kh << 2) + kw) * 8 + cg) * 256 + n0 + m) * 32 + (quad << 3);
                    bf16x8 b0 = *(const bf16x8*)&wf[wbase];
                    bf16x8 b1 = *(const bf16x8*)&wf[wbase + 16 * 32];
                    bf16x8 b2 = *(const bf16x8*)&wf[wbase + 32 * 32];
                    bf16x8 b3 = *(const bf16x8*)&wf[wbase + 48 * 32];
                    acc[0][0][0] = MFMA_B16(a00, b0, acc[0][0][0]);
                    acc[0][0][1] = MFMA_B16(a00, b1, acc[0][0][1]);
                    acc[0][0][2] = MFMA_B16(a00, b2, acc[0][0][2]);
                    acc[0][0][3] = MFMA_B16(a00, b3, acc[0][0][3]);
                    acc[0][1][0] = MFMA_B16(a01, b0, acc[0][1][0]);
                    acc[0][1][1] = MFMA_B16(a01, b1, acc[0][1][1]);
                    acc[0][1][2] = MFMA_B16(a01, b2, acc[0][1][2]);
                    acc[0][1][3] = MFMA_B16(a01, b3, acc[0][1][3]);
                    acc[1][0][0] = MFMA_B16(a10, b0, acc[1][0][0]);
                    acc[1][0][1] = MFMA_B16(a10, b1, acc[1][0][1]);
                    acc[1][0][2] = MFMA_B16(a10, b2, acc[1][0][2]);
                    acc[1][0][3] = MFMA_B16(a10, b3, acc[1][0][3]);
                    acc[1][1][0] = MFMA_B16(a11, b0, acc[1][1][0]);
                    acc[1][1][1] = MFMA_B16(a11, b1, acc[1][1][1]);
                    acc[1][1][2] = MFMA_B16(a11, b2, acc[1][1][2]);
                    acc[1][1][3] = MFMA_B16(a11, b3, acc[1][1][3]);
                }
            }
        }
    }
    #pragma unroll
    for (int row = 0; row < 2; ++row) {
        int oh = 2 * j + row;
        #pragma unroll
        for (int mt = 0; mt < 2; ++mt)
            #pragma unroll
            for (int nt = 0; nt < 4; ++nt)
                #pragma unroll
                for (int r = 0; r < 4; ++r) {
                    int px = mt * 16 + quad * 4 + r;
                    int col = n0 + nt * 16 + m;
                    out[((((bb << 5) + oh) << 5) + px) * 256 + col] = f2b(fmaxf(acc[row][mt][nt][r], 0.f));
                }
    }
}

// ======================================================================
// res3: FUSED residual block (R9). Part 1 = mconv3 (3x3 s1 p1, ReLU)
// with acc in regs; handoff: ReLU'd conv3 output -> LDS [64px][264]
// (aliased over the staging buffer, 33.8 <= 35.9 KB); Part 2 = 1x1
// matmul from LDS + residual add (res == in) -> outb (+ fp32 outf).
// grid = B*16 = 512. LDS 35.9 KB -> 3 blocks/CU.
// ======================================================================
__global__ void __launch_bounds__(256, 3)
res3_k(const unsigned short* __restrict__ in, const unsigned short* __restrict__ wfA,
       const unsigned short* __restrict__ wfB, unsigned short* __restrict__ outb,
       float* __restrict__ outf, int f32out)
{
    int blk = blockIdx.x;
    int bb = blk >> 4, j = blk & 15;      // out rows 2j, 2j+1
    int tid = threadIdx.x;
    int lane = tid & 63;
    int n0 = (tid >> 6) << 6;
    int m = lane & 15, quad = lane >> 4;
    __shared__ __align__(16) unsigned short win[4 * 34 * 132];  // 35.9 KB (>= 64*264 for handoff)
    f32x4 acc[2][2][4];
    f32x4 z = {0.f, 0.f, 0.f, 0.f};
    #pragma unroll
    for (int a = 0; a < 2; ++a)
        #pragma unroll
        for (int i = 0; i < 2; ++i)
            #pragma unroll
            for (int t = 0; t < 4; ++t) acc[a][i][t] = z;

    // ---- part 1: 3x3 conv (identical to verified mconv3) ----
    for (int c0 = 0; c0 < 256; c0 += 128) {
        __syncthreads();
        for (int s = tid; s < 4 * 34 * 16; s += 256) {
            int c16 = s & 15;
            int t2 = s >> 4;
            int col = t2 % 34;
            int rr = t2 / 34;
            int ih = 2 * j - 1 + rr, iw = col - 1;
            int4 v = make_int4(0, 0, 0, 0);
            if ((unsigned)ih < 32u && (unsigned)iw < 32u)
                v = *(const int4*)&in[((((bb << 5) + ih) << 5) + iw) * 256 + c0 + (c16 << 3)];
            *(int4*)&win[(rr * 34 + col) * 132 + (c16 << 3)] = v;
        }
        __syncthreads();
        for (int kh = 0; kh < 3; ++kh) {
            #pragma unroll
            for (int kw = 0; kw < 3; ++kw) {
                #pragma unroll
                for (int cch = 0; cch < 4; ++cch) {
                    const unsigned short* ba = &win[(kh * 34 + m + kw) * 132 + (cch << 5) + (quad << 3)];
                    bf16x8 a00 = *(const bf16x8*)ba;
                    bf16x8 a01 = *(const bf16x8*)(ba + 16 * 132);
                    bf16x8 a10 = *(const bf16x8*)(ba + 34 * 132);
                    bf16x8 a11 = *(const bf16x8*)(ba + 50 * 132);
                    int cg = (c0 >> 5) + cch;
                    int wbase = (((kh * 3 + kw) * 8 + cg) * 256 + n0 + m) * 32 + (quad << 3);
                    bf16x8 b0 = *(const bf16x8*)&wfA[wbase];
                    bf16x8 b1 = *(const bf16x8*)&wfA[wbase + 16 * 32];
                    bf16x8 b2 = *(const bf16x8*)&wfA[wbase + 32 * 32];
                    bf16x8 b3 = *(const bf16x8*)&wfA[wbase + 48 * 32];
                    acc[0][0][0] = MFMA_B16(a00, b0, acc[0][0][0]);
                    acc[0][0][1] = MFMA_B16(a00, b1, acc[0][0][1]);
                    acc[0][0][2] = MFMA_B16(a00, b2, acc[0][0][2]);
                    acc[0][0][3] = MFMA_B16(a00, b3, acc[0][0][3]);
                    acc[0][1][0] = MFMA_B16(a01, b0, acc[0][1][0]);
                    acc[0][1][1] = MFMA_B16(a01, b1, acc[0][1][1]);
                    acc[0][1][2] = MFMA_B16(a01, b2, acc[0][1][2]);
                    acc[0][1][3] = MFMA_B16(a01, b3, acc[0][1][3]);
                    acc[1][0][0] = MFMA_B16(a10, b0, acc[1][0][0]);
                    acc[1][0][1] = MFMA_B16(a10, b1, acc[1][0][1]);
                    acc[1][0][2] = MFMA_B16(a10, b2, acc[1][0][2]);
                    acc[1][0][3] = MFMA_B16(a10, b3, acc[1][0][3]);
                    acc[1][1][0] = MFMA_B16(a11, b0, acc[1][1][0]);
                    acc[1][1][1] = MFMA_B16(a11, b1, acc[1][1][1]);
                    acc[1][1][2] = MFMA_B16(a11, b2, acc[1][1][2]);
                    acc[1][1][3] = MFMA_B16(a11, b3, acc[1][1][3]);
                }
            }
        }
    }

    // ---- handoff: ReLU(conv3) -> LDS [64][264] (alias over win) ----
    __syncthreads();   // all waves done reading win
    #pragma unroll
    for (int row = 0; row < 2; ++row)
        #pragma unroll
        for (int mt = 0; mt < 2; ++mt)
            #pragma unroll
            for (int nt = 0; nt < 4; ++nt)
                #pragma unroll
                for (int r = 0; r < 4; ++r) {
                    int p = row * 32 + mt * 16 + quad * 4 + r;
                    win[p * 264 + n0 + nt * 16 + m] = f2b(fmaxf(acc[row][mt][nt][r], 0.f));
                }
    __syncthreads();   // handoff complete

    // ---- part 2: 1x1 matmul from LDS + residual (identical to m1x1) ----
    f32x4 acc2[4][4];
    #pragma unroll
    for (int i = 0; i < 4; ++i)
        #pragma unroll
        for (int t = 0; t < 4; ++t) acc2[i][t] = z;

    #pragma unroll
    for (int cch = 0; cch < 8; ++cch) {
        bf16x8 a0 = *(const bf16x8*)&win[m * 264 + (cch << 5) + (quad << 3)];
        bf16x8 a1 = *(const bf16x8*)&win[(m + 16) * 264 + (cch << 5) + (quad << 3)];
        bf16x8 a2 = *(const bf16x8*)&win[(m + 32) * 264 + (cch << 5) + (quad << 3)];
        bf16x8 a3 = *(const bf16x8*)&win[(m + 48) * 264 + (cch << 5) + (quad << 3)];
        int wbase = (cch * 256 + n0 + m) * 32 + (quad << 3);
        bf16x8 b0 = *(const bf16x8*)&wfB[wbase];
        bf16x8 b1 = *(const bf16x8*)&wfB[wbase + 16 * 32];
        bf16x8 b2 = *(const bf16x8*)&wfB[wbase + 32 * 32];
        bf16x8 b3 = *(const bf16x8*)&wfB[wbase + 48 * 32];
        acc2[0][0] = MFMA_B16(a0, b0, acc2[0][0]);
        acc2[0][1] = MFMA_B16(a0, b1, acc2[0][1]);
        acc2[0][2] = MFMA_B16(a0, b2, acc2[0][2]);
        acc2[0][3] = MFMA_B16(a0, b3, acc2[0][3]);
        acc2[1][0] = MFMA_B16(a1, b0, acc2[1][0]);
        acc2[1][1] = MFMA_B16(a1, b1, acc2[1][1]);
        acc2[1][2] = MFMA_B16(a1, b2, acc2[1][2]);
        acc2[1][3] = MFMA_B16(a1, b3, acc2[1][3]);
        acc2[2][0] = MFMA_B16(a2, b0, acc2[2][0]);
        acc2[2][1] = MFMA_B16(a2, b1, acc2[2][1]);
        acc2[2][2] = MFMA_B16(a2, b2, acc2[2][2]);
        acc2[2][3] = MFMA_B16(a2, b3, acc2[2][3]);
        acc2[3][0] = MFMA_B16(a3, b0, acc2[3][0]);
        acc2[3][1] = MFMA_B16(a3, b1, acc2[3][1]);
        acc2[3][2] = MFMA_B16(a3, b2, acc2[3][2]);
        acc2[3][3] = MFMA_B16(a3, b3, acc2[3][3]);
    }
    int rowbase = blk << 14;   // 64 px * 256
    #pragma unroll
    for (int mt = 0; mt < 4; ++mt)
        #pragma unroll
        for (int nt = 0; nt < 4; ++nt)
            #pragma unroll
            for (int r = 0; r < 4; ++r) {
                int px = mt * 16 + quad * 4 + r;
                int col = n0 + nt * 16 + m;
                int idx = rowbase + (px << 8) + col;
                float v = acc2[mt][nt][r] + b2f(in[idx]);
                outb[idx] = f2b(v);
                if (f32out) outf[idx] = v;
            }
}

// ======================================================================
// mdeconv1: ConvTranspose2d(256->256,k4,s2,p1)+bias+ReLU. R1 2-row
// structure + R4 tb-epilogue (full-line dwordx4 stores). grid = 1024.
// ======================================================================
__global__ void __launch_bounds__(256, 3)
mdeconv1_k(const unsigned short* __restrict__ in, const unsigned short* __restrict__ wf,
           const float* __restrict__ bias, unsigned short* __restrict__ out)
{
    int blk = blockIdx.x;
    int bb = blk >> 5;
    int rem = blk & 31;
    int pp = rem >> 4;
    int i = rem & 15;
    int oy_a = pp + 4 * i;
    int p = (oy_a + 1) & 1;
    int r0a = (oy_a + 1 - p) >> 1;
    int rbase = r0a - 1;
    int tid = threadIdx.x;
    int lane = tid & 63;
    int n0 = (tid >> 6) << 6;
    int m = lane & 15, quad = lane >> 4;
    __shared__ __align__(16) unsigned short win[3 * 34 * 264];   // 53.9 KB
    __shared__ __align__(16) unsigned short tb[16 * 264];        // 8.4 KB

    for (int s = tid; s < 3 * 34 * 32; s += 256) {
        int c8 = s & 31;
        int t2 = s >> 5;
        int col = t2 % 34;
        int rr = t2 / 34;
        int ih = rbase + rr, iw = col - 1;
        int4 v = make_int4(0, 0, 0, 0);
        if ((unsigned)ih < 32u && (unsigned)iw < 32u)
            v = *(const int4*)&in[((((bb << 5) + ih) << 5) + iw) * 256 + (c8 << 3)];
        *(int4*)&win[(rr * 34 + col) * 264 + (c8 << 3)] = v;
    }
    __syncthreads();

    for (int par = 0; par < 2; ++par) {
        f32x4 acc[2][2][4];
        f32x4 z = {0.f, 0.f, 0.f, 0.f};
        #pragma unroll
        for (int a = 0; a < 2; ++a)
            #pragma unroll
            for (int i2 = 0; i2 < 2; ++i2)
                #pragma unroll
                for (int t = 0; t < 4; ++t) acc[a][i2][t] = z;

        #pragma unroll
        for (int t = 0; t < 2; ++t) {
            int kh = p + 2 * t;
            #pragma unroll
            for (int u = 0; u < 2; ++u) {
                int kw = (1 - par) + 2 * u;
                int ixoff = par - u + 1;
                #pragma unroll
                for (int cch = 0; cch < 8; ++cch) {
                    const unsigned short* baA = &win[((1 - t) * 34 + m + ixoff) * 264 + (cch << 5) + (quad << 3)];
                    const unsigned short* baB = baA + 34 * 264;
                    bf16x8 a00 = *(const bf16x8*)baA;
                    bf16x8 a01 = *(const bf16x8*)(baA + 16 * 264);
                    bf16x8 a10 = *(const bf16x8*)baB;
                    bf16x8 a11 = *(const bf16x8*)(baB + 16 * 264);
                    int wbase = ((((kh << 2) + kw) * 8 + cch) * 256 + n0 + m) * 32 + (quad << 3);
                    bf16x8 b0 = *(const bf16x8*)&wf[wbase];
                    bf16x8 b1 = *(const bf16x8*)&wf[wbase + 16 * 32];
                    bf16x8 b2 = *(const bf16x8*)&wf[wbase + 32 * 32];
                    bf16x8 b3 = *(const bf16x8*)&wf[wbase + 48 * 32];
                    acc[0][0][0] = MFMA_B16(a00, b0, acc[0][0][0]);
                    acc[0][0][1] = MFMA_B16(a00, b1, acc[0][0][1]);
                    acc[0][0][2] = MFMA_B16(a00, b2, acc[0][0][2]);
                    acc[0][0][3] = MFMA_B16(a00, b3, acc[0][0][3]);
                    acc[0][1][0] = MFMA_B16(a01, b0, acc[0][1][0]);
                    acc[0][1][1] = MFMA_B16(a01, b1, acc[0][1][1]);
                    acc[0][1][2] = MFMA_B16(a01, b2, acc[0][1][2]);
                    acc[0][1][3] = MFMA_B16(a01, b3, acc[0][1][3]);
                    acc[1][0][0] = MFMA_B16(a10, b0, acc[1][0][0]);
                    acc[1][0][1] = MFMA_B16(a10, b1, acc[1][0][1]);
                    acc[1][0][2] = MFMA_B16(a10, b2, acc[1][0][2]);
                    acc[1][0][3] = MFMA_B16(a10, b3, acc[1][0][3]);
                    acc[1][1][0] = MFMA_B16(a11, b0, acc[1][1][0]);
                    acc[1][1][1] = MFMA_B16(a11, b1, acc[1][1][1]);
                    acc[1][1][2] = MFMA_B16(a11, b2, acc[1][1][2]);
                    acc[1][1][3] = MFMA_B16(a11, b3, acc[1][1][3]);
                }
            }
        }

        #pragma unroll
        for (int row = 0; row < 2; ++row) {
            int oy = oy_a + 2 * row;
            #pragma unroll
            for (int mt = 0; mt < 2; ++mt) {
                __syncthreads();
                #pragma unroll
                for (int nt = 0; nt < 4; ++nt) {
                    float bs = bias[n0 + nt * 16 + m];
                    #pragma unroll
                    for (int rr = 0; rr < 4; ++rr) {
                        float v = fmaxf(acc[row][mt][nt][rr] + bs, 0.f);
                        tb[(quad * 4 + rr) * 264 + n0 + nt * 16 + m] = f2b(v);
                    }
                }
                __syncthreads();
                #pragma unroll
                for (int k = 0; k < 2; ++k) {
                    int s = tid + k * 256;
                    int pxl = s >> 5;
                    int c8 = s & 31;
                    int ox = 2 * (mt * 16 + pxl) + par;
                    *(int4*)&out[((((bb << 6) + oy) << 6) + ox) * 256 + (c8 << 3)] =
                        *(const int4*)&tb[pxl * 264 + (c8 << 3)];
                }
            }
        }
    }
}

// ======================================================================
// vqm: MFMA VQ + exact fp32 gather/loss. grid = B*32. Deterministic
// loss partials to lpart[bh*4+wv].
// ======================================================================
__global__ void __launch_bounds__(256, 2)
vqm_k(const unsigned short* __restrict__ zeb, const float* __restrict__ zef,
      const unsigned short* __restrict__ embF, const float* __restrict__ embed,
      const float* __restrict__ nrm, unsigned short* __restrict__ zq,
      float* __restrict__ lpart)
{
    int bh = blockIdx.x;
    int tid = threadIdx.x;
    int lane = tid & 63;
    int wv = tid >> 6;
    int m = lane & 15, quad = lane >> 4;
    __shared__ __align__(16) unsigned short win[32 * 264];
    __shared__ float bvv[4][32];
    __shared__ int   bii[4][32];
    __shared__ int   bidx[32];
    int rowbase = bh << 13;
    for (int s = tid; s < 32 * 32; s += 256) {
        int c8 = s & 31, px = s >> 5;
        *(int4*)&win[px * 264 + (c8 << 3)] = *(const int4*)&zeb[rowbase + (px << 8) + (c8 << 3)];
    }
    __syncthreads();

    f32x4 acc[2][8];
    f32x4 z = {0.f, 0.f, 0.f, 0.f};
    #pragma unroll
    for (int i = 0; i < 2; ++i)
        #pragma unroll
        for (int j = 0; j < 8; ++j) acc[i][j] = z;

    #pragma unroll
    for (int cch = 0; cch < 8; ++cch) {
        bf16x8 a0 = *(const bf16x8*)&win[m * 264 + (cch << 5) + (quad << 3)];
        bf16x8 a1 = *(const bf16x8*)&win[(m + 16) * 264 + (cch << 5) + (quad << 3)];
        #pragma unroll
        for (int nt = 0; nt < 8; ++nt) {
            bf16x8 b = *(const bf16x8*)&embF[((cch << 9) + (wv << 7) + (nt << 4) + m) * 32 + (quad << 3)];
            acc[0][nt] = MFMA_B16(a0, b, acc[0][nt]);
            acc[1][nt] = MFMA_B16(a1, b, acc[1][nt]);
        }
    }

    float nv[8];
    #pragma unroll
    for (int nt = 0; nt < 8; ++nt) nv[nt] = nrm[(wv << 7) + (nt << 4) + m];

    #pragma unroll
    for (int mt = 0; mt < 2; ++mt)
        #pragma unroll
        for (int r = 0; r < 4; ++r) {
            float bv = 1e30f;
            int bi = 0x7fffffff;
            #pragma unroll
            for (int nt = 0; nt < 8; ++nt) {
                float d = nv[nt] - 2.f * acc[mt][nt][r];
                int n = (wv << 7) + (nt << 4) + m;
                if (d < bv || (d == bv && n < bi)) { bv = d; bi = n; }
            }
            #pragma unroll
            for (int off = 1; off < 16; off <<= 1) {
                float ov = __shfl_xor(bv, off);
                int oi = __shfl_xor(bi, off);
                if (ov < bv || (ov == bv && oi < bi)) { bv = ov; bi = oi; }
            }
            if (m == 0) {
                int px = mt * 16 + quad * 4 + r;
                bvv[wv][px] = bv;
                bii[wv][px] = bi;
            }
        }
    __syncthreads();
    if (tid < 32) {
        float bv = bvv[0][tid];
        int bi = bii[0][tid];
        #pragma unroll
        for (int w2 = 1; w2 < 4; ++w2) {
            float ov = bvv[w2][tid];
            int oi = bii[w2][tid];
            if (ov < bv || (ov == bv && oi < bi)) { bv = ov; bi = oi; }
        }
        bidx[tid] = bi;
    }
    __syncthreads();

    float lsum = 0.f;
    #pragma unroll
    for (int j = 0; j < 8; ++j) {
        int px = (wv << 3) + j;
        int bi = bidx[px];
        int pix = (bh << 5) + px;
        const float4 e = *(const float4*)&embed[bi * 256 + (lane << 2)];
        const float4 zv = *(const float4*)&zef[(pix << 8) + (lane << 2)];
        ushort4 eq;
        eq.x = f2b(e.x); eq.y = f2b(e.y); eq.z = f2b(e.z); eq.w = f2b(e.w);
        *(ushort4*)&zq[(pix << 8) + (lane << 2)] = eq;
        float dx = zv.x - e.x, dy = zv.y - e.y, dz = zv.z - e.z, dw = zv.w - e.w;
        lsum += dx * dx + dy * dy + dz * dz + dw * dw;
    }
    #pragma unroll
    for (int off = 1; off < 64; off <<= 1) lsum += __shfl_xor(lsum, off);
    if (lane == 0) lpart[(bh << 2) + wv] = lsum;
}

// ======================================================================
// mdec2a: deconv2 pass 1 — Y[B*64*64, 48] = X[.,256] x Wg[256,48]
// ======================================================================
__global__ void __launch_bounds__(256, 4)
mdec2a_k(const unsigned short* __restrict__ in, const unsigned short* __restrict__ wg,
         float* __restrict__ Y)
{
    int tid = threadIdx.x;
    int lane = tid & 63;
    int wv = tid >> 6;
    int m = lane & 15, quad = lane >> 4;
    __shared__ __align__(16) unsigned short win[64 * 264];
    int pxbase = blockIdx.x << 6;
    for (int s = tid; s < 64 * 32; s += 256) {
        int c8 = s & 31, px = s >> 5;
        *(int4*)&win[px * 264 + (c8 << 3)] = *(const int4*)&in[((pxbase + px) << 8) + (c8 << 3)];
    }
    __syncthreads();
    f32x4 acc[3];
    f32x4 z = {0.f, 0.f, 0.f, 0.f};
    acc[0] = z; acc[1] = z; acc[2] = z;
    #pragma unroll
    for (int cch = 0; cch < 8; ++cch) {
        bf16x8 a = *(const bf16x8*)&win[((wv << 4) + m) * 264 + (cch << 5) + (quad << 3)];
        #pragma unroll
        for (int nt = 0; nt < 3; ++nt) {
            bf16x8 b = *(const bf16x8*)&wg[(cch * 48 + nt * 16 + m) * 32 + (quad << 3)];
            acc[nt] = MFMA_B16(a, b, acc[nt]);
        }
    }
    #pragma unroll
    for (int nt = 0; nt < 3; ++nt)
        #pragma unroll
        for (int r = 0; r < 4; ++r) {
            int px = pxbase + (wv << 4) + quad * 4 + r;
            Y[px * 48 + nt * 16 + m] = acc[nt][r];
        }
}

// ======================================================================
// dec2b: deconv2 pass 2 — gather taps, +bias, sigmoid, NCHW out.
// ======================================================================
__global__ void dec2b_k(const float* __restrict__ Y, const float* __restrict__ bias,
                        float* __restrict__ out)
{
    int idx = blockIdx.x * 256 + threadIdx.x;    // < 524288
    int b = idx >> 14;
    int rem = idx & 16383;
    int oy = rem >> 7;
    int ox = rem & 127;
    int p = (oy + 1) & 1;
    int q = (ox + 1) & 1;
    float acc0 = bias[0], acc1 = bias[1], acc2 = bias[2];
    #pragma unroll
    for (int t = 0; t < 2; ++t) {
        int kh = p + 2 * t;
        int ih = (oy + 1 - kh) >> 1;
        if ((unsigned)ih >= 64u) continue;
        #pragma unroll
        for (int u = 0; u < 2; ++u) {
            int kw = q + 2 * u;
            int iw = (ox + 1 - kw) >> 1;
            if ((unsigned)iw >= 64u) continue;
            int base = ((((b << 6) + ih) << 6) + iw) * 48 + ((kh << 2) + kw) * 3;
            acc0 += Y[base];
            acc1 += Y[base + 1];
            acc2 += Y[base + 2];
        }
    }
    int obase = (b * 3 << 14) + (oy << 7) + ox;
    out[obase]           = 1.f / (1.f + expf(-acc0));
    out[obase + 16384]   = 1.f / (1.f + expf(-acc1));
    out[obase + 32768]   = 1.f / (1.f + expf(-acc2));
}

// ======================================================================
extern "C" void kernel_launch(void* const* d_in, const int* in_sizes, int n_in,
                              void* d_out, int out_size, void* d_ws, size_t ws_size,
                              hipStream_t stream)
{
    (void)in_sizes; (void)n_in; (void)out_size; (void)ws_size;
    const float* x      = (const float*)d_in[0];
    const float* embed  = (const float*)d_in[1];
    const float* e_w1   = (const float*)d_in[2];
    const float* e_w2   = (const float*)d_in[3];
    const float* e_r1a  = (const float*)d_in[4];
    const float* e_r1b  = (const float*)d_in[5];
    const float* e_r2a  = (const float*)d_in[6];
    const float* e_r2b  = (const float*)d_in[7];
    const float* d_r1a  = (const float*)d_in[8];
    const float* d_r1b  = (const float*)d_in[9];
    const float* d_r2a  = (const float*)d_in[10];
    const float* d_r2b  = (const float*)d_in[11];
    const float* dt1_w  = (const float*)d_in[12];
    const float* dt1_b  = (const float*)d_in[13];
    const float* dt2_w  = (const float*)d_in[14];
    const float* dt2_b  = (const float*)d_in[15];
    float* outp = (float*)d_out;

    // ---- workspace layout ----
    char* base = (char*)d_ws;
    size_t off = 0;
    auto alloc = [&](size_t bytes) { char* p = base + off; off += (bytes + 255) & ~size_t(255); return p; };
    unsigned short* A0b = (unsigned short*)alloc(67108864);  // (B,64,64,256) bf16
    float*          A1f = (float*)alloc(33554432);           // ze fp32; later Y
    unsigned short* L0  = (unsigned short*)alloc(16777216);
    unsigned short* L1  = (unsigned short*)alloc(16777216);
    unsigned short* L2  = (unsigned short*)alloc(16777216);  // (unused after R9 fusion; kept)
    unsigned short* Wf  = (unsigned short*)alloc(9437184);   // 10 frag-ordered weights
    unsigned short* Wg  = (unsigned short*)alloc(24576);     // deconv2 frag weights
    unsigned short* EmbF = (unsigned short*)alloc(262144);   // codebook frag bf16
    unsigned short* WgC = (unsigned short*)alloc(32768);     // conv1 frag weights
    float* Nrm  = (float*)alloc(2048);
    float* Lpart = (float*)alloc(16384);                     // 4096 loss partials
    float* Y = A1f;   // alias: ze dead after vqm_k
    (void)L2;

    // frag-weight segment offsets inside Wf (element counts)
    unsigned short* Wf_ew2  = Wf;
    unsigned short* Wf_er1a = Wf + 1048576;
    unsigned short* Wf_er1b = Wf + 1638400;
    unsigned short* Wf_er2a = Wf + 1703936;
    unsigned short* Wf_er2b = Wf + 2293760;
    unsigned short* Wf_dr1a = Wf + 2359296;
    unsigned short* Wf_dr1b = Wf + 2949120;
    unsigned short* Wf_dr2a = Wf + 3014656;
    unsigned short* Wf_dr2b = Wf + 3604480;
    unsigned short* Wf_dt1  = Wf + 3670016;

    PermfArgs pa;
    const float* srcs[10] = {e_w2, e_r1a, e_r1b, e_r2a, e_r2b, d_r1a, d_r1b, d_r2a, d_r2b, dt1_w};
    int kws[10] = {4, 3, 1, 3, 1, 3, 1, 3, 1, 4};
    int sos[10] = {4096, 2304, 256, 2304, 256, 2304, 256, 2304, 256, 16};
    int sis[10] = {16, 9, 1, 9, 1, 9, 1, 9, 1, 4096};
    int shs[10] = {4, 3, 0, 3, 0, 3, 0, 3, 0, 4};
    int sws[10] = {1, 1, 0, 1, 0, 1, 0, 1, 0, 1};
    int cums[11] = {0, 1048576, 1638400, 1703936, 2293760, 2359296,
                    2949120, 3014656, 3604480, 3670016, 4718592};
    for (int k = 0; k < 10; ++k) {
        pa.src[k] = srcs[k]; pa.kw[k] = kws[k]; pa.so[k] = sos[k];
        pa.si[k] = sis[k]; pa.sh[k] = shs[k]; pa.sw[k] = sws[k];
        pa.cum[k] = cums[k];
    }
    pa.cum[10] = cums[10];

    permf_all_k<<<18432, 256, 0, stream>>>(pa, Wf);
    misc_prep_k<<<752, 256, 0, stream>>>(dt2_w, Wg, embed, EmbF, e_w1, WgC, Nrm);

    // ---- encoder ----
    conv1m_k<<<32 * 64, 256, 0, stream>>>(x, WgC, A0b);
    mconv2_k<<<32 * 16, 256, 0, stream>>>(A0b, Wf_ew2, L1);                      // h
    res3_k<<<32 * 16, 256, 0, stream>>>(L1, Wf_er1a, Wf_er1b, L0, nullptr, 0);   // r1 -> L0
    res3_k<<<32 * 16, 256, 0, stream>>>(L0, Wf_er2a, Wf_er2b, L1, A1f, 1);       // ze: bf16->L1, fp32->A1f

    // ---- VQ ----
    vqm_k<<<32 * 32, 256, 0, stream>>>(L1, A1f, EmbF, embed, Nrm, L1, Lpart);

    // ---- decoder ----
    res3_k<<<32 * 16, 256, 0, stream>>>(L1, Wf_dr1a, Wf_dr1b, L0, nullptr, 0);   // d1 -> L0
    res3_k<<<32 * 16, 256, 0, stream>>>(L0, Wf_dr2a, Wf_dr2b, L1, nullptr, 0);   // d2 -> L1
    mdeconv1_k<<<32 * 32, 256, 0, stream>>>(L1, Wf_dt1, dt1_b, A0b);
    mdec2a_k<<<2048, 256, 0, stream>>>(A0b, Wg, Y);
    dec2b_k<<<2048, 256, 0, stream>>>(Y, dt2_b, outp);
    lossfin_k<<<1, 256, 0, stream>>>(Lpart, outp);
}

// Round 11
// 718.903 us; speedup vs baseline: 1.2694x; 1.0297x over previous
//
#include <hip/hip_runtime.h>

// ======================================================================
// VQ-VAE forward, all-MFMA. B=32, CIN=3, IMG=128, D=256, K=512.
// NHWC bf16 activations. M=64 px per block for all 256-ch convs. LDS row
// stride 132/264 shorts. Weights frag-ordered Wf[khkw][cch][n][32].
// MFMA 16x16x32 bf16: A[m=lane&15][k=quad*8+j], B[n][k], D col=lane&15,
// row=quad*4+reg.
// R4: mdeconv1 tb-epilogue (full-line dwordx4 stores) -> out of top-5.
// R6: deterministic loss. R9: fused residual block (res3_k). 740.2 us.
// R11: res3 epilogue v2 — acc2 spilled fp32 to LDS (2 halves of 32px,
// 33.3KB aliased over win), then coalesced int4 residual read + add +
// full-line int4/float4 stores. R10's interleaved scattered 2B
// reads+writes churned L2 (WRITE 99.8MB = 6x ideal, partial-line
// evict/refetch); dense full-line window fixes it. Bit-identical math.
// ======================================================================

typedef __attribute__((ext_vector_type(8))) short bf16x8;
typedef __attribute__((ext_vector_type(4))) float f32x4;
#define MFMA_B16(a, b, c) __builtin_amdgcn_mfma_f32_16x16x32_bf16(a, b, c, 0, 0, 0)

__device__ inline unsigned short f2b(float f) {
    unsigned int u = __float_as_uint(f);
    unsigned int r = u + 0x7fffu + ((u >> 16) & 1u);
    return (unsigned short)(r >> 16);
}
__device__ inline float b2f(unsigned short u) {
    return __uint_as_float(((unsigned int)u) << 16);
}

// ======================================================================
// batched bf16 frag-order weight permute for the 10 conv/deconv weights.
// ======================================================================
struct PermfArgs {
    const float* src[10];
    int kw[10];
    int so[10], si[10], sh[10], sw[10];
    int cum[11];
};

__global__ void permf_all_k(PermfArgs a, unsigned short* __restrict__ dst)
{
    int gid = blockIdx.x * 256 + threadIdx.x;
    if (gid >= a.cum[10]) return;
    int seg = 0;
    while (seg < 9 && gid >= a.cum[seg + 1]) ++seg;
    int l = gid - a.cum[seg];
    int q = l & 31;
    int n = (l >> 5) & 255;
    int rest = l >> 13;
    int cch = rest & 7;
    int khkw = rest >> 3;
    int kh = khkw / a.kw[seg], kw = khkw % a.kw[seg];
    int ci = cch * 32 + q;
    dst[gid] = f2b(a.src[seg][n * a.so[seg] + ci * a.si[seg] + kh * a.sh[seg] + kw * a.sw[seg]]);
}

// ======================================================================
// misc prep: deconv2 frag weights, codebook frag, conv1 frag weights,
// codebook norms. 752 blocks x 256.
// ======================================================================
__global__ void misc_prep_k(const float* __restrict__ dt2_w, unsigned short* __restrict__ wg,
                            const float* __restrict__ embed, unsigned short* __restrict__ embF,
                            const float* __restrict__ e_w1, unsigned short* __restrict__ wgc,
                            float* __restrict__ nrm)
{
    int blk = blockIdx.x, tid = threadIdx.x;
    if (blk < 48) {
        int idx = blk * 256 + tid;        // < 12288
        int q = idx & 31;
        int n = (idx >> 5) % 48;
        int cch = idx / (48 * 32);
        int ci = cch * 32 + q;
        int oc = n % 3, khkw = n / 3;
        int kh = khkw >> 2, kw = khkw & 3;
        wg[idx] = f2b(dt2_w[ci * 48 + oc * 16 + kh * 4 + kw]);
    } else if (blk < 560) {
        int idx = (blk - 48) * 256 + tid; // < 131072
        int q = idx & 31;
        int n = (idx >> 5) & 511;
        int cch = idx >> 14;
        embF[idx] = f2b(embed[n * 256 + cch * 32 + q]);
    } else if (blk < 624) {
        int idx = (blk - 560) * 256 + tid;  // < 16384
        int q = idx & 31;
        int n = (idx >> 5) & 255;
        int kt = idx >> 13;
        int k = kt * 32 + q;
        float v = 0.f;
        if (k < 48) {
            int ci = k >> 4, kh = (k >> 2) & 3, kwv = k & 3;
            v = e_w1[n * 48 + ci * 16 + kh * 4 + kwv];
        }
        wgc[idx] = f2b(v);
    } else {
        int row = (blk - 624) * 4 + (tid >> 6);
        int lane = tid & 63;
        float s = 0.f;
        #pragma unroll
        for (int c = 0; c < 256; c += 64) {
            float v = embed[row * 256 + c + lane];
            s += v * v;
        }
        #pragma unroll
        for (int off = 1; off < 64; off <<= 1) s += __shfl_xor(s, off);
        if (lane == 0) nrm[row] = s;
    }
}

// ======================================================================
// lossfin: deterministic fixed-order reduction of 4096 wave-partials.
// ======================================================================
__global__ void lossfin_k(const float* __restrict__ lpart, float* __restrict__ out)
{
    __shared__ float red[256];
    int tid = threadIdx.x;
    float s = 0.f;
    #pragma unroll
    for (int i = 0; i < 16; ++i) s += lpart[tid * 16 + i];
    red[tid] = s;
    __syncthreads();
    for (int off = 128; off > 0; off >>= 1) {
        if (tid < off) red[tid] += red[tid + off];
        __syncthreads();
    }
    if (tid == 0) {
        float m = red[0] * (1.0f / 32768.0f);
        out[1572864] = m;
        out[1572865] = m;
    }
}

// ======================================================================
// conv1m: MFMA im2col conv1. x NCHW fp32 -> NHWC bf16 (B,64,64,256),
// k4 s2 p1, ReLU. grid = B*64.
// ======================================================================
__global__ void __launch_bounds__(256, 4)
conv1m_k(const float* __restrict__ x, const unsigned short* __restrict__ wgc,
         unsigned short* __restrict__ out)
{
    int bh = blockIdx.x;             // b*64 + oh
    int b = bh >> 6, oh = bh & 63;
    int tid = threadIdx.x;
    int lane = tid & 63, wv = tid >> 6;
    int m = lane & 15, quad = lane >> 4;
    __shared__ float xrow[3][4][130];
    __shared__ __align__(16) unsigned short imc[64 * 72];
    for (int s = tid; s < 1560; s += 256) {
        int col = s % 130;
        int t = s / 130;
        int r = t & 3;
        int c = t >> 2;
        int ih = 2 * oh - 1 + r, iw = col - 1;
        float v = 0.f;
        if ((unsigned)ih < 128u && (unsigned)iw < 128u)
            v = x[(((b * 3 + c) << 7) + ih) * 128 + iw];
        xrow[c][r][col] = v;
    }
    __syncthreads();
    for (int s = tid; s < 4096; s += 256) {
        int px = s >> 6, k = s & 63;
        float v = 0.f;
        if (k < 48) {
            int ci = k >> 4, kh = (k >> 2) & 3, kw = k & 3;
            v = xrow[ci][kh][2 * px + kw];
        }
        imc[px * 72 + k] = f2b(v);
    }
    __syncthreads();
    f32x4 acc[16];
    f32x4 z = {0.f, 0.f, 0.f, 0.f};
    #pragma unroll
    for (int i = 0; i < 16; ++i) acc[i] = z;
    bf16x8 a0 = *(const bf16x8*)&imc[((wv << 4) + m) * 72 + (quad << 3)];
    bf16x8 a1 = *(const bf16x8*)&imc[((wv << 4) + m) * 72 + 32 + (quad << 3)];
    #pragma unroll
    for (int nt = 0; nt < 16; ++nt) {
        bf16x8 b0 = *(const bf16x8*)&wgc[(nt * 16 + m) * 32 + (quad << 3)];
        bf16x8 b1 = *(const bf16x8*)&wgc[(256 + nt * 16 + m) * 32 + (quad << 3)];
        acc[nt] = MFMA_B16(a0, b0, acc[nt]);
        acc[nt] = MFMA_B16(a1, b1, acc[nt]);
    }
    #pragma unroll
    for (int nt = 0; nt < 16; ++nt)
        #pragma unroll
        for (int r = 0; r < 4; ++r) {
            int px = (wv << 4) + quad * 4 + r;
            out[(((bh << 6) + px) << 8) + nt * 16 + (lane & 15)] = f2b(fmaxf(acc[nt][r], 0.f));
        }
}

// ======================================================================
// mconv2: k4 s2 p1, (B,64,64,256)->(B,32,32,256), ReLU. M=64. grid B*16.
// ======================================================================
__global__ void __launch_bounds__(256, 3)
mconv2_k(const unsigned short* __restrict__ in, const unsigned short* __restrict__ wf,
         unsigned short* __restrict__ out)
{
    int blk = blockIdx.x;
    int bb = blk >> 4, j = blk & 15;
    int lane = threadIdx.x & 63;
    int n0 = (threadIdx.x >> 6) << 6;
    int m = lane & 15, quad = lane >> 4;
    __shared__ __align__(16) unsigned short win[2 * 66 * 132];  // 34.8 KB
    f32x4 acc[2][2][4];
    f32x4 z = {0.f, 0.f, 0.f, 0.f};
    #pragma unroll
    for (int a = 0; a < 2; ++a)
        #pragma unroll
        for (int i = 0; i < 2; ++i)
            #pragma unroll
            for (int t = 0; t < 4; ++t) acc[a][i][t] = z;

    for (int c0 = 0; c0 < 256; c0 += 128) {
        for (int kh = 0; kh < 4; ++kh) {
            __syncthreads();
            for (int s = threadIdx.x; s < 2 * 66 * 16; s += 256) {
                int c16 = s & 15;
                int t2 = s >> 4;
                int col = t2 % 66;
                int rr = t2 / 66;
                int ih = 4 * j - 1 + kh + 2 * rr, iw = col - 1;
                int4 v = make_int4(0, 0, 0, 0);
                if ((unsigned)ih < 64u && (unsigned)iw < 64u)
                    v = *(const int4*)&in[((((bb << 6) + ih) << 6) + iw) * 256 + c0 + (c16 << 3)];
                int cs = (col >> 1) + (col & 1) * 33;
                *(int4*)&win[(rr * 66 + cs) * 132 + (c16 << 3)] = v;
            }
            __syncthreads();
            #pragma unroll
            for (int kw = 0; kw < 4; ++kw) {
                int csoff = (kw >> 1) + (kw & 1) * 33;
                #pragma unroll
                for (int cch = 0; cch < 4; ++cch) {
                    bf16x8 a00 = *(const bf16x8*)&win[(m + csoff) * 132 + (cch << 5) + (quad << 3)];
                    bf16x8 a01 = *(const bf16x8*)&win[(m + 16 + csoff) * 132 + (cch << 5) + (quad << 3)];
                    bf16x8 a10 = *(const bf16x8*)&win[(66 + m + csoff) * 132 + (cch << 5) + (quad << 3)];
                    bf16x8 a11 = *(const bf16x8*)&win[(66 + m + 16 + csoff) * 132 + (cch << 5) + (quad << 3)];
                    int cg = (c0 >> 5) + cch;
                    int wbase = ((((kh << 2) + kw) * 8 + cg) * 256 + n0 + m) * 32 + (quad << 3);
                    bf16x8 b0 = *(const bf16x8*)&wf[wbase];
                    bf16x8 b1 = *(const bf16x8*)&wf[wbase + 16 * 32];
                    bf16x8 b2 = *(const bf16x8*)&wf[wbase + 32 * 32];
                    bf16x8 b3 = *(const bf16x8*)&wf[wbase + 48 * 32];
                    acc[0][0][0] = MFMA_B16(a00, b0, acc[0][0][0]);
                    acc[0][0][1] = MFMA_B16(a00, b1, acc[0][0][1]);
                    acc[0][0][2] = MFMA_B16(a00, b2, acc[0][0][2]);
                    acc[0][0][3] = MFMA_B16(a00, b3, acc[0][0][3]);
                    acc[0][1][0] = MFMA_B16(a01, b0, acc[0][1][0]);
                    acc[0][1][1] = MFMA_B16(a01, b1, acc[0][1][1]);
                    acc[0][1][2] = MFMA_B16(a01, b2, acc[0][1][2]);
                    acc[0][1][3] = MFMA_B16(a01, b3, acc[0][1][3]);
                    acc[1][0][0] = MFMA_B16(a10, b0, acc[1][0][0]);
                    acc[1][0][1] = MFMA_B16(a10, b1, acc[1][0][1]);
                    acc[1][0][2] = MFMA_B16(a10, b2, acc[1][0][2]);
                    acc[1][0][3] = MFMA_B16(a10, b3, acc[1][0][3]);
                    acc[1][1][0] = MFMA_B16(a11, b0, acc[1][1][0]);
                    acc[1][1][1] = MFMA_B16(a11, b1, acc[1][1][1]);
                    acc[1][1][2] = MFMA_B16(a11, b2, acc[1][1][2]);
                    acc[1][1][3] = MFMA_B16(a11, b3, acc[1][1][3]);
                }
            }
        }
    }
    #pragma unroll
    for (int row = 0; row < 2; ++row) {
        int oh = 2 * j + row;
        #pragma unroll
        for (int mt = 0; mt < 2; ++mt)
            #pragma unroll
            for (int nt = 0; nt < 4; ++nt)
                #pragma unroll
                for (int r = 0; r < 4; ++r) {
                    int px = mt * 16 + quad * 4 + r;
                    int col = n0 + nt * 16 + m;
                    out[((((bb << 5) + oh) << 5) + px) * 256 + col] = f2b(fmaxf(acc[row][mt][nt][r], 0.f));
                }
    }
}

// ======================================================================
// res3: FUSED residual block. Part 1 = mconv3 (3x3 s1 p1, ReLU);
// handoff: ReLU'd conv3 out -> LDS bf16 [64][264]; Part 2 = 1x1 from
// LDS; R11 epilogue v2: acc2 spilled fp32 to LDS (two 32-px halves,
// stride 260 floats), then coalesced int4 residual read + fp32 add +
// full-line int4 bf16 stores (+ float4 fp32 stores when f32out).
// grid = B*16 = 512. LDS 35.9 KB -> 3 blocks/CU.
// ======================================================================
__global__ void __launch_bounds__(256, 3)
res3_k(const unsigned short* __restrict__ in, const unsigned short* __restrict__ wfA,
       const unsigned short* __restrict__ wfB, unsigned short* __restrict__ outb,
       float* __restrict__ outf, int f32out)
{
    int blk = blockIdx.x;
    int bb = blk >> 4, j = blk & 15;      // out rows 2j, 2j+1
    int tid = threadIdx.x;
    int lane = tid & 63;
    int n0 = (tid >> 6) << 6;
    int m = lane & 15, quad = lane >> 4;
    __shared__ __align__(16) unsigned short win[4 * 34 * 132];  // 35.9 KB
    f32x4 acc[2][2][4];
    f32x4 z = {0.f, 0.f, 0.f, 0.f};
    #pragma unroll
    for (int a = 0; a < 2; ++a)
        #pragma unroll
        for (int i = 0; i < 2; ++i)
            #pragma unroll
            for (int t = 0; t < 4; ++t) acc[a][i][t] = z;

    // ---- part 1: 3x3 conv (identical to verified mconv3) ----
    for (int c0 = 0; c0 < 256; c0 += 128) {
        __syncthreads();
        for (int s = tid; s < 4 * 34 * 16; s += 256) {
            int c16 = s & 15;
            int t2 = s >> 4;
            int col = t2 % 34;
            int rr = t2 / 34;
            int ih = 2 * j - 1 + rr, iw = col - 1;
            int4 v = make_int4(0, 0, 0, 0);
            if ((unsigned)ih < 32u && (unsigned)iw < 32u)
                v = *(const int4*)&in[((((bb << 5) + ih) << 5) + iw) * 256 + c0 + (c16 << 3)];
            *(int4*)&win[(rr * 34 + col) * 132 + (c16 << 3)] = v;
        }
        __syncthreads();
        for (int kh = 0; kh < 3; ++kh) {
            #pragma unroll
            for (int kw = 0; kw < 3; ++kw) {
                #pragma unroll
                for (int cch = 0; cch < 4; ++cch) {
                    const unsigned short* ba = &win[(kh * 34 + m + kw) * 132 + (cch << 5) + (quad << 3)];
                    bf16x8 a00 = *(const bf16x8*)ba;
                    bf16x8 a01 = *(const bf16x8*)(ba + 16 * 132);
                    bf16x8 a10 = *(const bf16x8*)(ba + 34 * 132);
                    bf16x8 a11 = *(const bf16x8*)(ba + 50 * 132);
                    int cg = (c0 >> 5) + cch;
                    int wbase = (((kh * 3 + kw) * 8 + cg) * 256 + n0 + m) * 32 + (quad << 3);
                    bf16x8 b0 = *(const bf16x8*)&wfA[wbase];
                    bf16x8 b1 = *(const bf16x8*)&wfA[wbase + 16 * 32];
                    bf16x8 b2 = *(const bf16x8*)&wfA[wbase + 32 * 32];
                    bf16x8 b3 = *(const bf16x8*)&wfA[wbase + 48 * 32];
                    acc[0][0][0] = MFMA_B16(a00, b0, acc[0][0][0]);
                    acc[0][0][1] = MFMA_B16(a00, b1, acc[0][0][1]);
                    acc[0][0][2] = MFMA_B16(a00, b2, acc[0][0][2]);
                    acc[0][0][3] = MFMA_B16(a00, b3, acc[0][0][3]);
                    acc[0][1][0] = MFMA_B16(a01, b0, acc[0][1][0]);
                    acc[0][1][1] = MFMA_B16(a01, b1, acc[0][1][1]);
                    acc[0][1][2] = MFMA_B16(a01, b2, acc[0][1][2]);
                    acc[0][1][3] = MFMA_B16(a01, b3, acc[0][1][3]);
                    acc[1][0][0] = MFMA_B16(a10, b0, acc[1][0][0]);
                    acc[1][0][1] = MFMA_B16(a10, b1, acc[1][0][1]);
                    acc[1][0][2] = MFMA_B16(a10, b2, acc[1][0][2]);
                    acc[1][0][3] = MFMA_B16(a10, b3, acc[1][0][3]);
                    acc[1][1][0] = MFMA_B16(a11, b0, acc[1][1][0]);
                    acc[1][1][1] = MFMA_B16(a11, b1, acc[1][1][1]);
                    acc[1][1][2] = MFMA_B16(a11, b2, acc[1][1][2]);
                    acc[1][1][3] = MFMA_B16(a11, b3, acc[1][1][3]);
                }
            }
        }
    }

    // ---- handoff: ReLU(conv3) -> LDS bf16 [64][264] (alias over win) ----
    __syncthreads();   // all waves done reading win
    #pragma unroll
    for (int row = 0; row < 2; ++row)
        #pragma unroll
        for (int mt = 0; mt < 2; ++mt)
            #pragma unroll
            for (int nt = 0; nt < 4; ++nt)
                #pragma unroll
                for (int r = 0; r < 4; ++r) {
                    int p = row * 32 + mt * 16 + quad * 4 + r;
                    win[p * 264 + n0 + nt * 16 + m] = f2b(fmaxf(acc[row][mt][nt][r], 0.f));
                }
    __syncthreads();   // handoff complete

    // ---- part 2: 1x1 matmul from LDS ----
    f32x4 acc2[4][4];
    #pragma unroll
    for (int i = 0; i < 4; ++i)
        #pragma unroll
        for (int t = 0; t < 4; ++t) acc2[i][t] = z;

    #pragma unroll
    for (int cch = 0; cch < 8; ++cch) {
        bf16x8 a0 = *(const bf16x8*)&win[m * 264 + (cch << 5) + (quad << 3)];
        bf16x8 a1 = *(const bf16x8*)&win[(m + 16) * 264 + (cch << 5) + (quad << 3)];
        bf16x8 a2 = *(const bf16x8*)&win[(m + 32) * 264 + (cch << 5) + (quad << 3)];
        bf16x8 a3 = *(const bf16x8*)&win[(m + 48) * 264 + (cch << 5) + (quad << 3)];
        int wbase = (cch * 256 + n0 + m) * 32 + (quad << 3);
        bf16x8 b0 = *(const bf16x8*)&wfB[wbase];
        bf16x8 b1 = *(const bf16x8*)&wfB[wbase + 16 * 32];
        bf16x8 b2 = *(const bf16x8*)&wfB[wbase + 32 * 32];
        bf16x8 b3 = *(const bf16x8*)&wfB[wbase + 48 * 32];
        acc2[0][0] = MFMA_B16(a0, b0, acc2[0][0]);
        acc2[0][1] = MFMA_B16(a0, b1, acc2[0][1]);
        acc2[0][2] = MFMA_B16(a0, b2, acc2[0][2]);
        acc2[0][3] = MFMA_B16(a0, b3, acc2[0][3]);
        acc2[1][0] = MFMA_B16(a1, b0, acc2[1][0]);
        acc2[1][1] = MFMA_B16(a1, b1, acc2[1][1]);
        acc2[1][2] = MFMA_B16(a1, b2, acc2[1][2]);
        acc2[1][3] = MFMA_B16(a1, b3, acc2[1][3]);
        acc2[2][0] = MFMA_B16(a2, b0, acc2[2][0]);
        acc2[2][1] = MFMA_B16(a2, b1, acc2[2][1]);
        acc2[2][2] = MFMA_B16(a2, b2, acc2[2][2]);
        acc2[2][3] = MFMA_B16(a2, b3, acc2[2][3]);
        acc2[3][0] = MFMA_B16(a3, b0, acc2[3][0]);
        acc2[3][1] = MFMA_B16(a3, b1, acc2[3][1]);
        acc2[3][2] = MFMA_B16(a3, b2, acc2[3][2]);
        acc2[3][3] = MFMA_B16(a3, b3, acc2[3][3]);
    }

    // ---- R11 epilogue v2: fp32 LDS spill -> coalesced full-line IO ----
    float* winf = (float*)win;         // 32*260 floats = 33.3 KB <= 35.9 KB
    int rowbase = blk << 14;           // 64 px * 256
    #pragma unroll
    for (int half = 0; half < 2; ++half) {
        __syncthreads();   // winf free (a-frags consumed / prev half read)
        #pragma unroll
        for (int mt2 = 0; mt2 < 2; ++mt2) {
            int mt = half * 2 + mt2;
            #pragma unroll
            for (int nt = 0; nt < 4; ++nt)
                #pragma unroll
                for (int r = 0; r < 4; ++r) {
                    int pxl = mt2 * 16 + quad * 4 + r;   // 0..31
                    winf[pxl * 260 + n0 + nt * 16 + m] = acc2[mt][nt][r];
                }
        }
        __syncthreads();   // winf ready
        #pragma unroll
        for (int k = 0; k < 4; ++k) {
            int s = tid + k * 256;
            int pxl = s >> 5;          // 0..31
            int c8 = s & 31;           // 8-channel group
            int px = half * 32 + pxl;
            int idx = rowbase + (px << 8) + (c8 << 3);
            int4 rv = *(const int4*)&in[idx];          // 8 bf16 residual
            const float* wp = &winf[pxl * 260 + (c8 << 3)];
            float v0 = wp[0] + b2f((unsigned short)((unsigned)rv.x & 0xffffu));
            float v1 = wp[1] + b2f((unsigned short)((unsigned)rv.x >> 16));
            float v2 = wp[2] + b2f((unsigned short)((unsigned)rv.y & 0xffffu));
            float v3 = wp[3] + b2f((unsigned short)((unsigned)rv.y >> 16));
            float v4 = wp[4] + b2f((unsigned short)((unsigned)rv.z & 0xffffu));
            float v5 = wp[5] + b2f((unsigned short)((unsigned)rv.z >> 16));
            float v6 = wp[6] + b2f((unsigned short)((unsigned)rv.w & 0xffffu));
            float v7 = wp[7] + b2f((unsigned short)((unsigned)rv.w >> 16));
            unsigned w0 = (unsigned)f2b(v0) | ((unsigned)f2b(v1) << 16);
            unsigned w1 = (unsigned)f2b(v2) | ((unsigned)f2b(v3) << 16);
            unsigned w2 = (unsigned)f2b(v4) | ((unsigned)f2b(v5) << 16);
            unsigned w3 = (unsigned)f2b(v6) | ((unsigned)f2b(v7) << 16);
            *(int4*)&outb[idx] = make_int4((int)w0, (int)w1, (int)w2, (int)w3);
            if (f32out) {
                *(float4*)&outf[idx]     = make_float4(v0, v1, v2, v3);
                *(float4*)&outf[idx + 4] = make_float4(v4, v5, v6, v7);
            }
        }
    }
}

// ======================================================================
// mdeconv1: ConvTranspose2d(256->256,k4,s2,p1)+bias+ReLU. R1 2-row
// structure + R4 tb-epilogue (full-line dwordx4 stores). grid = 1024.
// ======================================================================
__global__ void __launch_bounds__(256, 3)
mdeconv1_k(const unsigned short* __restrict__ in, const unsigned short* __restrict__ wf,
           const float* __restrict__ bias, unsigned short* __restrict__ out)
{
    int blk = blockIdx.x;
    int bb = blk >> 5;
    int rem = blk & 31;
    int pp = rem >> 4;
    int i = rem & 15;
    int oy_a = pp + 4 * i;
    int p = (oy_a + 1) & 1;
    int r0a = (oy_a + 1 - p) >> 1;
    int rbase = r0a - 1;
    int tid = threadIdx.x;
    int lane = tid & 63;
    int n0 = (tid >> 6) << 6;
    int m = lane & 15, quad = lane >> 4;
    __shared__ __align__(16) unsigned short win[3 * 34 * 264];   // 53.9 KB
    __shared__ __align__(16) unsigned short tb[16 * 264];        // 8.4 KB

    for (int s = tid; s < 3 * 34 * 32; s += 256) {
        int c8 = s & 31;
        int t2 = s >> 5;
        int col = t2 % 34;
        int rr = t2 / 34;
        int ih = rbase + rr, iw = col - 1;
        int4 v = make_int4(0, 0, 0, 0);
        if ((unsigned)ih < 32u && (unsigned)iw < 32u)
            v = *(const int4*)&in[((((bb << 5) + ih) << 5) + iw) * 256 + (c8 << 3)];
        *(int4*)&win[(rr * 34 + col) * 264 + (c8 << 3)] = v;
    }
    __syncthreads();

    for (int par = 0; par < 2; ++par) {
        f32x4 acc[2][2][4];
        f32x4 z = {0.f, 0.f, 0.f, 0.f};
        #pragma unroll
        for (int a = 0; a < 2; ++a)
            #pragma unroll
            for (int i2 = 0; i2 < 2; ++i2)
                #pragma unroll
                for (int t = 0; t < 4; ++t) acc[a][i2][t] = z;

        #pragma unroll
        for (int t = 0; t < 2; ++t) {
            int kh = p + 2 * t;
            #pragma unroll
            for (int u = 0; u < 2; ++u) {
                int kw = (1 - par) + 2 * u;
                int ixoff = par - u + 1;
                #pragma unroll
                for (int cch = 0; cch < 8; ++cch) {
                    const unsigned short* baA = &win[((1 - t) * 34 + m + ixoff) * 264 + (cch << 5) + (quad << 3)];
                    const unsigned short* baB = baA + 34 * 264;
                    bf16x8 a00 = *(const bf16x8*)baA;
                    bf16x8 a01 = *(const bf16x8*)(baA + 16 * 264);
                    bf16x8 a10 = *(const bf16x8*)baB;
                    bf16x8 a11 = *(const bf16x8*)(baB + 16 * 264);
                    int wbase = ((((kh << 2) + kw) * 8 + cch) * 256 + n0 + m) * 32 + (quad << 3);
                    bf16x8 b0 = *(const bf16x8*)&wf[wbase];
                    bf16x8 b1 = *(const bf16x8*)&wf[wbase + 16 * 32];
                    bf16x8 b2 = *(const bf16x8*)&wf[wbase + 32 * 32];
                    bf16x8 b3 = *(const bf16x8*)&wf[wbase + 48 * 32];
                    acc[0][0][0] = MFMA_B16(a00, b0, acc[0][0][0]);
                    acc[0][0][1] = MFMA_B16(a00, b1, acc[0][0][1]);
                    acc[0][0][2] = MFMA_B16(a00, b2, acc[0][0][2]);
                    acc[0][0][3] = MFMA_B16(a00, b3, acc[0][0][3]);
                    acc[0][1][0] = MFMA_B16(a01, b0, acc[0][1][0]);
                    acc[0][1][1] = MFMA_B16(a01, b1, acc[0][1][1]);
                    acc[0][1][2] = MFMA_B16(a01, b2, acc[0][1][2]);
                    acc[0][1][3] = MFMA_B16(a01, b3, acc[0][1][3]);
                    acc[1][0][0] = MFMA_B16(a10, b0, acc[1][0][0]);
                    acc[1][0][1] = MFMA_B16(a10, b1, acc[1][0][1]);
                    acc[1][0][2] = MFMA_B16(a10, b2, acc[1][0][2]);
                    acc[1][0][3] = MFMA_B16(a10, b3, acc[1][0][3]);
                    acc[1][1][0] = MFMA_B16(a11, b0, acc[1][1][0]);
                    acc[1][1][1] = MFMA_B16(a11, b1, acc[1][1][1]);
                    acc[1][1][2] = MFMA_B16(a11, b2, acc[1][1][2]);
                    acc[1][1][3] = MFMA_B16(a11, b3, acc[1][1][3]);
                }
            }
        }

        #pragma unroll
        for (int row = 0; row < 2; ++row) {
            int oy = oy_a + 2 * row;
            #pragma unroll
            for (int mt = 0; mt < 2; ++mt) {
                __syncthreads();
                #pragma unroll
                for (int nt = 0; nt < 4; ++nt) {
                    float bs = bias[n0 + nt * 16 + m];
                    #pragma unroll
                    for (int rr = 0; rr < 4; ++rr) {
                        float v = fmaxf(acc[row][mt][nt][rr] + bs, 0.f);
                        tb[(quad * 4 + rr) * 264 + n0 + nt * 16 + m] = f2b(v);
                    }
                }
                __syncthreads();
                #pragma unroll
                for (int k = 0; k < 2; ++k) {
                    int s = tid + k * 256;
                    int pxl = s >> 5;
                    int c8 = s & 31;
                    int ox = 2 * (mt * 16 + pxl) + par;
                    *(int4*)&out[((((bb << 6) + oy) << 6) + ox) * 256 + (c8 << 3)] =
                        *(const int4*)&tb[pxl * 264 + (c8 << 3)];
                }
            }
        }
    }
}

// ======================================================================
// vqm: MFMA VQ + exact fp32 gather/loss. grid = B*32. Deterministic
// loss partials to lpart[bh*4+wv].
// ======================================================================
__global__ void __launch_bounds__(256, 2)
vqm_k(const unsigned short* __restrict__ zeb, const float* __restrict__ zef,
      const unsigned short* __restrict__ embF, const float* __restrict__ embed,
      const float* __restrict__ nrm, unsigned short* __restrict__ zq,
      float* __restrict__ lpart)
{
    int bh = blockIdx.x;
    int tid = threadIdx.x;
    int lane = tid & 63;
    int wv = tid >> 6;
    int m = lane & 15, quad = lane >> 4;
    __shared__ __align__(16) unsigned short win[32 * 264];
    __shared__ float bvv[4][32];
    __shared__ int   bii[4][32];
    __shared__ int   bidx[32];
    int rowbase = bh << 13;
    for (int s = tid; s < 32 * 32; s += 256) {
        int c8 = s & 31, px = s >> 5;
        *(int4*)&win[px * 264 + (c8 << 3)] = *(const int4*)&zeb[rowbase + (px << 8) + (c8 << 3)];
    }
    __syncthreads();

    f32x4 acc[2][8];
    f32x4 z = {0.f, 0.f, 0.f, 0.f};
    #pragma unroll
    for (int i = 0; i < 2; ++i)
        #pragma unroll
        for (int j = 0; j < 8; ++j) acc[i][j] = z;

    #pragma unroll
    for (int cch = 0; cch < 8; ++cch) {
        bf16x8 a0 = *(const bf16x8*)&win[m * 264 + (cch << 5) + (quad << 3)];
        bf16x8 a1 = *(const bf16x8*)&win[(m + 16) * 264 + (cch << 5) + (quad << 3)];
        #pragma unroll
        for (int nt = 0; nt < 8; ++nt) {
            bf16x8 b = *(const bf16x8*)&embF[((cch << 9) + (wv << 7) + (nt << 4) + m) * 32 + (quad << 3)];
            acc[0][nt] = MFMA_B16(a0, b, acc[0][nt]);
            acc[1][nt] = MFMA_B16(a1, b, acc[1][nt]);
        }
    }

    float nv[8];
    #pragma unroll
    for (int nt = 0; nt < 8; ++nt) nv[nt] = nrm[(wv << 7) + (nt << 4) + m];

    #pragma unroll
    for (int mt = 0; mt < 2; ++mt)
        #pragma unroll
        for (int r = 0; r < 4; ++r) {
            float bv = 1e30f;
            int bi = 0x7fffffff;
            #pragma unroll
            for (int nt = 0; nt < 8; ++nt) {
                float d = nv[nt] - 2.f * acc[mt][nt][r];
                int n = (wv << 7) + (nt << 4) + m;
                if (d < bv || (d == bv && n < bi)) { bv = d; bi = n; }
            }
            #pragma unroll
            for (int off = 1; off < 16; off <<= 1) {
                float ov = __shfl_xor(bv, off);
                int oi = __shfl_xor(bi, off);
                if (ov < bv || (ov == bv && oi < bi)) { bv = ov; bi = oi; }
            }
            if (m == 0) {
                int px = mt * 16 + quad * 4 + r;
                bvv[wv][px] = bv;
                bii[wv][px] = bi;
            }
        }
    __syncthreads();
    if (tid < 32) {
        float bv = bvv[0][tid];
        int bi = bii[0][tid];
        #pragma unroll
        for (int w2 = 1; w2 < 4; ++w2) {
            float ov = bvv[w2][tid];
            int oi = bii[w2][tid];
            if (ov < bv || (ov == bv && oi < bi)) { bv = ov; bi = oi; }
        }
        bidx[tid] = bi;
    }
    __syncthreads();

    float lsum = 0.f;
    #pragma unroll
    for (int j = 0; j < 8; ++j) {
        int px = (wv << 3) + j;
        int bi = bidx[px];
        int pix = (bh << 5) + px;
        const float4 e = *(const float4*)&embed[bi * 256 + (lane << 2)];
        const float4 zv = *(const float4*)&zef[(pix << 8) + (lane << 2)];
        ushort4 eq;
        eq.x = f2b(e.x); eq.y = f2b(e.y); eq.z = f2b(e.z); eq.w = f2b(e.w);
        *(ushort4*)&zq[(pix << 8) + (lane << 2)] = eq;
        float dx = zv.x - e.x, dy = zv.y - e.y, dz = zv.z - e.z, dw = zv.w - e.w;
        lsum += dx * dx + dy * dy + dz * dz + dw * dw;
    }
    #pragma unroll
    for (int off = 1; off < 64; off <<= 1) lsum += __shfl_xor(lsum, off);
    if (lane == 0) lpart[(bh << 2) + wv] = lsum;
}

// ======================================================================
// mdec2a: deconv2 pass 1 — Y[B*64*64, 48] = X[.,256] x Wg[256,48]
// ======================================================================
__global__ void __launch_bounds__(256, 4)
mdec2a_k(const unsigned short* __restrict__ in, const unsigned short* __restrict__ wg,
         float* __restrict__ Y)
{
    int tid = threadIdx.x;
    int lane = tid & 63;
    int wv = tid >> 6;
    int m = lane & 15, quad = lane >> 4;
    __shared__ __align__(16) unsigned short win[64 * 264];
    int pxbase = blockIdx.x << 6;
    for (int s = tid; s < 64 * 32; s += 256) {
        int c8 = s & 31, px = s >> 5;
        *(int4*)&win[px * 264 + (c8 << 3)] = *(const int4*)&in[((pxbase + px) << 8) + (c8 << 3)];
    }
    __syncthreads();
    f32x4 acc[3];
    f32x4 z = {0.f, 0.f, 0.f, 0.f};
    acc[0] = z; acc[1] = z; acc[2] = z;
    #pragma unroll
    for (int cch = 0; cch < 8; ++cch) {
        bf16x8 a = *(const bf16x8*)&win[((wv << 4) + m) * 264 + (cch << 5) + (quad << 3)];
        #pragma unroll
        for (int nt = 0; nt < 3; ++nt) {
            bf16x8 b = *(const bf16x8*)&wg[(cch * 48 + nt * 16 + m) * 32 + (quad << 3)];
            acc[nt] = MFMA_B16(a, b, acc[nt]);
        }
    }
    #pragma unroll
    for (int nt = 0; nt < 3; ++nt)
        #pragma unroll
        for (int r = 0; r < 4; ++r) {
            int px = pxbase + (wv << 4) + quad * 4 + r;
            Y[px * 48 + nt * 16 + m] = acc[nt][r];
        }
}

// ======================================================================
// dec2b: deconv2 pass 2 — gather taps, +bias, sigmoid, NCHW out.
// ======================================================================
__global__ void dec2b_k(const float* __restrict__ Y, const float* __restrict__ bias,
                        float* __restrict__ out)
{
    int idx = blockIdx.x * 256 + threadIdx.x;    // < 524288
    int b = idx >> 14;
    int rem = idx & 16383;
    int oy = rem >> 7;
    int ox = rem & 127;
    int p = (oy + 1) & 1;
    int q = (ox + 1) & 1;
    float acc0 = bias[0], acc1 = bias[1], acc2 = bias[2];
    #pragma unroll
    for (int t = 0; t < 2; ++t) {
        int kh = p + 2 * t;
        int ih = (oy + 1 - kh) >> 1;
        if ((unsigned)ih >= 64u) continue;
        #pragma unroll
        for (int u = 0; u < 2; ++u) {
            int kw = q + 2 * u;
            int iw = (ox + 1 - kw) >> 1;
            if ((unsigned)iw >= 64u) continue;
            int base = ((((b << 6) + ih) << 6) + iw) * 48 + ((kh << 2) + kw) * 3;
            acc0 += Y[base];
            acc1 += Y[base + 1];
            acc2 += Y[base + 2];
        }
    }
    int obase = (b * 3 << 14) + (oy << 7) + ox;
    out[obase]           = 1.f / (1.f + expf(-acc0));
    out[obase + 16384]   = 1.f / (1.f + expf(-acc1));
    out[obase + 32768]   = 1.f / (1.f + expf(-acc2));
}

// ======================================================================
extern "C" void kernel_launch(void* const* d_in, const int* in_sizes, int n_in,
                              void* d_out, int out_size, void* d_ws, size_t ws_size,
                              hipStream_t stream)
{
    (void)in_sizes; (void)n_in; (void)out_size; (void)ws_size;
    const float* x      = (const float*)d_in[0];
    const float* embed  = (const float*)d_in[1];
    const float* e_w1   = (const float*)d_in[2];
    const float* e_w2   = (const float*)d_in[3];
    const float* e_r1a  = (const float*)d_in[4];
    const float* e_r1b  = (const float*)d_in[5];
    const float* e_r2a  = (const float*)d_in[6];
    const float* e_r2b  = (const float*)d_in[7];
    const float* d_r1a  = (const float*)d_in[8];
    const float* d_r1b  = (const float*)d_in[9];
    const float* d_r2a  = (const float*)d_in[10];
    const float* d_r2b  = (const float*)d_in[11];
    const float* dt1_w  = (const float*)d_in[12];
    const float* dt1_b  = (const float*)d_in[13];
    const float* dt2_w  = (const float*)d_in[14];
    const float* dt2_b  = (const float*)d_in[15];
    float* outp = (float*)d_out;

    // ---- workspace layout ----
    char* base = (char*)d_ws;
    size_t off = 0;
    auto alloc = [&](size_t bytes) { char* p = base + off; off += (bytes + 255) & ~size_t(255); return p; };
    unsigned short* A0b = (unsigned short*)alloc(67108864);  // (B,64,64,256) bf16
    float*          A1f = (float*)alloc(33554432);           // ze fp32; later Y
    unsigned short* L0  = (unsigned short*)alloc(16777216);
    unsigned short* L1  = (unsigned short*)alloc(16777216);
    unsigned short* L2  = (unsigned short*)alloc(16777216);  // (unused after R9 fusion; kept)
    unsigned short* Wf  = (unsigned short*)alloc(9437184);   // 10 frag-ordered weights
    unsigned short* Wg  = (unsigned short*)alloc(24576);     // deconv2 frag weights
    unsigned short* EmbF = (unsigned short*)alloc(262144);   // codebook frag bf16
    unsigned short* WgC = (unsigned short*)alloc(32768);     // conv1 frag weights
    float* Nrm  = (float*)alloc(2048);
    float* Lpart = (float*)alloc(16384);                     // 4096 loss partials
    float* Y = A1f;   // alias: ze dead after vqm_k
    (void)L2;

    // frag-weight segment offsets inside Wf (element counts)
    unsigned short* Wf_ew2  = Wf;
    unsigned short* Wf_er1a = Wf + 1048576;
    unsigned short* Wf_er1b = Wf + 1638400;
    unsigned short* Wf_er2a = Wf + 1703936;
    unsigned short* Wf_er2b = Wf + 2293760;
    unsigned short* Wf_dr1a = Wf + 2359296;
    unsigned short* Wf_dr1b = Wf + 2949120;
    unsigned short* Wf_dr2a = Wf + 3014656;
    unsigned short* Wf_dr2b = Wf + 3604480;
    unsigned short* Wf_dt1  = Wf + 3670016;

    PermfArgs pa;
    const float* srcs[10] = {e_w2, e_r1a, e_r1b, e_r2a, e_r2b, d_r1a, d_r1b, d_r2a, d_r2b, dt1_w};
    int kws[10] = {4, 3, 1, 3, 1, 3, 1, 3, 1, 4};
    int sos[10] = {4096, 2304, 256, 2304, 256, 2304, 256, 2304, 256, 16};
    int sis[10] = {16, 9, 1, 9, 1, 9, 1, 9, 1, 4096};
    int shs[10] = {4, 3, 0, 3, 0, 3, 0, 3, 0, 4};
    int sws[10] = {1, 1, 0, 1, 0, 1, 0, 1, 0, 1};
    int cums[11] = {0, 1048576, 1638400, 1703936, 2293760, 2359296,
                    2949120, 3014656, 3604480, 3670016, 4718592};
    for (int k = 0; k < 10; ++k) {
        pa.src[k] = srcs[k]; pa.kw[k] = kws[k]; pa.so[k] = sos[k];
        pa.si[k] = sis[k]; pa.sh[k] = shs[k]; pa.sw[k] = sws[k];
        pa.cum[k] = cums[k];
    }
    pa.cum[10] = cums[10];

    permf_all_k<<<18432, 256, 0, stream>>>(pa, Wf);
    misc_prep_k<<<752, 256, 0, stream>>>(dt2_w, Wg, embed, EmbF, e_w1, WgC, Nrm);

    // ---- encoder ----
    conv1m_k<<<32 * 64, 256, 0, stream>>>(x, WgC, A0b);
    mconv2_k<<<32 * 16, 256, 0, stream>>>(A0b, Wf_ew2, L1);                      // h
    res3_k<<<32 * 16, 256, 0, stream>>>(L1, Wf_er1a, Wf_er1b, L0, nullptr, 0);   // r1 -> L0
    res3_k<<<32 * 16, 256, 0, stream>>>(L0, Wf_er2a, Wf_er2b, L1, A1f, 1);       // ze: bf16->L1, fp32->A1f

    // ---- VQ ----
    vqm_k<<<32 * 32, 256, 0, stream>>>(L1, A1f, EmbF, embed, Nrm, L1, Lpart);

    // ---- decoder ----
    res3_k<<<32 * 16, 256, 0, stream>>>(L1, Wf_dr1a, Wf_dr1b, L0, nullptr, 0);   // d1 -> L0
    res3_k<<<32 * 16, 256, 0, stream>>>(L0, Wf_dr2a, Wf_dr2b, L1, nullptr, 0);   // d2 -> L1
    mdeconv1_k<<<32 * 32, 256, 0, stream>>>(L1, Wf_dt1, dt1_b, A0b);
    mdec2a_k<<<2048, 256, 0, stream>>>(A0b, Wg, Y);
    dec2b_k<<<2048, 256, 0, stream>>>(Y, dt2_b, outp);
    lossfin_k<<<1, 256, 0, stream>>>(Lpart, outp);
}

// Round 12
// 713.709 us; speedup vs baseline: 1.2787x; 1.0073x over previous
//
#include <hip/hip_runtime.h>

// ======================================================================
// VQ-VAE forward, all-MFMA. B=32, CIN=3, IMG=128, D=256, K=512.
// NHWC bf16 activations. Weights frag-ordered Wf[khkw][cch][n][32].
// MFMA 16x16x32 bf16: A[m=lane&15][k=quad*8+j], B[n][k], D col=lane&15,
// row=quad*4+reg.
// R4: mdeconv1 tb-epilogue. R6: deterministic loss. R9: fused residual
// block. R11: res3 full-line epilogue (WRITE 99.8->~17MB). 718.9 us.
// R12: res3 M=32 (one output row/block), grid 1024 -> 4 blocks/CU
// (was 2, grid-limited; Occupancy 21%, all pipes <30% = latency-bound).
// Staging 3 rows x 34 x 128ch = 26.9KB; launch_bounds(256,4). 2x TLP.
// ======================================================================

typedef __attribute__((ext_vector_type(8))) short bf16x8;
typedef __attribute__((ext_vector_type(4))) float f32x4;
#define MFMA_B16(a, b, c) __builtin_amdgcn_mfma_f32_16x16x32_bf16(a, b, c, 0, 0, 0)

__device__ inline unsigned short f2b(float f) {
    unsigned int u = __float_as_uint(f);
    unsigned int r = u + 0x7fffu + ((u >> 16) & 1u);
    return (unsigned short)(r >> 16);
}
__device__ inline float b2f(unsigned short u) {
    return __uint_as_float(((unsigned int)u) << 16);
}

// ======================================================================
// batched bf16 frag-order weight permute for the 10 conv/deconv weights.
// ======================================================================
struct PermfArgs {
    const float* src[10];
    int kw[10];
    int so[10], si[10], sh[10], sw[10];
    int cum[11];
};

__global__ void permf_all_k(PermfArgs a, unsigned short* __restrict__ dst)
{
    int gid = blockIdx.x * 256 + threadIdx.x;
    if (gid >= a.cum[10]) return;
    int seg = 0;
    while (seg < 9 && gid >= a.cum[seg + 1]) ++seg;
    int l = gid - a.cum[seg];
    int q = l & 31;
    int n = (l >> 5) & 255;
    int rest = l >> 13;
    int cch = rest & 7;
    int khkw = rest >> 3;
    int kh = khkw / a.kw[seg], kw = khkw % a.kw[seg];
    int ci = cch * 32 + q;
    dst[gid] = f2b(a.src[seg][n * a.so[seg] + ci * a.si[seg] + kh * a.sh[seg] + kw * a.sw[seg]]);
}

// ======================================================================
// misc prep: deconv2 frag weights, codebook frag, conv1 frag weights,
// codebook norms. 752 blocks x 256.
// ======================================================================
__global__ void misc_prep_k(const float* __restrict__ dt2_w, unsigned short* __restrict__ wg,
                            const float* __restrict__ embed, unsigned short* __restrict__ embF,
                            const float* __restrict__ e_w1, unsigned short* __restrict__ wgc,
                            float* __restrict__ nrm)
{
    int blk = blockIdx.x, tid = threadIdx.x;
    if (blk < 48) {
        int idx = blk * 256 + tid;        // < 12288
        int q = idx & 31;
        int n = (idx >> 5) % 48;
        int cch = idx / (48 * 32);
        int ci = cch * 32 + q;
        int oc = n % 3, khkw = n / 3;
        int kh = khkw >> 2, kw = khkw & 3;
        wg[idx] = f2b(dt2_w[ci * 48 + oc * 16 + kh * 4 + kw]);
    } else if (blk < 560) {
        int idx = (blk - 48) * 256 + tid; // < 131072
        int q = idx & 31;
        int n = (idx >> 5) & 511;
        int cch = idx >> 14;
        embF[idx] = f2b(embed[n * 256 + cch * 32 + q]);
    } else if (blk < 624) {
        int idx = (blk - 560) * 256 + tid;  // < 16384
        int q = idx & 31;
        int n = (idx >> 5) & 255;
        int kt = idx >> 13;
        int k = kt * 32 + q;
        float v = 0.f;
        if (k < 48) {
            int ci = k >> 4, kh = (k >> 2) & 3, kwv = k & 3;
            v = e_w1[n * 48 + ci * 16 + kh * 4 + kwv];
        }
        wgc[idx] = f2b(v);
    } else {
        int row = (blk - 624) * 4 + (tid >> 6);
        int lane = tid & 63;
        float s = 0.f;
        #pragma unroll
        for (int c = 0; c < 256; c += 64) {
            float v = embed[row * 256 + c + lane];
            s += v * v;
        }
        #pragma unroll
        for (int off = 1; off < 64; off <<= 1) s += __shfl_xor(s, off);
        if (lane == 0) nrm[row] = s;
    }
}

// ======================================================================
// lossfin: deterministic fixed-order reduction of 4096 wave-partials.
// ======================================================================
__global__ void lossfin_k(const float* __restrict__ lpart, float* __restrict__ out)
{
    __shared__ float red[256];
    int tid = threadIdx.x;
    float s = 0.f;
    #pragma unroll
    for (int i = 0; i < 16; ++i) s += lpart[tid * 16 + i];
    red[tid] = s;
    __syncthreads();
    for (int off = 128; off > 0; off >>= 1) {
        if (tid < off) red[tid] += red[tid + off];
        __syncthreads();
    }
    if (tid == 0) {
        float m = red[0] * (1.0f / 32768.0f);
        out[1572864] = m;
        out[1572865] = m;
    }
}

// ======================================================================
// conv1m: MFMA im2col conv1. x NCHW fp32 -> NHWC bf16 (B,64,64,256),
// k4 s2 p1, ReLU. grid = B*64.
// ======================================================================
__global__ void __launch_bounds__(256, 4)
conv1m_k(const float* __restrict__ x, const unsigned short* __restrict__ wgc,
         unsigned short* __restrict__ out)
{
    int bh = blockIdx.x;             // b*64 + oh
    int b = bh >> 6, oh = bh & 63;
    int tid = threadIdx.x;
    int lane = tid & 63, wv = tid >> 6;
    int m = lane & 15, quad = lane >> 4;
    __shared__ float xrow[3][4][130];
    __shared__ __align__(16) unsigned short imc[64 * 72];
    for (int s = tid; s < 1560; s += 256) {
        int col = s % 130;
        int t = s / 130;
        int r = t & 3;
        int c = t >> 2;
        int ih = 2 * oh - 1 + r, iw = col - 1;
        float v = 0.f;
        if ((unsigned)ih < 128u && (unsigned)iw < 128u)
            v = x[(((b * 3 + c) << 7) + ih) * 128 + iw];
        xrow[c][r][col] = v;
    }
    __syncthreads();
    for (int s = tid; s < 4096; s += 256) {
        int px = s >> 6, k = s & 63;
        float v = 0.f;
        if (k < 48) {
            int ci = k >> 4, kh = (k >> 2) & 3, kw = k & 3;
            v = xrow[ci][kh][2 * px + kw];
        }
        imc[px * 72 + k] = f2b(v);
    }
    __syncthreads();
    f32x4 acc[16];
    f32x4 z = {0.f, 0.f, 0.f, 0.f};
    #pragma unroll
    for (int i = 0; i < 16; ++i) acc[i] = z;
    bf16x8 a0 = *(const bf16x8*)&imc[((wv << 4) + m) * 72 + (quad << 3)];
    bf16x8 a1 = *(const bf16x8*)&imc[((wv << 4) + m) * 72 + 32 + (quad << 3)];
    #pragma unroll
    for (int nt = 0; nt < 16; ++nt) {
        bf16x8 b0 = *(const bf16x8*)&wgc[(nt * 16 + m) * 32 + (quad << 3)];
        bf16x8 b1 = *(const bf16x8*)&wgc[(256 + nt * 16 + m) * 32 + (quad << 3)];
        acc[nt] = MFMA_B16(a0, b0, acc[nt]);
        acc[nt] = MFMA_B16(a1, b1, acc[nt]);
    }
    #pragma unroll
    for (int nt = 0; nt < 16; ++nt)
        #pragma unroll
        for (int r = 0; r < 4; ++r) {
            int px = (wv << 4) + quad * 4 + r;
            out[(((bh << 6) + px) << 8) + nt * 16 + (lane & 15)] = f2b(fmaxf(acc[nt][r], 0.f));
        }
}

// ======================================================================
// mconv2: k4 s2 p1, (B,64,64,256)->(B,32,32,256), ReLU. M=64. grid B*16.
// ======================================================================
__global__ void __launch_bounds__(256, 3)
mconv2_k(const unsigned short* __restrict__ in, const unsigned short* __restrict__ wf,
         unsigned short* __restrict__ out)
{
    int blk = blockIdx.x;
    int bb = blk >> 4, j = blk & 15;
    int lane = threadIdx.x & 63;
    int n0 = (threadIdx.x >> 6) << 6;
    int m = lane & 15, quad = lane >> 4;
    __shared__ __align__(16) unsigned short win[2 * 66 * 132];  // 34.8 KB
    f32x4 acc[2][2][4];
    f32x4 z = {0.f, 0.f, 0.f, 0.f};
    #pragma unroll
    for (int a = 0; a < 2; ++a)
        #pragma unroll
        for (int i = 0; i < 2; ++i)
            #pragma unroll
            for (int t = 0; t < 4; ++t) acc[a][i][t] = z;

    for (int c0 = 0; c0 < 256; c0 += 128) {
        for (int kh = 0; kh < 4; ++kh) {
            __syncthreads();
            for (int s = threadIdx.x; s < 2 * 66 * 16; s += 256) {
                int c16 = s & 15;
                int t2 = s >> 4;
                int col = t2 % 66;
                int rr = t2 / 66;
                int ih = 4 * j - 1 + kh + 2 * rr, iw = col - 1;
                int4 v = make_int4(0, 0, 0, 0);
                if ((unsigned)ih < 64u && (unsigned)iw < 64u)
                    v = *(const int4*)&in[((((bb << 6) + ih) << 6) + iw) * 256 + c0 + (c16 << 3)];
                int cs = (col >> 1) + (col & 1) * 33;
                *(int4*)&win[(rr * 66 + cs) * 132 + (c16 << 3)] = v;
            }
            __syncthreads();
            #pragma unroll
            for (int kw = 0; kw < 4; ++kw) {
                int csoff = (kw >> 1) + (kw & 1) * 33;
                #pragma unroll
                for (int cch = 0; cch < 4; ++cch) {
                    bf16x8 a00 = *(const bf16x8*)&win[(m + csoff) * 132 + (cch << 5) + (quad << 3)];
                    bf16x8 a01 = *(const bf16x8*)&win[(m + 16 + csoff) * 132 + (cch << 5) + (quad << 3)];
                    bf16x8 a10 = *(const bf16x8*)&win[(66 + m + csoff) * 132 + (cch << 5) + (quad << 3)];
                    bf16x8 a11 = *(const bf16x8*)&win[(66 + m + 16 + csoff) * 132 + (cch << 5) + (quad << 3)];
                    int cg = (c0 >> 5) + cch;
                    int wbase = ((((kh << 2) + kw) * 8 + cg) * 256 + n0 + m) * 32 + (quad << 3);
                    bf16x8 b0 = *(const bf16x8*)&wf[wbase];
                    bf16x8 b1 = *(const bf16x8*)&wf[wbase + 16 * 32];
                    bf16x8 b2 = *(const bf16x8*)&wf[wbase + 32 * 32];
                    bf16x8 b3 = *(const bf16x8*)&wf[wbase + 48 * 32];
                    acc[0][0][0] = MFMA_B16(a00, b0, acc[0][0][0]);
                    acc[0][0][1] = MFMA_B16(a00, b1, acc[0][0][1]);
                    acc[0][0][2] = MFMA_B16(a00, b2, acc[0][0][2]);
                    acc[0][0][3] = MFMA_B16(a00, b3, acc[0][0][3]);
                    acc[0][1][0] = MFMA_B16(a01, b0, acc[0][1][0]);
                    acc[0][1][1] = MFMA_B16(a01, b1, acc[0][1][1]);
                    acc[0][1][2] = MFMA_B16(a01, b2, acc[0][1][2]);
                    acc[0][1][3] = MFMA_B16(a01, b3, acc[0][1][3]);
                    acc[1][0][0] = MFMA_B16(a10, b0, acc[1][0][0]);
                    acc[1][0][1] = MFMA_B16(a10, b1, acc[1][0][1]);
                    acc[1][0][2] = MFMA_B16(a10, b2, acc[1][0][2]);
                    acc[1][0][3] = MFMA_B16(a10, b3, acc[1][0][3]);
                    acc[1][1][0] = MFMA_B16(a11, b0, acc[1][1][0]);
                    acc[1][1][1] = MFMA_B16(a11, b1, acc[1][1][1]);
                    acc[1][1][2] = MFMA_B16(a11, b2, acc[1][1][2]);
                    acc[1][1][3] = MFMA_B16(a11, b3, acc[1][1][3]);
                }
            }
        }
    }
    #pragma unroll
    for (int row = 0; row < 2; ++row) {
        int oh = 2 * j + row;
        #pragma unroll
        for (int mt = 0; mt < 2; ++mt)
            #pragma unroll
            for (int nt = 0; nt < 4; ++nt)
                #pragma unroll
                for (int r = 0; r < 4; ++r) {
                    int px = mt * 16 + quad * 4 + r;
                    int col = n0 + nt * 16 + m;
                    out[((((bb << 5) + oh) << 5) + px) * 256 + col] = f2b(fmaxf(acc[row][mt][nt][r], 0.f));
                }
    }
}

// ======================================================================
// res3: FUSED residual block, R12 M=32 (one output row per block).
// grid = B*32 = 1024 -> 4 blocks/CU (2x TLP vs R11). Part 1 = 3x3 conv
// (stage 3 rows x 34 x 128ch/phase, 26.9KB); handoff ReLU'd out ->
// LDS bf16 [32][264]; Part 2 = 1x1 from LDS; epilogue: fp32 spill in
// two 16-px halves + coalesced int4 residual read / full-line stores.
// ======================================================================
__global__ void __launch_bounds__(256, 4)
res3_k(const unsigned short* __restrict__ in, const unsigned short* __restrict__ wfA,
       const unsigned short* __restrict__ wfB, unsigned short* __restrict__ outb,
       float* __restrict__ outf, int f32out)
{
    int blk = blockIdx.x;
    int bb = blk >> 5, j = blk & 31;      // output row j
    int tid = threadIdx.x;
    int lane = tid & 63;
    int n0 = (tid >> 6) << 6;
    int m = lane & 15, quad = lane >> 4;
    __shared__ __align__(16) unsigned short win[3 * 34 * 132];  // 26.9 KB
    f32x4 acc[2][4];
    f32x4 z = {0.f, 0.f, 0.f, 0.f};
    #pragma unroll
    for (int i = 0; i < 2; ++i)
        #pragma unroll
        for (int t = 0; t < 4; ++t) acc[i][t] = z;

    // ---- part 1: 3x3 conv, 2 channel phases ----
    for (int c0 = 0; c0 < 256; c0 += 128) {
        __syncthreads();
        for (int s = tid; s < 3 * 34 * 16; s += 256) {
            int c16 = s & 15;
            int t2 = s >> 4;
            int col = t2 % 34;
            int rr = t2 / 34;
            int ih = j - 1 + rr, iw = col - 1;
            int4 v = make_int4(0, 0, 0, 0);
            if ((unsigned)ih < 32u && (unsigned)iw < 32u)
                v = *(const int4*)&in[((((bb << 5) + ih) << 5) + iw) * 256 + c0 + (c16 << 3)];
            *(int4*)&win[(rr * 34 + col) * 132 + (c16 << 3)] = v;
        }
        __syncthreads();
        for (int kh = 0; kh < 3; ++kh) {
            #pragma unroll
            for (int kw = 0; kw < 3; ++kw) {
                #pragma unroll
                for (int cch = 0; cch < 4; ++cch) {
                    const unsigned short* ba = &win[(kh * 34 + m + kw) * 132 + (cch << 5) + (quad << 3)];
                    bf16x8 a0 = *(const bf16x8*)ba;
                    bf16x8 a1 = *(const bf16x8*)(ba + 16 * 132);
                    int cg = (c0 >> 5) + cch;
                    int wbase = (((kh * 3 + kw) * 8 + cg) * 256 + n0 + m) * 32 + (quad << 3);
                    bf16x8 b0 = *(const bf16x8*)&wfA[wbase];
                    bf16x8 b1 = *(const bf16x8*)&wfA[wbase + 16 * 32];
                    bf16x8 b2 = *(const bf16x8*)&wfA[wbase + 32 * 32];
                    bf16x8 b3 = *(const bf16x8*)&wfA[wbase + 48 * 32];
                    acc[0][0] = MFMA_B16(a0, b0, acc[0][0]);
                    acc[0][1] = MFMA_B16(a0, b1, acc[0][1]);
                    acc[0][2] = MFMA_B16(a0, b2, acc[0][2]);
                    acc[0][3] = MFMA_B16(a0, b3, acc[0][3]);
                    acc[1][0] = MFMA_B16(a1, b0, acc[1][0]);
                    acc[1][1] = MFMA_B16(a1, b1, acc[1][1]);
                    acc[1][2] = MFMA_B16(a1, b2, acc[1][2]);
                    acc[1][3] = MFMA_B16(a1, b3, acc[1][3]);
                }
            }
        }
    }

    // ---- handoff: ReLU(conv3) -> LDS bf16 [32][264] (alias over win) ----
    __syncthreads();   // all waves done reading win
    #pragma unroll
    for (int i = 0; i < 2; ++i)
        #pragma unroll
        for (int nt = 0; nt < 4; ++nt)
            #pragma unroll
            for (int r = 0; r < 4; ++r) {
                int p = i * 16 + quad * 4 + r;       // 0..31
                win[p * 264 + n0 + nt * 16 + m] = f2b(fmaxf(acc[i][nt][r], 0.f));
            }
    __syncthreads();   // handoff complete

    // ---- part 2: 1x1 matmul from LDS ----
    f32x4 acc2[2][4];
    #pragma unroll
    for (int i = 0; i < 2; ++i)
        #pragma unroll
        for (int t = 0; t < 4; ++t) acc2[i][t] = z;

    #pragma unroll
    for (int cch = 0; cch < 8; ++cch) {
        bf16x8 a0 = *(const bf16x8*)&win[m * 264 + (cch << 5) + (quad << 3)];
        bf16x8 a1 = *(const bf16x8*)&win[(m + 16) * 264 + (cch << 5) + (quad << 3)];
        int wbase = (cch * 256 + n0 + m) * 32 + (quad << 3);
        bf16x8 b0 = *(const bf16x8*)&wfB[wbase];
        bf16x8 b1 = *(const bf16x8*)&wfB[wbase + 16 * 32];
        bf16x8 b2 = *(const bf16x8*)&wfB[wbase + 32 * 32];
        bf16x8 b3 = *(const bf16x8*)&wfB[wbase + 48 * 32];
        acc2[0][0] = MFMA_B16(a0, b0, acc2[0][0]);
        acc2[0][1] = MFMA_B16(a0, b1, acc2[0][1]);
        acc2[0][2] = MFMA_B16(a0, b2, acc2[0][2]);
        acc2[0][3] = MFMA_B16(a0, b3, acc2[0][3]);
        acc2[1][0] = MFMA_B16(a1, b0, acc2[1][0]);
        acc2[1][1] = MFMA_B16(a1, b1, acc2[1][1]);
        acc2[1][2] = MFMA_B16(a1, b2, acc2[1][2]);
        acc2[1][3] = MFMA_B16(a1, b3, acc2[1][3]);
    }

    // ---- epilogue: fp32 LDS spill (16-px halves) -> coalesced IO ----
    float* winf = (float*)win;         // 16*260 floats = 16.6 KB <= 26.9 KB
    int rowbase = blk << 13;           // 32 px * 256
    #pragma unroll
    for (int half = 0; half < 2; ++half) {
        __syncthreads();   // winf free
        #pragma unroll
        for (int nt = 0; nt < 4; ++nt)
            #pragma unroll
            for (int r = 0; r < 4; ++r) {
                int pxl = quad * 4 + r;              // 0..15
                winf[pxl * 260 + n0 + nt * 16 + m] = acc2[half][nt][r];
            }
        __syncthreads();   // winf ready
        #pragma unroll
        for (int k = 0; k < 2; ++k) {
            int s = tid + k * 256;
            int pxl = s >> 5;          // 0..15
            int c8 = s & 31;           // 8-channel group
            int px = half * 16 + pxl;
            int idx = rowbase + (px << 8) + (c8 << 3);
            int4 rv = *(const int4*)&in[idx];          // 8 bf16 residual
            const float* wp = &winf[pxl * 260 + (c8 << 3)];
            float v0 = wp[0] + b2f((unsigned short)((unsigned)rv.x & 0xffffu));
            float v1 = wp[1] + b2f((unsigned short)((unsigned)rv.x >> 16));
            float v2 = wp[2] + b2f((unsigned short)((unsigned)rv.y & 0xffffu));
            float v3 = wp[3] + b2f((unsigned short)((unsigned)rv.y >> 16));
            float v4 = wp[4] + b2f((unsigned short)((unsigned)rv.z & 0xffffu));
            float v5 = wp[5] + b2f((unsigned short)((unsigned)rv.z >> 16));
            float v6 = wp[6] + b2f((unsigned short)((unsigned)rv.w & 0xffffu));
            float v7 = wp[7] + b2f((unsigned short)((unsigned)rv.w >> 16));
            unsigned w0 = (unsigned)f2b(v0) | ((unsigned)f2b(v1) << 16);
            unsigned w1 = (unsigned)f2b(v2) | ((unsigned)f2b(v3) << 16);
            unsigned w2 = (unsigned)f2b(v4) | ((unsigned)f2b(v5) << 16);
            unsigned w3 = (unsigned)f2b(v6) | ((unsigned)f2b(v7) << 16);
            *(int4*)&outb[idx] = make_int4((int)w0, (int)w1, (int)w2, (int)w3);
            if (f32out) {
                *(float4*)&outf[idx]     = make_float4(v0, v1, v2, v3);
                *(float4*)&outf[idx + 4] = make_float4(v4, v5, v6, v7);
            }
        }
    }
}

// ======================================================================
// mdeconv1: ConvTranspose2d(256->256,k4,s2,p1)+bias+ReLU. R1 2-row
// structure + R4 tb-epilogue (full-line dwordx4 stores). grid = 1024.
// ======================================================================
__global__ void __launch_bounds__(256, 3)
mdeconv1_k(const unsigned short* __restrict__ in, const unsigned short* __restrict__ wf,
           const float* __restrict__ bias, unsigned short* __restrict__ out)
{
    int blk = blockIdx.x;
    int bb = blk >> 5;
    int rem = blk & 31;
    int pp = rem >> 4;
    int i = rem & 15;
    int oy_a = pp + 4 * i;
    int p = (oy_a + 1) & 1;
    int r0a = (oy_a + 1 - p) >> 1;
    int rbase = r0a - 1;
    int tid = threadIdx.x;
    int lane = tid & 63;
    int n0 = (tid >> 6) << 6;
    int m = lane & 15, quad = lane >> 4;
    __shared__ __align__(16) unsigned short win[3 * 34 * 264];   // 53.9 KB
    __shared__ __align__(16) unsigned short tb[16 * 264];        // 8.4 KB

    for (int s = tid; s < 3 * 34 * 32; s += 256) {
        int c8 = s & 31;
        int t2 = s >> 5;
        int col = t2 % 34;
        int rr = t2 / 34;
        int ih = rbase + rr, iw = col - 1;
        int4 v = make_int4(0, 0, 0, 0);
        if ((unsigned)ih < 32u && (unsigned)iw < 32u)
            v = *(const int4*)&in[((((bb << 5) + ih) << 5) + iw) * 256 + (c8 << 3)];
        *(int4*)&win[(rr * 34 + col) * 264 + (c8 << 3)] = v;
    }
    __syncthreads();

    for (int par = 0; par < 2; ++par) {
        f32x4 acc[2][2][4];
        f32x4 z = {0.f, 0.f, 0.f, 0.f};
        #pragma unroll
        for (int a = 0; a < 2; ++a)
            #pragma unroll
            for (int i2 = 0; i2 < 2; ++i2)
                #pragma unroll
                for (int t = 0; t < 4; ++t) acc[a][i2][t] = z;

        #pragma unroll
        for (int t = 0; t < 2; ++t) {
            int kh = p + 2 * t;
            #pragma unroll
            for (int u = 0; u < 2; ++u) {
                int kw = (1 - par) + 2 * u;
                int ixoff = par - u + 1;
                #pragma unroll
                for (int cch = 0; cch < 8; ++cch) {
                    const unsigned short* baA = &win[((1 - t) * 34 + m + ixoff) * 264 + (cch << 5) + (quad << 3)];
                    const unsigned short* baB = baA + 34 * 264;
                    bf16x8 a00 = *(const bf16x8*)baA;
                    bf16x8 a01 = *(const bf16x8*)(baA + 16 * 264);
                    bf16x8 a10 = *(const bf16x8*)baB;
                    bf16x8 a11 = *(const bf16x8*)(baB + 16 * 264);
                    int wbase = ((((kh << 2) + kw) * 8 + cch) * 256 + n0 + m) * 32 + (quad << 3);
                    bf16x8 b0 = *(const bf16x8*)&wf[wbase];
                    bf16x8 b1 = *(const bf16x8*)&wf[wbase + 16 * 32];
                    bf16x8 b2 = *(const bf16x8*)&wf[wbase + 32 * 32];
                    bf16x8 b3 = *(const bf16x8*)&wf[wbase + 48 * 32];
                    acc[0][0][0] = MFMA_B16(a00, b0, acc[0][0][0]);
                    acc[0][0][1] = MFMA_B16(a00, b1, acc[0][0][1]);
                    acc[0][0][2] = MFMA_B16(a00, b2, acc[0][0][2]);
                    acc[0][0][3] = MFMA_B16(a00, b3, acc[0][0][3]);
                    acc[0][1][0] = MFMA_B16(a01, b0, acc[0][1][0]);
                    acc[0][1][1] = MFMA_B16(a01, b1, acc[0][1][1]);
                    acc[0][1][2] = MFMA_B16(a01, b2, acc[0][1][2]);
                    acc[0][1][3] = MFMA_B16(a01, b3, acc[0][1][3]);
                    acc[1][0][0] = MFMA_B16(a10, b0, acc[1][0][0]);
                    acc[1][0][1] = MFMA_B16(a10, b1, acc[1][0][1]);
                    acc[1][0][2] = MFMA_B16(a10, b2, acc[1][0][2]);
                    acc[1][0][3] = MFMA_B16(a10, b3, acc[1][0][3]);
                    acc[1][1][0] = MFMA_B16(a11, b0, acc[1][1][0]);
                    acc[1][1][1] = MFMA_B16(a11, b1, acc[1][1][1]);
                    acc[1][1][2] = MFMA_B16(a11, b2, acc[1][1][2]);
                    acc[1][1][3] = MFMA_B16(a11, b3, acc[1][1][3]);
                }
            }
        }

        #pragma unroll
        for (int row = 0; row < 2; ++row) {
            int oy = oy_a + 2 * row;
            #pragma unroll
            for (int mt = 0; mt < 2; ++mt) {
                __syncthreads();
                #pragma unroll
                for (int nt = 0; nt < 4; ++nt) {
                    float bs = bias[n0 + nt * 16 + m];
                    #pragma unroll
                    for (int rr = 0; rr < 4; ++rr) {
                        float v = fmaxf(acc[row][mt][nt][rr] + bs, 0.f);
                        tb[(quad * 4 + rr) * 264 + n0 + nt * 16 + m] = f2b(v);
                    }
                }
                __syncthreads();
                #pragma unroll
                for (int k = 0; k < 2; ++k) {
                    int s = tid + k * 256;
                    int pxl = s >> 5;
                    int c8 = s & 31;
                    int ox = 2 * (mt * 16 + pxl) + par;
                    *(int4*)&out[((((bb << 6) + oy) << 6) + ox) * 256 + (c8 << 3)] =
                        *(const int4*)&tb[pxl * 264 + (c8 << 3)];
                }
            }
        }
    }
}

// ======================================================================
// vqm: MFMA VQ + exact fp32 gather/loss. grid = B*32. Deterministic
// loss partials to lpart[bh*4+wv].
// ======================================================================
__global__ void __launch_bounds__(256, 2)
vqm_k(const unsigned short* __restrict__ zeb, const float* __restrict__ zef,
      const unsigned short* __restrict__ embF, const float* __restrict__ embed,
      const float* __restrict__ nrm, unsigned short* __restrict__ zq,
      float* __restrict__ lpart)
{
    int bh = blockIdx.x;
    int tid = threadIdx.x;
    int lane = tid & 63;
    int wv = tid >> 6;
    int m = lane & 15, quad = lane >> 4;
    __shared__ __align__(16) unsigned short win[32 * 264];
    __shared__ float bvv[4][32];
    __shared__ int   bii[4][32];
    __shared__ int   bidx[32];
    int rowbase = bh << 13;
    for (int s = tid; s < 32 * 32; s += 256) {
        int c8 = s & 31, px = s >> 5;
        *(int4*)&win[px * 264 + (c8 << 3)] = *(const int4*)&zeb[rowbase + (px << 8) + (c8 << 3)];
    }
    __syncthreads();

    f32x4 acc[2][8];
    f32x4 z = {0.f, 0.f, 0.f, 0.f};
    #pragma unroll
    for (int i = 0; i < 2; ++i)
        #pragma unroll
        for (int j = 0; j < 8; ++j) acc[i][j] = z;

    #pragma unroll
    for (int cch = 0; cch < 8; ++cch) {
        bf16x8 a0 = *(const bf16x8*)&win[m * 264 + (cch << 5) + (quad << 3)];
        bf16x8 a1 = *(const bf16x8*)&win[(m + 16) * 264 + (cch << 5) + (quad << 3)];
        #pragma unroll
        for (int nt = 0; nt < 8; ++nt) {
            bf16x8 b = *(const bf16x8*)&embF[((cch << 9) + (wv << 7) + (nt << 4) + m) * 32 + (quad << 3)];
            acc[0][nt] = MFMA_B16(a0, b, acc[0][nt]);
            acc[1][nt] = MFMA_B16(a1, b, acc[1][nt]);
        }
    }

    float nv[8];
    #pragma unroll
    for (int nt = 0; nt < 8; ++nt) nv[nt] = nrm[(wv << 7) + (nt << 4) + m];

    #pragma unroll
    for (int mt = 0; mt < 2; ++mt)
        #pragma unroll
        for (int r = 0; r < 4; ++r) {
            float bv = 1e30f;
            int bi = 0x7fffffff;
            #pragma unroll
            for (int nt = 0; nt < 8; ++nt) {
                float d = nv[nt] - 2.f * acc[mt][nt][r];
                int n = (wv << 7) + (nt << 4) + m;
                if (d < bv || (d == bv && n < bi)) { bv = d; bi = n; }
            }
            #pragma unroll
            for (int off = 1; off < 16; off <<= 1) {
                float ov = __shfl_xor(bv, off);
                int oi = __shfl_xor(bi, off);
                if (ov < bv || (ov == bv && oi < bi)) { bv = ov; bi = oi; }
            }
            if (m == 0) {
                int px = mt * 16 + quad * 4 + r;
                bvv[wv][px] = bv;
                bii[wv][px] = bi;
            }
        }
    __syncthreads();
    if (tid < 32) {
        float bv = bvv[0][tid];
        int bi = bii[0][tid];
        #pragma unroll
        for (int w2 = 1; w2 < 4; ++w2) {
            float ov = bvv[w2][tid];
            int oi = bii[w2][tid];
            if (ov < bv || (ov == bv && oi < bi)) { bv = ov; bi = oi; }
        }
        bidx[tid] = bi;
    }
    __syncthreads();

    float lsum = 0.f;
    #pragma unroll
    for (int j = 0; j < 8; ++j) {
        int px = (wv << 3) + j;
        int bi = bidx[px];
        int pix = (bh << 5) + px;
        const float4 e = *(const float4*)&embed[bi * 256 + (lane << 2)];
        const float4 zv = *(const float4*)&zef[(pix << 8) + (lane << 2)];
        ushort4 eq;
        eq.x = f2b(e.x); eq.y = f2b(e.y); eq.z = f2b(e.z); eq.w = f2b(e.w);
        *(ushort4*)&zq[(pix << 8) + (lane << 2)] = eq;
        float dx = zv.x - e.x, dy = zv.y - e.y, dz = zv.z - e.z, dw = zv.w - e.w;
        lsum += dx * dx + dy * dy + dz * dz + dw * dw;
    }
    #pragma unroll
    for (int off = 1; off < 64; off <<= 1) lsum += __shfl_xor(lsum, off);
    if (lane == 0) lpart[(bh << 2) + wv] = lsum;
}

// ======================================================================
// mdec2a: deconv2 pass 1 — Y[B*64*64, 48] = X[.,256] x Wg[256,48]
// ======================================================================
__global__ void __launch_bounds__(256, 4)
mdec2a_k(const unsigned short* __restrict__ in, const unsigned short* __restrict__ wg,
         float* __restrict__ Y)
{
    int tid = threadIdx.x;
    int lane = tid & 63;
    int wv = tid >> 6;
    int m = lane & 15, quad = lane >> 4;
    __shared__ __align__(16) unsigned short win[64 * 264];
    int pxbase = blockIdx.x << 6;
    for (int s = tid; s < 64 * 32; s += 256) {
        int c8 = s & 31, px = s >> 5;
        *(int4*)&win[px * 264 + (c8 << 3)] = *(const int4*)&in[((pxbase + px) << 8) + (c8 << 3)];
    }
    __syncthreads();
    f32x4 acc[3];
    f32x4 z = {0.f, 0.f, 0.f, 0.f};
    acc[0] = z; acc[1] = z; acc[2] = z;
    #pragma unroll
    for (int cch = 0; cch < 8; ++cch) {
        bf16x8 a = *(const bf16x8*)&win[((wv << 4) + m) * 264 + (cch << 5) + (quad << 3)];
        #pragma unroll
        for (int nt = 0; nt < 3; ++nt) {
            bf16x8 b = *(const bf16x8*)&wg[(cch * 48 + nt * 16 + m) * 32 + (quad << 3)];
            acc[nt] = MFMA_B16(a, b, acc[nt]);
        }
    }
    #pragma unroll
    for (int nt = 0; nt < 3; ++nt)
        #pragma unroll
        for (int r = 0; r < 4; ++r) {
            int px = pxbase + (wv << 4) + quad * 4 + r;
            Y[px * 48 + nt * 16 + m] = acc[nt][r];
        }
}

// ======================================================================
// dec2b: deconv2 pass 2 — gather taps, +bias, sigmoid, NCHW out.
// ======================================================================
__global__ void dec2b_k(const float* __restrict__ Y, const float* __restrict__ bias,
                        float* __restrict__ out)
{
    int idx = blockIdx.x * 256 + threadIdx.x;    // < 524288
    int b = idx >> 14;
    int rem = idx & 16383;
    int oy = rem >> 7;
    int ox = rem & 127;
    int p = (oy + 1) & 1;
    int q = (ox + 1) & 1;
    float acc0 = bias[0], acc1 = bias[1], acc2 = bias[2];
    #pragma unroll
    for (int t = 0; t < 2; ++t) {
        int kh = p + 2 * t;
        int ih = (oy + 1 - kh) >> 1;
        if ((unsigned)ih >= 64u) continue;
        #pragma unroll
        for (int u = 0; u < 2; ++u) {
            int kw = q + 2 * u;
            int iw = (ox + 1 - kw) >> 1;
            if ((unsigned)iw >= 64u) continue;
            int base = ((((b << 6) + ih) << 6) + iw) * 48 + ((kh << 2) + kw) * 3;
            acc0 += Y[base];
            acc1 += Y[base + 1];
            acc2 += Y[base + 2];
        }
    }
    int obase = (b * 3 << 14) + (oy << 7) + ox;
    out[obase]           = 1.f / (1.f + expf(-acc0));
    out[obase + 16384]   = 1.f / (1.f + expf(-acc1));
    out[obase + 32768]   = 1.f / (1.f + expf(-acc2));
}

// ======================================================================
extern "C" void kernel_launch(void* const* d_in, const int* in_sizes, int n_in,
                              void* d_out, int out_size, void* d_ws, size_t ws_size,
                              hipStream_t stream)
{
    (void)in_sizes; (void)n_in; (void)out_size; (void)ws_size;
    const float* x      = (const float*)d_in[0];
    const float* embed  = (const float*)d_in[1];
    const float* e_w1   = (const float*)d_in[2];
    const float* e_w2   = (const float*)d_in[3];
    const float* e_r1a  = (const float*)d_in[4];
    const float* e_r1b  = (const float*)d_in[5];
    const float* e_r2a  = (const float*)d_in[6];
    const float* e_r2b  = (const float*)d_in[7];
    const float* d_r1a  = (const float*)d_in[8];
    const float* d_r1b  = (const float*)d_in[9];
    const float* d_r2a  = (const float*)d_in[10];
    const float* d_r2b  = (const float*)d_in[11];
    const float* dt1_w  = (const float*)d_in[12];
    const float* dt1_b  = (const float*)d_in[13];
    const float* dt2_w  = (const float*)d_in[14];
    const float* dt2_b  = (const float*)d_in[15];
    float* outp = (float*)d_out;

    // ---- workspace layout ----
    char* base = (char*)d_ws;
    size_t off = 0;
    auto alloc = [&](size_t bytes) { char* p = base + off; off += (bytes + 255) & ~size_t(255); return p; };
    unsigned short* A0b = (unsigned short*)alloc(67108864);  // (B,64,64,256) bf16
    float*          A1f = (float*)alloc(33554432);           // ze fp32; later Y
    unsigned short* L0  = (unsigned short*)alloc(16777216);
    unsigned short* L1  = (unsigned short*)alloc(16777216);
    unsigned short* L2  = (unsigned short*)alloc(16777216);  // (unused after R9 fusion; kept)
    unsigned short* Wf  = (unsigned short*)alloc(9437184);   // 10 frag-ordered weights
    unsigned short* Wg  = (unsigned short*)alloc(24576);     // deconv2 frag weights
    unsigned short* EmbF = (unsigned short*)alloc(262144);   // codebook frag bf16
    unsigned short* WgC = (unsigned short*)alloc(32768);     // conv1 frag weights
    float* Nrm  = (float*)alloc(2048);
    float* Lpart = (float*)alloc(16384);                     // 4096 loss partials
    float* Y = A1f;   // alias: ze dead after vqm_k
    (void)L2;

    // frag-weight segment offsets inside Wf (element counts)
    unsigned short* Wf_ew2  = Wf;
    unsigned short* Wf_er1a = Wf + 1048576;
    unsigned short* Wf_er1b = Wf + 1638400;
    unsigned short* Wf_er2a = Wf + 1703936;
    unsigned short* Wf_er2b = Wf + 2293760;
    unsigned short* Wf_dr1a = Wf + 2359296;
    unsigned short* Wf_dr1b = Wf + 2949120;
    unsigned short* Wf_dr2a = Wf + 3014656;
    unsigned short* Wf_dr2b = Wf + 3604480;
    unsigned short* Wf_dt1  = Wf + 3670016;

    PermfArgs pa;
    const float* srcs[10] = {e_w2, e_r1a, e_r1b, e_r2a, e_r2b, d_r1a, d_r1b, d_r2a, d_r2b, dt1_w};
    int kws[10] = {4, 3, 1, 3, 1, 3, 1, 3, 1, 4};
    int sos[10] = {4096, 2304, 256, 2304, 256, 2304, 256, 2304, 256, 16};
    int sis[10] = {16, 9, 1, 9, 1, 9, 1, 9, 1, 4096};
    int shs[10] = {4, 3, 0, 3, 0, 3, 0, 3, 0, 4};
    int sws[10] = {1, 1, 0, 1, 0, 1, 0, 1, 0, 1};
    int cums[11] = {0, 1048576, 1638400, 1703936, 2293760, 2359296,
                    2949120, 3014656, 3604480, 3670016, 4718592};
    for (int k = 0; k < 10; ++k) {
        pa.src[k] = srcs[k]; pa.kw[k] = kws[k]; pa.so[k] = sos[k];
        pa.si[k] = sis[k]; pa.sh[k] = shs[k]; pa.sw[k] = sws[k];
        pa.cum[k] = cums[k];
    }
    pa.cum[10] = cums[10];

    permf_all_k<<<18432, 256, 0, stream>>>(pa, Wf);
    misc_prep_k<<<752, 256, 0, stream>>>(dt2_w, Wg, embed, EmbF, e_w1, WgC, Nrm);

    // ---- encoder ----
    conv1m_k<<<32 * 64, 256, 0, stream>>>(x, WgC, A0b);
    mconv2_k<<<32 * 16, 256, 0, stream>>>(A0b, Wf_ew2, L1);                      // h
    res3_k<<<32 * 32, 256, 0, stream>>>(L1, Wf_er1a, Wf_er1b, L0, nullptr, 0);   // r1 -> L0
    res3_k<<<32 * 32, 256, 0, stream>>>(L0, Wf_er2a, Wf_er2b, L1, A1f, 1);       // ze: bf16->L1, fp32->A1f

    // ---- VQ ----
    vqm_k<<<32 * 32, 256, 0, stream>>>(L1, A1f, EmbF, embed, Nrm, L1, Lpart);

    // ---- decoder ----
    res3_k<<<32 * 32, 256, 0, stream>>>(L1, Wf_dr1a, Wf_dr1b, L0, nullptr, 0);   // d1 -> L0
    res3_k<<<32 * 32, 256, 0, stream>>>(L0, Wf_dr2a, Wf_dr2b, L1, nullptr, 0);   // d2 -> L1
    mdeconv1_k<<<32 * 32, 256, 0, stream>>>(L1, Wf_dt1, dt1_b, A0b);
    mdec2a_k<<<2048, 256, 0, stream>>>(A0b, Wg, Y);
    dec2b_k<<<2048, 256, 0, stream>>>(Y, dt2_b, outp);
    lossfin_k<<<1, 256, 0, stream>>>(Lpart, outp);
}

// Round 14
// 709.994 us; speedup vs baseline: 1.2854x; 1.0052x over previous
//
#include <hip/hip_runtime.h>

// ======================================================================
// VQ-VAE forward, all-MFMA. B=32, CIN=3, IMG=128, D=256, K=512.
// NHWC bf16 activations. Weights frag-ordered Wf[khkw][cch][n][32].
// MFMA 16x16x32 bf16: A[m=lane&15][k=quad*8+j], B[n][k], D col=lane&15,
// row=quad*4+reg.
// R4: mdeconv1 tb-epilogue. R6: deterministic loss. R9: fused residual
// block. R11: res3 full-line epilogue. R12: res3 M=32 (occupancy 2->4
// blk/CU) = NEUTRAL (-5us): TLP is not the binder for these kernels.
// R13: mconv2 restructure — launch_bounds(256,2) (VGPR 56->128; grid=512
// means 2 blk/CU regardless, cap was free), full-channel staging (2 rows
// x 66 x 256ch = 68KB, kh-phases 8->4, half the barrier drains), and
// flattened (kw,cch) loop with explicit B-frag register prefetch (the
// 56-VGPR build serialized 16 L2 round-trips per phase).
// ======================================================================

typedef __attribute__((ext_vector_type(8))) short bf16x8;
typedef __attribute__((ext_vector_type(4))) float f32x4;
#define MFMA_B16(a, b, c) __builtin_amdgcn_mfma_f32_16x16x32_bf16(a, b, c, 0, 0, 0)

__device__ inline unsigned short f2b(float f) {
    unsigned int u = __float_as_uint(f);
    unsigned int r = u + 0x7fffu + ((u >> 16) & 1u);
    return (unsigned short)(r >> 16);
}
__device__ inline float b2f(unsigned short u) {
    return __uint_as_float(((unsigned int)u) << 16);
}

// ======================================================================
// batched bf16 frag-order weight permute for the 10 conv/deconv weights.
// ======================================================================
struct PermfArgs {
    const float* src[10];
    int kw[10];
    int so[10], si[10], sh[10], sw[10];
    int cum[11];
};

__global__ void permf_all_k(PermfArgs a, unsigned short* __restrict__ dst)
{
    int gid = blockIdx.x * 256 + threadIdx.x;
    if (gid >= a.cum[10]) return;
    int seg = 0;
    while (seg < 9 && gid >= a.cum[seg + 1]) ++seg;
    int l = gid - a.cum[seg];
    int q = l & 31;
    int n = (l >> 5) & 255;
    int rest = l >> 13;
    int cch = rest & 7;
    int khkw = rest >> 3;
    int kh = khkw / a.kw[seg], kw = khkw % a.kw[seg];
    int ci = cch * 32 + q;
    dst[gid] = f2b(a.src[seg][n * a.so[seg] + ci * a.si[seg] + kh * a.sh[seg] + kw * a.sw[seg]]);
}

// ======================================================================
// misc prep: deconv2 frag weights, codebook frag, conv1 frag weights,
// codebook norms. 752 blocks x 256.
// ======================================================================
__global__ void misc_prep_k(const float* __restrict__ dt2_w, unsigned short* __restrict__ wg,
                            const float* __restrict__ embed, unsigned short* __restrict__ embF,
                            const float* __restrict__ e_w1, unsigned short* __restrict__ wgc,
                            float* __restrict__ nrm)
{
    int blk = blockIdx.x, tid = threadIdx.x;
    if (blk < 48) {
        int idx = blk * 256 + tid;        // < 12288
        int q = idx & 31;
        int n = (idx >> 5) % 48;
        int cch = idx / (48 * 32);
        int ci = cch * 32 + q;
        int oc = n % 3, khkw = n / 3;
        int kh = khkw >> 2, kw = khkw & 3;
        wg[idx] = f2b(dt2_w[ci * 48 + oc * 16 + kh * 4 + kw]);
    } else if (blk < 560) {
        int idx = (blk - 48) * 256 + tid; // < 131072
        int q = idx & 31;
        int n = (idx >> 5) & 511;
        int cch = idx >> 14;
        embF[idx] = f2b(embed[n * 256 + cch * 32 + q]);
    } else if (blk < 624) {
        int idx = (blk - 560) * 256 + tid;  // < 16384
        int q = idx & 31;
        int n = (idx >> 5) & 255;
        int kt = idx >> 13;
        int k = kt * 32 + q;
        float v = 0.f;
        if (k < 48) {
            int ci = k >> 4, kh = (k >> 2) & 3, kwv = k & 3;
            v = e_w1[n * 48 + ci * 16 + kh * 4 + kwv];
        }
        wgc[idx] = f2b(v);
    } else {
        int row = (blk - 624) * 4 + (tid >> 6);
        int lane = tid & 63;
        float s = 0.f;
        #pragma unroll
        for (int c = 0; c < 256; c += 64) {
            float v = embed[row * 256 + c + lane];
            s += v * v;
        }
        #pragma unroll
        for (int off = 1; off < 64; off <<= 1) s += __shfl_xor(s, off);
        if (lane == 0) nrm[row] = s;
    }
}

// ======================================================================
// lossfin: deterministic fixed-order reduction of 4096 wave-partials.
// ======================================================================
__global__ void lossfin_k(const float* __restrict__ lpart, float* __restrict__ out)
{
    __shared__ float red[256];
    int tid = threadIdx.x;
    float s = 0.f;
    #pragma unroll
    for (int i = 0; i < 16; ++i) s += lpart[tid * 16 + i];
    red[tid] = s;
    __syncthreads();
    for (int off = 128; off > 0; off >>= 1) {
        if (tid < off) red[tid] += red[tid + off];
        __syncthreads();
    }
    if (tid == 0) {
        float m = red[0] * (1.0f / 32768.0f);
        out[1572864] = m;
        out[1572865] = m;
    }
}

// ======================================================================
// conv1m: MFMA im2col conv1. x NCHW fp32 -> NHWC bf16 (B,64,64,256),
// k4 s2 p1, ReLU. grid = B*64.
// ======================================================================
__global__ void __launch_bounds__(256, 4)
conv1m_k(const float* __restrict__ x, const unsigned short* __restrict__ wgc,
         unsigned short* __restrict__ out)
{
    int bh = blockIdx.x;             // b*64 + oh
    int b = bh >> 6, oh = bh & 63;
    int tid = threadIdx.x;
    int lane = tid & 63, wv = tid >> 6;
    int m = lane & 15, quad = lane >> 4;
    __shared__ float xrow[3][4][130];
    __shared__ __align__(16) unsigned short imc[64 * 72];
    for (int s = tid; s < 1560; s += 256) {
        int col = s % 130;
        int t = s / 130;
        int r = t & 3;
        int c = t >> 2;
        int ih = 2 * oh - 1 + r, iw = col - 1;
        float v = 0.f;
        if ((unsigned)ih < 128u && (unsigned)iw < 128u)
            v = x[(((b * 3 + c) << 7) + ih) * 128 + iw];
        xrow[c][r][col] = v;
    }
    __syncthreads();
    for (int s = tid; s < 4096; s += 256) {
        int px = s >> 6, k = s & 63;
        float v = 0.f;
        if (k < 48) {
            int ci = k >> 4, kh = (k >> 2) & 3, kw = k & 3;
            v = xrow[ci][kh][2 * px + kw];
        }
        imc[px * 72 + k] = f2b(v);
    }
    __syncthreads();
    f32x4 acc[16];
    f32x4 z = {0.f, 0.f, 0.f, 0.f};
    #pragma unroll
    for (int i = 0; i < 16; ++i) acc[i] = z;
    bf16x8 a0 = *(const bf16x8*)&imc[((wv << 4) + m) * 72 + (quad << 3)];
    bf16x8 a1 = *(const bf16x8*)&imc[((wv << 4) + m) * 72 + 32 + (quad << 3)];
    #pragma unroll
    for (int nt = 0; nt < 16; ++nt) {
        bf16x8 b0 = *(const bf16x8*)&wgc[(nt * 16 + m) * 32 + (quad << 3)];
        bf16x8 b1 = *(const bf16x8*)&wgc[(256 + nt * 16 + m) * 32 + (quad << 3)];
        acc[nt] = MFMA_B16(a0, b0, acc[nt]);
        acc[nt] = MFMA_B16(a1, b1, acc[nt]);
    }
    #pragma unroll
    for (int nt = 0; nt < 16; ++nt)
        #pragma unroll
        for (int r = 0; r < 4; ++r) {
            int px = (wv << 4) + quad * 4 + r;
            out[(((bh << 6) + px) << 8) + nt * 16 + (lane & 15)] = f2b(fmaxf(acc[nt][r], 0.f));
        }
}

// ======================================================================
// mconv2: k4 s2 p1, (B,64,64,256)->(B,32,32,256), ReLU. M=64. grid B*16.
// R13: full-channel staging (2 rows x 66 x 256ch = 68KB, 4 kh-phases),
// launch_bounds(256,2) for VGPR headroom, flattened (kw,cch) loop with
// B-frag register prefetch to hide L2 latency under MFMA.
// ======================================================================
__global__ void __launch_bounds__(256, 2)
mconv2_k(const unsigned short* __restrict__ in, const unsigned short* __restrict__ wf,
         unsigned short* __restrict__ out)
{
    int blk = blockIdx.x;
    int bb = blk >> 4, j = blk & 15;
    int lane = threadIdx.x & 63;
    int n0 = (threadIdx.x >> 6) << 6;
    int m = lane & 15, quad = lane >> 4;
    __shared__ __align__(16) unsigned short win[2 * 66 * 264];  // 68.1 KB
    f32x4 acc[2][2][4];
    f32x4 z = {0.f, 0.f, 0.f, 0.f};
    #pragma unroll
    for (int a = 0; a < 2; ++a)
        #pragma unroll
        for (int i = 0; i < 2; ++i)
            #pragma unroll
            for (int t = 0; t < 4; ++t) acc[a][i][t] = z;

    for (int kh = 0; kh < 4; ++kh) {
        __syncthreads();
        for (int s = threadIdx.x; s < 2 * 66 * 32; s += 256) {
            int c32 = s & 31;
            int t2 = s >> 5;
            int col = t2 % 66;
            int rr = t2 / 66;
            int ih = 4 * j - 1 + kh + 2 * rr, iw = col - 1;
            int4 v = make_int4(0, 0, 0, 0);
            if ((unsigned)ih < 64u && (unsigned)iw < 64u)
                v = *(const int4*)&in[((((bb << 6) + ih) << 6) + iw) * 256 + (c32 << 3)];
            int cs = (col >> 1) + (col & 1) * 33;
            *(int4*)&win[(rr * 66 + cs) * 264 + (c32 << 3)] = v;
        }
        __syncthreads();
        // flattened it = kw*8 + cch (32 iterations), B-frags prefetched
        int wb0 = (((kh << 2) + 0) * 8 + 0) * 256;   // khkw base for kw=0
        const unsigned short* wrow = &wf[(wb0 + n0 + m) * 32 + (quad << 3)];
        bf16x8 nb0 = *(const bf16x8*)wrow;
        bf16x8 nb1 = *(const bf16x8*)(wrow + 16 * 32);
        bf16x8 nb2 = *(const bf16x8*)(wrow + 32 * 32);
        bf16x8 nb3 = *(const bf16x8*)(wrow + 48 * 32);
        #pragma unroll
        for (int it = 0; it < 32; ++it) {
            bf16x8 cb0 = nb0, cb1 = nb1, cb2 = nb2, cb3 = nb3;
            if (it < 31) {
                int it2 = it + 1;
                int kw2 = it2 >> 3, cch2 = it2 & 7;
                const unsigned short* wp =
                    &wf[((((kh << 2) + kw2) * 8 + cch2) * 256 + n0 + m) * 32 + (quad << 3)];
                nb0 = *(const bf16x8*)wp;
                nb1 = *(const bf16x8*)(wp + 16 * 32);
                nb2 = *(const bf16x8*)(wp + 32 * 32);
                nb3 = *(const bf16x8*)(wp + 48 * 32);
            }
            int kw = it >> 3, cch = it & 7;
            int csoff = (kw >> 1) + (kw & 1) * 33;
            const unsigned short* ba = &win[(m + csoff) * 264 + (cch << 5) + (quad << 3)];
            bf16x8 a00 = *(const bf16x8*)ba;
            bf16x8 a01 = *(const bf16x8*)(ba + 16 * 264);
            bf16x8 a10 = *(const bf16x8*)(ba + 66 * 264);
            bf16x8 a11 = *(const bf16x8*)(ba + 82 * 264);
            acc[0][0][0] = MFMA_B16(a00, cb0, acc[0][0][0]);
            acc[0][0][1] = MFMA_B16(a00, cb1, acc[0][0][1]);
            acc[0][0][2] = MFMA_B16(a00, cb2, acc[0][0][2]);
            acc[0][0][3] = MFMA_B16(a00, cb3, acc[0][0][3]);
            acc[0][1][0] = MFMA_B16(a01, cb0, acc[0][1][0]);
            acc[0][1][1] = MFMA_B16(a01, cb1, acc[0][1][1]);
            acc[0][1][2] = MFMA_B16(a01, cb2, acc[0][1][2]);
            acc[0][1][3] = MFMA_B16(a01, cb3, acc[0][1][3]);
            acc[1][0][0] = MFMA_B16(a10, cb0, acc[1][0][0]);
            acc[1][0][1] = MFMA_B16(a10, cb1, acc[1][0][1]);
            acc[1][0][2] = MFMA_B16(a10, cb2, acc[1][0][2]);
            acc[1][0][3] = MFMA_B16(a10, cb3, acc[1][0][3]);
            acc[1][1][0] = MFMA_B16(a11, cb0, acc[1][1][0]);
            acc[1][1][1] = MFMA_B16(a11, cb1, acc[1][1][1]);
            acc[1][1][2] = MFMA_B16(a11, cb2, acc[1][1][2]);
            acc[1][1][3] = MFMA_B16(a11, cb3, acc[1][1][3]);
        }
    }
    #pragma unroll
    for (int row = 0; row < 2; ++row) {
        int oh = 2 * j + row;
        #pragma unroll
        for (int mt = 0; mt < 2; ++mt)
            #pragma unroll
            for (int nt = 0; nt < 4; ++nt)
                #pragma unroll
                for (int r = 0; r < 4; ++r) {
                    int px = mt * 16 + quad * 4 + r;
                    int col = n0 + nt * 16 + m;
                    out[((((bb << 5) + oh) << 5) + px) * 256 + col] = f2b(fmaxf(acc[row][mt][nt][r], 0.f));
                }
    }
}

// ======================================================================
// res3: FUSED residual block, M=32 (one output row per block).
// grid = B*32 = 1024. Part 1 = 3x3 conv (stage 3 rows x 34 x 128ch);
// handoff ReLU'd out -> LDS bf16 [32][264]; Part 2 = 1x1 from LDS;
// epilogue: fp32 spill halves + coalesced full-line IO.
// ======================================================================
__global__ void __launch_bounds__(256, 4)
res3_k(const unsigned short* __restrict__ in, const unsigned short* __restrict__ wfA,
       const unsigned short* __restrict__ wfB, unsigned short* __restrict__ outb,
       float* __restrict__ outf, int f32out)
{
    int blk = blockIdx.x;
    int bb = blk >> 5, j = blk & 31;      // output row j
    int tid = threadIdx.x;
    int lane = tid & 63;
    int n0 = (tid >> 6) << 6;
    int m = lane & 15, quad = lane >> 4;
    __shared__ __align__(16) unsigned short win[3 * 34 * 132];  // 26.9 KB
    f32x4 acc[2][4];
    f32x4 z = {0.f, 0.f, 0.f, 0.f};
    #pragma unroll
    for (int i = 0; i < 2; ++i)
        #pragma unroll
        for (int t = 0; t < 4; ++t) acc[i][t] = z;

    // ---- part 1: 3x3 conv, 2 channel phases ----
    for (int c0 = 0; c0 < 256; c0 += 128) {
        __syncthreads();
        for (int s = tid; s < 3 * 34 * 16; s += 256) {
            int c16 = s & 15;
            int t2 = s >> 4;
            int col = t2 % 34;
            int rr = t2 / 34;
            int ih = j - 1 + rr, iw = col - 1;
            int4 v = make_int4(0, 0, 0, 0);
            if ((unsigned)ih < 32u && (unsigned)iw < 32u)
                v = *(const int4*)&in[((((bb << 5) + ih) << 5) + iw) * 256 + c0 + (c16 << 3)];
            *(int4*)&win[(rr * 34 + col) * 132 + (c16 << 3)] = v;
        }
        __syncthreads();
        for (int kh = 0; kh < 3; ++kh) {
            #pragma unroll
            for (int kw = 0; kw < 3; ++kw) {
                #pragma unroll
                for (int cch = 0; cch < 4; ++cch) {
                    const unsigned short* ba = &win[(kh * 34 + m + kw) * 132 + (cch << 5) + (quad << 3)];
                    bf16x8 a0 = *(const bf16x8*)ba;
                    bf16x8 a1 = *(const bf16x8*)(ba + 16 * 132);
                    int cg = (c0 >> 5) + cch;
                    int wbase = (((kh * 3 + kw) * 8 + cg) * 256 + n0 + m) * 32 + (quad << 3);
                    bf16x8 b0 = *(const bf16x8*)&wfA[wbase];
                    bf16x8 b1 = *(const bf16x8*)&wfA[wbase + 16 * 32];
                    bf16x8 b2 = *(const bf16x8*)&wfA[wbase + 32 * 32];
                    bf16x8 b3 = *(const bf16x8*)&wfA[wbase + 48 * 32];
                    acc[0][0] = MFMA_B16(a0, b0, acc[0][0]);
                    acc[0][1] = MFMA_B16(a0, b1, acc[0][1]);
                    acc[0][2] = MFMA_B16(a0, b2, acc[0][2]);
                    acc[0][3] = MFMA_B16(a0, b3, acc[0][3]);
                    acc[1][0] = MFMA_B16(a1, b0, acc[1][0]);
                    acc[1][1] = MFMA_B16(a1, b1, acc[1][1]);
                    acc[1][2] = MFMA_B16(a1, b2, acc[1][2]);
                    acc[1][3] = MFMA_B16(a1, b3, acc[1][3]);
                }
            }
        }
    }

    // ---- handoff: ReLU(conv3) -> LDS bf16 [32][264] (alias over win) ----
    __syncthreads();   // all waves done reading win
    #pragma unroll
    for (int i = 0; i < 2; ++i)
        #pragma unroll
        for (int nt = 0; nt < 4; ++nt)
            #pragma unroll
            for (int r = 0; r < 4; ++r) {
                int p = i * 16 + quad * 4 + r;       // 0..31
                win[p * 264 + n0 + nt * 16 + m] = f2b(fmaxf(acc[i][nt][r], 0.f));
            }
    __syncthreads();   // handoff complete

    // ---- part 2: 1x1 matmul from LDS ----
    f32x4 acc2[2][4];
    #pragma unroll
    for (int i = 0; i < 2; ++i)
        #pragma unroll
        for (int t = 0; t < 4; ++t) acc2[i][t] = z;

    #pragma unroll
    for (int cch = 0; cch < 8; ++cch) {
        bf16x8 a0 = *(const bf16x8*)&win[m * 264 + (cch << 5) + (quad << 3)];
        bf16x8 a1 = *(const bf16x8*)&win[(m + 16) * 264 + (cch << 5) + (quad << 3)];
        int wbase = (cch * 256 + n0 + m) * 32 + (quad << 3);
        bf16x8 b0 = *(const bf16x8*)&wfB[wbase];
        bf16x8 b1 = *(const bf16x8*)&wfB[wbase + 16 * 32];
        bf16x8 b2 = *(const bf16x8*)&wfB[wbase + 32 * 32];
        bf16x8 b3 = *(const bf16x8*)&wfB[wbase + 48 * 32];
        acc2[0][0] = MFMA_B16(a0, b0, acc2[0][0]);
        acc2[0][1] = MFMA_B16(a0, b1, acc2[0][1]);
        acc2[0][2] = MFMA_B16(a0, b2, acc2[0][2]);
        acc2[0][3] = MFMA_B16(a0, b3, acc2[0][3]);
        acc2[1][0] = MFMA_B16(a1, b0, acc2[1][0]);
        acc2[1][1] = MFMA_B16(a1, b1, acc2[1][1]);
        acc2[1][2] = MFMA_B16(a1, b2, acc2[1][2]);
        acc2[1][3] = MFMA_B16(a1, b3, acc2[1][3]);
    }

    // ---- epilogue: fp32 LDS spill (16-px halves) -> coalesced IO ----
    float* winf = (float*)win;         // 16*260 floats = 16.6 KB <= 26.9 KB
    int rowbase = blk << 13;           // 32 px * 256
    #pragma unroll
    for (int half = 0; half < 2; ++half) {
        __syncthreads();   // winf free
        #pragma unroll
        for (int nt = 0; nt < 4; ++nt)
            #pragma unroll
            for (int r = 0; r < 4; ++r) {
                int pxl = quad * 4 + r;              // 0..15
                winf[pxl * 260 + n0 + nt * 16 + m] = acc2[half][nt][r];
            }
        __syncthreads();   // winf ready
        #pragma unroll
        for (int k = 0; k < 2; ++k) {
            int s = tid + k * 256;
            int pxl = s >> 5;          // 0..15
            int c8 = s & 31;           // 8-channel group
            int px = half * 16 + pxl;
            int idx = rowbase + (px << 8) + (c8 << 3);
            int4 rv = *(const int4*)&in[idx];          // 8 bf16 residual
            const float* wp = &winf[pxl * 260 + (c8 << 3)];
            float v0 = wp[0] + b2f((unsigned short)((unsigned)rv.x & 0xffffu));
            float v1 = wp[1] + b2f((unsigned short)((unsigned)rv.x >> 16));
            float v2 = wp[2] + b2f((unsigned short)((unsigned)rv.y & 0xffffu));
            float v3 = wp[3] + b2f((unsigned short)((unsigned)rv.y >> 16));
            float v4 = wp[4] + b2f((unsigned short)((unsigned)rv.z & 0xffffu));
            float v5 = wp[5] + b2f((unsigned short)((unsigned)rv.z >> 16));
            float v6 = wp[6] + b2f((unsigned short)((unsigned)rv.w & 0xffffu));
            float v7 = wp[7] + b2f((unsigned short)((unsigned)rv.w >> 16));
            unsigned w0 = (unsigned)f2b(v0) | ((unsigned)f2b(v1) << 16);
            unsigned w1 = (unsigned)f2b(v2) | ((unsigned)f2b(v3) << 16);
            unsigned w2 = (unsigned)f2b(v4) | ((unsigned)f2b(v5) << 16);
            unsigned w3 = (unsigned)f2b(v6) | ((unsigned)f2b(v7) << 16);
            *(int4*)&outb[idx] = make_int4((int)w0, (int)w1, (int)w2, (int)w3);
            if (f32out) {
                *(float4*)&outf[idx]     = make_float4(v0, v1, v2, v3);
                *(float4*)&outf[idx + 4] = make_float4(v4, v5, v6, v7);
            }
        }
    }
}

// ======================================================================
// mdeconv1: ConvTranspose2d(256->256,k4,s2,p1)+bias+ReLU. R1 2-row
// structure + R4 tb-epilogue (full-line dwordx4 stores). grid = 1024.
// ======================================================================
__global__ void __launch_bounds__(256, 3)
mdeconv1_k(const unsigned short* __restrict__ in, const unsigned short* __restrict__ wf,
           const float* __restrict__ bias, unsigned short* __restrict__ out)
{
    int blk = blockIdx.x;
    int bb = blk >> 5;
    int rem = blk & 31;
    int pp = rem >> 4;
    int i = rem & 15;
    int oy_a = pp + 4 * i;
    int p = (oy_a + 1) & 1;
    int r0a = (oy_a + 1 - p) >> 1;
    int rbase = r0a - 1;
    int tid = threadIdx.x;
    int lane = tid & 63;
    int n0 = (tid >> 6) << 6;
    int m = lane & 15, quad = lane >> 4;
    __shared__ __align__(16) unsigned short win[3 * 34 * 264];   // 53.9 KB
    __shared__ __align__(16) unsigned short tb[16 * 264];        // 8.4 KB

    for (int s = tid; s < 3 * 34 * 32; s += 256) {
        int c8 = s & 31;
        int t2 = s >> 5;
        int col = t2 % 34;
        int rr = t2 / 34;
        int ih = rbase + rr, iw = col - 1;
        int4 v = make_int4(0, 0, 0, 0);
        if ((unsigned)ih < 32u && (unsigned)iw < 32u)
            v = *(const int4*)&in[((((bb << 5) + ih) << 5) + iw) * 256 + (c8 << 3)];
        *(int4*)&win[(rr * 34 + col) * 264 + (c8 << 3)] = v;
    }
    __syncthreads();

    for (int par = 0; par < 2; ++par) {
        f32x4 acc[2][2][4];
        f32x4 z = {0.f, 0.f, 0.f, 0.f};
        #pragma unroll
        for (int a = 0; a < 2; ++a)
            #pragma unroll
            for (int i2 = 0; i2 < 2; ++i2)
                #pragma unroll
                for (int t = 0; t < 4; ++t) acc[a][i2][t] = z;

        #pragma unroll
        for (int t = 0; t < 2; ++t) {
            int kh = p + 2 * t;
            #pragma unroll
            for (int u = 0; u < 2; ++u) {
                int kw = (1 - par) + 2 * u;
                int ixoff = par - u + 1;
                #pragma unroll
                for (int cch = 0; cch < 8; ++cch) {
                    const unsigned short* baA = &win[((1 - t) * 34 + m + ixoff) * 264 + (cch << 5) + (quad << 3)];
                    const unsigned short* baB = baA + 34 * 264;
                    bf16x8 a00 = *(const bf16x8*)baA;
                    bf16x8 a01 = *(const bf16x8*)(baA + 16 * 264);
                    bf16x8 a10 = *(const bf16x8*)baB;
                    bf16x8 a11 = *(const bf16x8*)(baB + 16 * 264);
                    int wbase = ((((kh << 2) + kw) * 8 + cch) * 256 + n0 + m) * 32 + (quad << 3);
                    bf16x8 b0 = *(const bf16x8*)&wf[wbase];
                    bf16x8 b1 = *(const bf16x8*)&wf[wbase + 16 * 32];
                    bf16x8 b2 = *(const bf16x8*)&wf[wbase + 32 * 32];
                    bf16x8 b3 = *(const bf16x8*)&wf[wbase + 48 * 32];
                    acc[0][0][0] = MFMA_B16(a00, b0, acc[0][0][0]);
                    acc[0][0][1] = MFMA_B16(a00, b1, acc[0][0][1]);
                    acc[0][0][2] = MFMA_B16(a00, b2, acc[0][0][2]);
                    acc[0][0][3] = MFMA_B16(a00, b3, acc[0][0][3]);
                    acc[0][1][0] = MFMA_B16(a01, b0, acc[0][1][0]);
                    acc[0][1][1] = MFMA_B16(a01, b1, acc[0][1][1]);
                    acc[0][1][2] = MFMA_B16(a01, b2, acc[0][1][2]);
                    acc[0][1][3] = MFMA_B16(a01, b3, acc[0][1][3]);
                    acc[1][0][0] = MFMA_B16(a10, b0, acc[1][0][0]);
                    acc[1][0][1] = MFMA_B16(a10, b1, acc[1][0][1]);
                    acc[1][0][2] = MFMA_B16(a10, b2, acc[1][0][2]);
                    acc[1][0][3] = MFMA_B16(a10, b3, acc[1][0][3]);
                    acc[1][1][0] = MFMA_B16(a11, b0, acc[1][1][0]);
                    acc[1][1][1] = MFMA_B16(a11, b1, acc[1][1][1]);
                    acc[1][1][2] = MFMA_B16(a11, b2, acc[1][1][2]);
                    acc[1][1][3] = MFMA_B16(a11, b3, acc[1][1][3]);
                }
            }
        }

        #pragma unroll
        for (int row = 0; row < 2; ++row) {
            int oy = oy_a + 2 * row;
            #pragma unroll
            for (int mt = 0; mt < 2; ++mt) {
                __syncthreads();
                #pragma unroll
                for (int nt = 0; nt < 4; ++nt) {
                    float bs = bias[n0 + nt * 16 + m];
                    #pragma unroll
                    for (int rr = 0; rr < 4; ++rr) {
                        float v = fmaxf(acc[row][mt][nt][rr] + bs, 0.f);
                        tb[(quad * 4 + rr) * 264 + n0 + nt * 16 + m] = f2b(v);
                    }
                }
                __syncthreads();
                #pragma unroll
                for (int k = 0; k < 2; ++k) {
                    int s = tid + k * 256;
                    int pxl = s >> 5;
                    int c8 = s & 31;
                    int ox = 2 * (mt * 16 + pxl) + par;
                    *(int4*)&out[((((bb << 6) + oy) << 6) + ox) * 256 + (c8 << 3)] =
                        *(const int4*)&tb[pxl * 264 + (c8 << 3)];
                }
            }
        }
    }
}

// ======================================================================
// vqm: MFMA VQ + exact fp32 gather/loss. grid = B*32. Deterministic
// loss partials to lpart[bh*4+wv].
// ======================================================================
__global__ void __launch_bounds__(256, 2)
vqm_k(const unsigned short* __restrict__ zeb, const float* __restrict__ zef,
      const unsigned short* __restrict__ embF, const float* __restrict__ embed,
      const float* __restrict__ nrm, unsigned short* __restrict__ zq,
      float* __restrict__ lpart)
{
    int bh = blockIdx.x;
    int tid = threadIdx.x;
    int lane = tid & 63;
    int wv = tid >> 6;
    int m = lane & 15, quad = lane >> 4;
    __shared__ __align__(16) unsigned short win[32 * 264];
    __shared__ float bvv[4][32];
    __shared__ int   bii[4][32];
    __shared__ int   bidx[32];
    int rowbase = bh << 13;
    for (int s = tid; s < 32 * 32; s += 256) {
        int c8 = s & 31, px = s >> 5;
        *(int4*)&win[px * 264 + (c8 << 3)] = *(const int4*)&zeb[rowbase + (px << 8) + (c8 << 3)];
    }
    __syncthreads();

    f32x4 acc[2][8];
    f32x4 z = {0.f, 0.f, 0.f, 0.f};
    #pragma unroll
    for (int i = 0; i < 2; ++i)
        #pragma unroll
        for (int j = 0; j < 8; ++j) acc[i][j] = z;

    #pragma unroll
    for (int cch = 0; cch < 8; ++cch) {
        bf16x8 a0 = *(const bf16x8*)&win[m * 264 + (cch << 5) + (quad << 3)];
        bf16x8 a1 = *(const bf16x8*)&win[(m + 16) * 264 + (cch << 5) + (quad << 3)];
        #pragma unroll
        for (int nt = 0; nt < 8; ++nt) {
            bf16x8 b = *(const bf16x8*)&embF[((cch << 9) + (wv << 7) + (nt << 4) + m) * 32 + (quad << 3)];
            acc[0][nt] = MFMA_B16(a0, b, acc[0][nt]);
            acc[1][nt] = MFMA_B16(a1, b, acc[1][nt]);
        }
    }

    float nv[8];
    #pragma unroll
    for (int nt = 0; nt < 8; ++nt) nv[nt] = nrm[(wv << 7) + (nt << 4) + m];

    #pragma unroll
    for (int mt = 0; mt < 2; ++mt)
        #pragma unroll
        for (int r = 0; r < 4; ++r) {
            float bv = 1e30f;
            int bi = 0x7fffffff;
            #pragma unroll
            for (int nt = 0; nt < 8; ++nt) {
                float d = nv[nt] - 2.f * acc[mt][nt][r];
                int n = (wv << 7) + (nt << 4) + m;
                if (d < bv || (d == bv && n < bi)) { bv = d; bi = n; }
            }
            #pragma unroll
            for (int off = 1; off < 16; off <<= 1) {
                float ov = __shfl_xor(bv, off);
                int oi = __shfl_xor(bi, off);
                if (ov < bv || (ov == bv && oi < bi)) { bv = ov; bi = oi; }
            }
            if (m == 0) {
                int px = mt * 16 + quad * 4 + r;
                bvv[wv][px] = bv;
                bii[wv][px] = bi;
            }
        }
    __syncthreads();
    if (tid < 32) {
        float bv = bvv[0][tid];
        int bi = bii[0][tid];
        #pragma unroll
        for (int w2 = 1; w2 < 4; ++w2) {
            float ov = bvv[w2][tid];
            int oi = bii[w2][tid];
            if (ov < bv || (ov == bv && oi < bi)) { bv = ov; bi = oi; }
        }
        bidx[tid] = bi;
    }
    __syncthreads();

    float lsum = 0.f;
    #pragma unroll
    for (int j = 0; j < 8; ++j) {
        int px = (wv << 3) + j;
        int bi = bidx[px];
        int pix = (bh << 5) + px;
        const float4 e = *(const float4*)&embed[bi * 256 + (lane << 2)];
        const float4 zv = *(const float4*)&zef[(pix << 8) + (lane << 2)];
        ushort4 eq;
        eq.x = f2b(e.x); eq.y = f2b(e.y); eq.z = f2b(e.z); eq.w = f2b(e.w);
        *(ushort4*)&zq[(pix << 8) + (lane << 2)] = eq;
        float dx = zv.x - e.x, dy = zv.y - e.y, dz = zv.z - e.z, dw = zv.w - e.w;
        lsum += dx * dx + dy * dy + dz * dz + dw * dw;
    }
    #pragma unroll
    for (int off = 1; off < 64; off <<= 1) lsum += __shfl_xor(lsum, off);
    if (lane == 0) lpart[(bh << 2) + wv] = lsum;
}

// ======================================================================
// mdec2a: deconv2 pass 1 — Y[B*64*64, 48] = X[.,256] x Wg[256,48]
// ======================================================================
__global__ void __launch_bounds__(256, 4)
mdec2a_k(const unsigned short* __restrict__ in, const unsigned short* __restrict__ wg,
         float* __restrict__ Y)
{
    int tid = threadIdx.x;
    int lane = tid & 63;
    int wv = tid >> 6;
    int m = lane & 15, quad = lane >> 4;
    __shared__ __align__(16) unsigned short win[64 * 264];
    int pxbase = blockIdx.x << 6;
    for (int s = tid; s < 64 * 32; s += 256) {
        int c8 = s & 31, px = s >> 5;
        *(int4*)&win[px * 264 + (c8 << 3)] = *(const int4*)&in[((pxbase + px) << 8) + (c8 << 3)];
    }
    __syncthreads();
    f32x4 acc[3];
    f32x4 z = {0.f, 0.f, 0.f, 0.f};
    acc[0] = z; acc[1] = z; acc[2] = z;
    #pragma unroll
    for (int cch = 0; cch < 8; ++cch) {
        bf16x8 a = *(const bf16x8*)&win[((wv << 4) + m) * 264 + (cch << 5) + (quad << 3)];
        #pragma unroll
        for (int nt = 0; nt < 3; ++nt) {
            bf16x8 b = *(const bf16x8*)&wg[(cch * 48 + nt * 16 + m) * 32 + (quad << 3)];
            acc[nt] = MFMA_B16(a, b, acc[nt]);
        }
    }
    #pragma unroll
    for (int nt = 0; nt < 3; ++nt)
        #pragma unroll
        for (int r = 0; r < 4; ++r) {
            int px = pxbase + (wv << 4) + quad * 4 + r;
            Y[px * 48 + nt * 16 + m] = acc[nt][r];
        }
}

// ======================================================================
// dec2b: deconv2 pass 2 — gather taps, +bias, sigmoid, NCHW out.
// ======================================================================
__global__ void dec2b_k(const float* __restrict__ Y, const float* __restrict__ bias,
                        float* __restrict__ out)
{
    int idx = blockIdx.x * 256 + threadIdx.x;    // < 524288
    int b = idx >> 14;
    int rem = idx & 16383;
    int oy = rem >> 7;
    int ox = rem & 127;
    int p = (oy + 1) & 1;
    int q = (ox + 1) & 1;
    float acc0 = bias[0], acc1 = bias[1], acc2 = bias[2];
    #pragma unroll
    for (int t = 0; t < 2; ++t) {
        int kh = p + 2 * t;
        int ih = (oy + 1 - kh) >> 1;
        if ((unsigned)ih >= 64u) continue;
        #pragma unroll
        for (int u = 0; u < 2; ++u) {
            int kw = q + 2 * u;
            int iw = (ox + 1 - kw) >> 1;
            if ((unsigned)iw >= 64u) continue;
            int base = ((((b << 6) + ih) << 6) + iw) * 48 + ((kh << 2) + kw) * 3;
            acc0 += Y[base];
            acc1 += Y[base + 1];
            acc2 += Y[base + 2];
        }
    }
    int obase = (b * 3 << 14) + (oy << 7) + ox;
    out[obase]           = 1.f / (1.f + expf(-acc0));
    out[obase + 16384]   = 1.f / (1.f + expf(-acc1));
    out[obase + 32768]   = 1.f / (1.f + expf(-acc2));
}

// ======================================================================
extern "C" void kernel_launch(void* const* d_in, const int* in_sizes, int n_in,
                              void* d_out, int out_size, void* d_ws, size_t ws_size,
                              hipStream_t stream)
{
    (void)in_sizes; (void)n_in; (void)out_size; (void)ws_size;
    const float* x      = (const float*)d_in[0];
    const float* embed  = (const float*)d_in[1];
    const float* e_w1   = (const float*)d_in[2];
    const float* e_w2   = (const float*)d_in[3];
    const float* e_r1a  = (const float*)d_in[4];
    const float* e_r1b  = (const float*)d_in[5];
    const float* e_r2a  = (const float*)d_in[6];
    const float* e_r2b  = (const float*)d_in[7];
    const float* d_r1a  = (const float*)d_in[8];
    const float* d_r1b  = (const float*)d_in[9];
    const float* d_r2a  = (const float*)d_in[10];
    const float* d_r2b  = (const float*)d_in[11];
    const float* dt1_w  = (const float*)d_in[12];
    const float* dt1_b  = (const float*)d_in[13];
    const float* dt2_w  = (const float*)d_in[14];
    const float* dt2_b  = (const float*)d_in[15];
    float* outp = (float*)d_out;

    // ---- workspace layout ----
    char* base = (char*)d_ws;
    size_t off = 0;
    auto alloc = [&](size_t bytes) { char* p = base + off; off += (bytes + 255) & ~size_t(255); return p; };
    unsigned short* A0b = (unsigned short*)alloc(67108864);  // (B,64,64,256) bf16
    float*          A1f = (float*)alloc(33554432);           // ze fp32; later Y
    unsigned short* L0  = (unsigned short*)alloc(16777216);
    unsigned short* L1  = (unsigned short*)alloc(16777216);
    unsigned short* L2  = (unsigned short*)alloc(16777216);  // (unused after R9 fusion; kept)
    unsigned short* Wf  = (unsigned short*)alloc(9437184);   // 10 frag-ordered weights
    unsigned short* Wg  = (unsigned short*)alloc(24576);     // deconv2 frag weights
    unsigned short* EmbF = (unsigned short*)alloc(262144);   // codebook frag bf16
    unsigned short* WgC = (unsigned short*)alloc(32768);     // conv1 frag weights
    float* Nrm  = (float*)alloc(2048);
    float* Lpart = (float*)alloc(16384);                     // 4096 loss partials
    float* Y = A1f;   // alias: ze dead after vqm_k
    (void)L2;

    // frag-weight segment offsets inside Wf (element counts)
    unsigned short* Wf_ew2  = Wf;
    unsigned short* Wf_er1a = Wf + 1048576;
    unsigned short* Wf_er1b = Wf + 1638400;
    unsigned short* Wf_er2a = Wf + 1703936;
    unsigned short* Wf_er2b = Wf + 2293760;
    unsigned short* Wf_dr1a = Wf + 2359296;
    unsigned short* Wf_dr1b = Wf + 2949120;
    unsigned short* Wf_dr2a = Wf + 3014656;
    unsigned short* Wf_dr2b = Wf + 3604480;
    unsigned short* Wf_dt1  = Wf + 3670016;

    PermfArgs pa;
    const float* srcs[10] = {e_w2, e_r1a, e_r1b, e_r2a, e_r2b, d_r1a, d_r1b, d_r2a, d_r2b, dt1_w};
    int kws[10] = {4, 3, 1, 3, 1, 3, 1, 3, 1, 4};
    int sos[10] = {4096, 2304, 256, 2304, 256, 2304, 256, 2304, 256, 16};
    int sis[10] = {16, 9, 1, 9, 1, 9, 1, 9, 1, 4096};
    int shs[10] = {4, 3, 0, 3, 0, 3, 0, 3, 0, 4};
    int sws[10] = {1, 1, 0, 1, 0, 1, 0, 1, 0, 1};
    int cums[11] = {0, 1048576, 1638400, 1703936, 2293760, 2359296,
                    2949120, 3014656, 3604480, 3670016, 4718592};
    for (int k = 0; k < 10; ++k) {
        pa.src[k] = srcs[k]; pa.kw[k] = kws[k]; pa.so[k] = sos[k];
        pa.si[k] = sis[k]; pa.sh[k] = shs[k]; pa.sw[k] = sws[k];
        pa.cum[k] = cums[k];
    }
    pa.cum[10] = cums[10];

    permf_all_k<<<18432, 256, 0, stream>>>(pa, Wf);
    misc_prep_k<<<752, 256, 0, stream>>>(dt2_w, Wg, embed, EmbF, e_w1, WgC, Nrm);

    // ---- encoder ----
    conv1m_k<<<32 * 64, 256, 0, stream>>>(x, WgC, A0b);
    mconv2_k<<<32 * 16, 256, 0, stream>>>(A0b, Wf_ew2, L1);                      // h
    res3_k<<<32 * 32, 256, 0, stream>>>(L1, Wf_er1a, Wf_er1b, L0, nullptr, 0);   // r1 -> L0
    res3_k<<<32 * 32, 256, 0, stream>>>(L0, Wf_er2a, Wf_er2b, L1, A1f, 1);       // ze: bf16->L1, fp32->A1f

    // ---- VQ ----
    vqm_k<<<32 * 32, 256, 0, stream>>>(L1, A1f, EmbF, embed, Nrm, L1, Lpart);

    // ---- decoder ----
    res3_k<<<32 * 32, 256, 0, stream>>>(L1, Wf_dr1a, Wf_dr1b, L0, nullptr, 0);   // d1 -> L0
    res3_k<<<32 * 32, 256, 0, stream>>>(L0, Wf_dr2a, Wf_dr2b, L1, nullptr, 0);   // d2 -> L1
    mdeconv1_k<<<32 * 32, 256, 0, stream>>>(L1, Wf_dt1, dt1_b, A0b);
    mdec2a_k<<<2048, 256, 0, stream>>>(A0b, Wg, Y);
    dec2b_k<<<2048, 256, 0, stream>>>(Y, dt2_b, outp);
    lossfin_k<<<1, 256, 0, stream>>>(Lpart, outp);
}

// Round 16
// 703.533 us; speedup vs baseline: 1.2972x; 1.0092x over previous
//
#include <hip/hip_runtime.h>

// ======================================================================
// VQ-VAE forward, all-MFMA. B=32, CIN=3, IMG=128, D=256, K=512.
// NHWC bf16 activations. Weights frag-ordered Wf[khkw][cch][n][32].
// MFMA 16x16x32 bf16: A[m=lane&15][k=quad*8+j], B[n][k], D col=lane&15,
// row=quad*4+reg.
// R4 tb-epilogue; R6 deterministic loss; R9 fused res-block; R11
// full-line res3 epilogue; R12 (occupancy) + R13 (B-prefetch) = NULL:
// MfmaUtil pinned at 28% => staging phases are ~70% of wall time,
// latency-exposed (input 67MB > L2, ~900cy loads serialized between
// barriers).
// R14: T14 async-STAGE split in mconv2 + res3 — issue phase k+1 global
// loads into regs BEFORE phase k's MFMA loop; ds_write after the
// post-compute barrier. HBM latency hides under MFMA. mconv2 drops the
// null B-prefetch (frees VGPRs for rv[17]); res3 rv[7].
// ======================================================================

typedef __attribute__((ext_vector_type(8))) short bf16x8;
typedef __attribute__((ext_vector_type(4))) float f32x4;
#define MFMA_B16(a, b, c) __builtin_amdgcn_mfma_f32_16x16x32_bf16(a, b, c, 0, 0, 0)

__device__ inline unsigned short f2b(float f) {
    unsigned int u = __float_as_uint(f);
    unsigned int r = u + 0x7fffu + ((u >> 16) & 1u);
    return (unsigned short)(r >> 16);
}
__device__ inline float b2f(unsigned short u) {
    return __uint_as_float(((unsigned int)u) << 16);
}

// ======================================================================
// batched bf16 frag-order weight permute for the 10 conv/deconv weights.
// ======================================================================
struct PermfArgs {
    const float* src[10];
    int kw[10];
    int so[10], si[10], sh[10], sw[10];
    int cum[11];
};

__global__ void permf_all_k(PermfArgs a, unsigned short* __restrict__ dst)
{
    int gid = blockIdx.x * 256 + threadIdx.x;
    if (gid >= a.cum[10]) return;
    int seg = 0;
    while (seg < 9 && gid >= a.cum[seg + 1]) ++seg;
    int l = gid - a.cum[seg];
    int q = l & 31;
    int n = (l >> 5) & 255;
    int rest = l >> 13;
    int cch = rest & 7;
    int khkw = rest >> 3;
    int kh = khkw / a.kw[seg], kw = khkw % a.kw[seg];
    int ci = cch * 32 + q;
    dst[gid] = f2b(a.src[seg][n * a.so[seg] + ci * a.si[seg] + kh * a.sh[seg] + kw * a.sw[seg]]);
}

// ======================================================================
// misc prep: deconv2 frag weights, codebook frag, conv1 frag weights,
// codebook norms. 752 blocks x 256.
// ======================================================================
__global__ void misc_prep_k(const float* __restrict__ dt2_w, unsigned short* __restrict__ wg,
                            const float* __restrict__ embed, unsigned short* __restrict__ embF,
                            const float* __restrict__ e_w1, unsigned short* __restrict__ wgc,
                            float* __restrict__ nrm)
{
    int blk = blockIdx.x, tid = threadIdx.x;
    if (blk < 48) {
        int idx = blk * 256 + tid;        // < 12288
        int q = idx & 31;
        int n = (idx >> 5) % 48;
        int cch = idx / (48 * 32);
        int ci = cch * 32 + q;
        int oc = n % 3, khkw = n / 3;
        int kh = khkw >> 2, kw = khkw & 3;
        wg[idx] = f2b(dt2_w[ci * 48 + oc * 16 + kh * 4 + kw]);
    } else if (blk < 560) {
        int idx = (blk - 48) * 256 + tid; // < 131072
        int q = idx & 31;
        int n = (idx >> 5) & 511;
        int cch = idx >> 14;
        embF[idx] = f2b(embed[n * 256 + cch * 32 + q]);
    } else if (blk < 624) {
        int idx = (blk - 560) * 256 + tid;  // < 16384
        int q = idx & 31;
        int n = (idx >> 5) & 255;
        int kt = idx >> 13;
        int k = kt * 32 + q;
        float v = 0.f;
        if (k < 48) {
            int ci = k >> 4, kh = (k >> 2) & 3, kwv = k & 3;
            v = e_w1[n * 48 + ci * 16 + kh * 4 + kwv];
        }
        wgc[idx] = f2b(v);
    } else {
        int row = (blk - 624) * 4 + (tid >> 6);
        int lane = tid & 63;
        float s = 0.f;
        #pragma unroll
        for (int c = 0; c < 256; c += 64) {
            float v = embed[row * 256 + c + lane];
            s += v * v;
        }
        #pragma unroll
        for (int off = 1; off < 64; off <<= 1) s += __shfl_xor(s, off);
        if (lane == 0) nrm[row] = s;
    }
}

// ======================================================================
// lossfin: deterministic fixed-order reduction of 4096 wave-partials.
// ======================================================================
__global__ void lossfin_k(const float* __restrict__ lpart, float* __restrict__ out)
{
    __shared__ float red[256];
    int tid = threadIdx.x;
    float s = 0.f;
    #pragma unroll
    for (int i = 0; i < 16; ++i) s += lpart[tid * 16 + i];
    red[tid] = s;
    __syncthreads();
    for (int off = 128; off > 0; off >>= 1) {
        if (tid < off) red[tid] += red[tid + off];
        __syncthreads();
    }
    if (tid == 0) {
        float m = red[0] * (1.0f / 32768.0f);
        out[1572864] = m;
        out[1572865] = m;
    }
}

// ======================================================================
// conv1m: MFMA im2col conv1. x NCHW fp32 -> NHWC bf16 (B,64,64,256),
// k4 s2 p1, ReLU. grid = B*64.
// ======================================================================
__global__ void __launch_bounds__(256, 4)
conv1m_k(const float* __restrict__ x, const unsigned short* __restrict__ wgc,
         unsigned short* __restrict__ out)
{
    int bh = blockIdx.x;             // b*64 + oh
    int b = bh >> 6, oh = bh & 63;
    int tid = threadIdx.x;
    int lane = tid & 63, wv = tid >> 6;
    int m = lane & 15, quad = lane >> 4;
    __shared__ float xrow[3][4][130];
    __shared__ __align__(16) unsigned short imc[64 * 72];
    for (int s = tid; s < 1560; s += 256) {
        int col = s % 130;
        int t = s / 130;
        int r = t & 3;
        int c = t >> 2;
        int ih = 2 * oh - 1 + r, iw = col - 1;
        float v = 0.f;
        if ((unsigned)ih < 128u && (unsigned)iw < 128u)
            v = x[(((b * 3 + c) << 7) + ih) * 128 + iw];
        xrow[c][r][col] = v;
    }
    __syncthreads();
    for (int s = tid; s < 4096; s += 256) {
        int px = s >> 6, k = s & 63;
        float v = 0.f;
        if (k < 48) {
            int ci = k >> 4, kh = (k >> 2) & 3, kw = k & 3;
            v = xrow[ci][kh][2 * px + kw];
        }
        imc[px * 72 + k] = f2b(v);
    }
    __syncthreads();
    f32x4 acc[16];
    f32x4 z = {0.f, 0.f, 0.f, 0.f};
    #pragma unroll
    for (int i = 0; i < 16; ++i) acc[i] = z;
    bf16x8 a0 = *(const bf16x8*)&imc[((wv << 4) + m) * 72 + (quad << 3)];
    bf16x8 a1 = *(const bf16x8*)&imc[((wv << 4) + m) * 72 + 32 + (quad << 3)];
    #pragma unroll
    for (int nt = 0; nt < 16; ++nt) {
        bf16x8 b0 = *(const bf16x8*)&wgc[(nt * 16 + m) * 32 + (quad << 3)];
        bf16x8 b1 = *(const bf16x8*)&wgc[(256 + nt * 16 + m) * 32 + (quad << 3)];
        acc[nt] = MFMA_B16(a0, b0, acc[nt]);
        acc[nt] = MFMA_B16(a1, b1, acc[nt]);
    }
    #pragma unroll
    for (int nt = 0; nt < 16; ++nt)
        #pragma unroll
        for (int r = 0; r < 4; ++r) {
            int px = (wv << 4) + quad * 4 + r;
            out[(((bh << 6) + px) << 8) + nt * 16 + (lane & 15)] = f2b(fmaxf(acc[nt][r], 0.f));
        }
}

// ======================================================================
// mconv2: k4 s2 p1, (B,64,64,256)->(B,32,32,256), ReLU. M=64. grid B*16.
// R14: T14 async-STAGE — rv[17] loads for kh+1 issued BEFORE kh's MFMA
// loop; ds_write after the post-compute barrier. Full-channel staging
// (2 rows x 66 x 256ch = 68KB, 4 kh-phases). No B-prefetch (null R13).
// ======================================================================
__global__ void __launch_bounds__(256, 2)
mconv2_k(const unsigned short* __restrict__ in, const unsigned short* __restrict__ wf,
         unsigned short* __restrict__ out)
{
    int blk = blockIdx.x;
    int bb = blk >> 4, j = blk & 15;
    int tid = threadIdx.x;
    int lane = tid & 63;
    int n0 = (tid >> 6) << 6;
    int m = lane & 15, quad = lane >> 4;
    __shared__ __align__(16) unsigned short win[2 * 66 * 264];  // 68.1 KB
    f32x4 acc[2][2][4];
    f32x4 z = {0.f, 0.f, 0.f, 0.f};
    #pragma unroll
    for (int a = 0; a < 2; ++a)
        #pragma unroll
        for (int i = 0; i < 2; ++i)
            #pragma unroll
            for (int t = 0; t < 4; ++t) acc[a][i][t] = z;

    int4 rv[17];

    // ---- prologue: stage kh=0 ----
    #pragma unroll
    for (int k = 0; k < 17; ++k) {
        int s = tid + (k << 8);
        rv[k] = make_int4(0, 0, 0, 0);
        if (s < 4224) {
            int c32 = s & 31;
            int t2 = s >> 5;
            int col = t2 % 66;
            int rr = t2 / 66;
            int ih = 4 * j - 1 + 2 * rr, iw = col - 1;
            if ((unsigned)ih < 64u && (unsigned)iw < 64u)
                rv[k] = *(const int4*)&in[((((bb << 6) + ih) << 6) + iw) * 256 + (c32 << 3)];
        }
    }
    #pragma unroll
    for (int k = 0; k < 17; ++k) {
        int s = tid + (k << 8);
        if (s < 4224) {
            int c32 = s & 31;
            int t2 = s >> 5;
            int col = t2 % 66;
            int rr = t2 / 66;
            int cs = (col >> 1) + (col & 1) * 33;
            *(int4*)&win[(rr * 66 + cs) * 264 + (c32 << 3)] = rv[k];
        }
    }
    __syncthreads();

    for (int kh = 0; kh < 4; ++kh) {
        // ---- T14: issue kh+1 loads BEFORE compute ----
        if (kh < 3) {
            #pragma unroll
            for (int k = 0; k < 17; ++k) {
                int s = tid + (k << 8);
                rv[k] = make_int4(0, 0, 0, 0);
                if (s < 4224) {
                    int c32 = s & 31;
                    int t2 = s >> 5;
                    int col = t2 % 66;
                    int rr = t2 / 66;
                    int ih = 4 * j + kh + 2 * rr, iw = col - 1;   // kh+1 - 1 = kh
                    if ((unsigned)ih < 64u && (unsigned)iw < 64u)
                        rv[k] = *(const int4*)&in[((((bb << 6) + ih) << 6) + iw) * 256 + (c32 << 3)];
                }
            }
        }
        // ---- compute kh ----
        for (int kw = 0; kw < 4; ++kw) {
            int csoff = (kw >> 1) + (kw & 1) * 33;
            #pragma unroll
            for (int cch = 0; cch < 8; ++cch) {
                const unsigned short* ba = &win[(m + csoff) * 264 + (cch << 5) + (quad << 3)];
                bf16x8 a00 = *(const bf16x8*)ba;
                bf16x8 a01 = *(const bf16x8*)(ba + 16 * 264);
                bf16x8 a10 = *(const bf16x8*)(ba + 66 * 264);
                bf16x8 a11 = *(const bf16x8*)(ba + 82 * 264);
                int wbase = ((((kh << 2) + kw) * 8 + cch) * 256 + n0 + m) * 32 + (quad << 3);
                bf16x8 b0 = *(const bf16x8*)&wf[wbase];
                bf16x8 b1 = *(const bf16x8*)&wf[wbase + 16 * 32];
                bf16x8 b2 = *(const bf16x8*)&wf[wbase + 32 * 32];
                bf16x8 b3 = *(const bf16x8*)&wf[wbase + 48 * 32];
                acc[0][0][0] = MFMA_B16(a00, b0, acc[0][0][0]);
                acc[0][0][1] = MFMA_B16(a00, b1, acc[0][0][1]);
                acc[0][0][2] = MFMA_B16(a00, b2, acc[0][0][2]);
                acc[0][0][3] = MFMA_B16(a00, b3, acc[0][0][3]);
                acc[0][1][0] = MFMA_B16(a01, b0, acc[0][1][0]);
                acc[0][1][1] = MFMA_B16(a01, b1, acc[0][1][1]);
                acc[0][1][2] = MFMA_B16(a01, b2, acc[0][1][2]);
                acc[0][1][3] = MFMA_B16(a01, b3, acc[0][1][3]);
                acc[1][0][0] = MFMA_B16(a10, b0, acc[1][0][0]);
                acc[1][0][1] = MFMA_B16(a10, b1, acc[1][0][1]);
                acc[1][0][2] = MFMA_B16(a10, b2, acc[1][0][2]);
                acc[1][0][3] = MFMA_B16(a10, b3, acc[1][0][3]);
                acc[1][1][0] = MFMA_B16(a11, b0, acc[1][1][0]);
                acc[1][1][1] = MFMA_B16(a11, b1, acc[1][1][1]);
                acc[1][1][2] = MFMA_B16(a11, b2, acc[1][1][2]);
                acc[1][1][3] = MFMA_B16(a11, b3, acc[1][1][3]);
            }
        }
        __syncthreads();          // all waves done reading win
        if (kh < 3) {
            #pragma unroll
            for (int k = 0; k < 17; ++k) {
                int s = tid + (k << 8);
                if (s < 4224) {
                    int c32 = s & 31;
                    int t2 = s >> 5;
                    int col = t2 % 66;
                    int rr = t2 / 66;
                    int cs = (col >> 1) + (col & 1) * 33;
                    *(int4*)&win[(rr * 66 + cs) * 264 + (c32 << 3)] = rv[k];
                }
            }
            __syncthreads();      // win holds kh+1
        }
    }
    #pragma unroll
    for (int row = 0; row < 2; ++row) {
        int oh = 2 * j + row;
        #pragma unroll
        for (int mt = 0; mt < 2; ++mt)
            #pragma unroll
            for (int nt = 0; nt < 4; ++nt)
                #pragma unroll
                for (int r = 0; r < 4; ++r) {
                    int px = mt * 16 + quad * 4 + r;
                    int col = n0 + nt * 16 + m;
                    out[((((bb << 5) + oh) << 5) + px) * 256 + col] = f2b(fmaxf(acc[row][mt][nt][r], 0.f));
                }
    }
}

// ======================================================================
// res3: FUSED residual block, M=32. grid = B*32 = 1024, 4 blocks/CU.
// R14: T14 async-STAGE — rv[7] loads for channel-phase 1 issued before
// phase 0's MFMA; ds_write after the post-compute barrier.
// ======================================================================
__global__ void __launch_bounds__(256, 4)
res3_k(const unsigned short* __restrict__ in, const unsigned short* __restrict__ wfA,
       const unsigned short* __restrict__ wfB, unsigned short* __restrict__ outb,
       float* __restrict__ outf, int f32out)
{
    int blk = blockIdx.x;
    int bb = blk >> 5, j = blk & 31;      // output row j
    int tid = threadIdx.x;
    int lane = tid & 63;
    int n0 = (tid >> 6) << 6;
    int m = lane & 15, quad = lane >> 4;
    __shared__ __align__(16) unsigned short win[3 * 34 * 132];  // 26.9 KB
    f32x4 acc[2][4];
    f32x4 z = {0.f, 0.f, 0.f, 0.f};
    #pragma unroll
    for (int i = 0; i < 2; ++i)
        #pragma unroll
        for (int t = 0; t < 4; ++t) acc[i][t] = z;

    int4 rv[7];

    // ---- prologue: stage phase c0=0 ----
    #pragma unroll
    for (int k = 0; k < 7; ++k) {
        int s = tid + (k << 8);
        rv[k] = make_int4(0, 0, 0, 0);
        if (s < 1632) {
            int c16 = s & 15;
            int t2 = s >> 4;
            int col = t2 % 34;
            int rr = t2 / 34;
            int ih = j - 1 + rr, iw = col - 1;
            if ((unsigned)ih < 32u && (unsigned)iw < 32u)
                rv[k] = *(const int4*)&in[((((bb << 5) + ih) << 5) + iw) * 256 + (c16 << 3)];
        }
    }
    #pragma unroll
    for (int k = 0; k < 7; ++k) {
        int s = tid + (k << 8);
        if (s < 1632) {
            int c16 = s & 15;
            int t2 = s >> 4;
            int col = t2 % 34;
            int rr = t2 / 34;
            *(int4*)&win[(rr * 34 + col) * 132 + (c16 << 3)] = rv[k];
        }
    }
    __syncthreads();

    // ---- part 1: 3x3 conv, 2 channel phases, T14 split ----
    for (int ph = 0; ph < 2; ++ph) {
        if (ph == 0) {
            #pragma unroll
            for (int k = 0; k < 7; ++k) {
                int s = tid + (k << 8);
                rv[k] = make_int4(0, 0, 0, 0);
                if (s < 1632) {
                    int c16 = s & 15;
                    int t2 = s >> 4;
                    int col = t2 % 34;
                    int rr = t2 / 34;
                    int ih = j - 1 + rr, iw = col - 1;
                    if ((unsigned)ih < 32u && (unsigned)iw < 32u)
                        rv[k] = *(const int4*)&in[((((bb << 5) + ih) << 5) + iw) * 256 + 128 + (c16 << 3)];
                }
            }
        }
        for (int kh = 0; kh < 3; ++kh) {
            #pragma unroll
            for (int kw = 0; kw < 3; ++kw) {
                #pragma unroll
                for (int cch = 0; cch < 4; ++cch) {
                    const unsigned short* ba = &win[(kh * 34 + m + kw) * 132 + (cch << 5) + (quad << 3)];
                    bf16x8 a0 = *(const bf16x8*)ba;
                    bf16x8 a1 = *(const bf16x8*)(ba + 16 * 132);
                    int cg = ph * 4 + cch;
                    int wbase = (((kh * 3 + kw) * 8 + cg) * 256 + n0 + m) * 32 + (quad << 3);
                    bf16x8 b0 = *(const bf16x8*)&wfA[wbase];
                    bf16x8 b1 = *(const bf16x8*)&wfA[wbase + 16 * 32];
                    bf16x8 b2 = *(const bf16x8*)&wfA[wbase + 32 * 32];
                    bf16x8 b3 = *(const bf16x8*)&wfA[wbase + 48 * 32];
                    acc[0][0] = MFMA_B16(a0, b0, acc[0][0]);
                    acc[0][1] = MFMA_B16(a0, b1, acc[0][1]);
                    acc[0][2] = MFMA_B16(a0, b2, acc[0][2]);
                    acc[0][3] = MFMA_B16(a0, b3, acc[0][3]);
                    acc[1][0] = MFMA_B16(a1, b0, acc[1][0]);
                    acc[1][1] = MFMA_B16(a1, b1, acc[1][1]);
                    acc[1][2] = MFMA_B16(a1, b2, acc[1][2]);
                    acc[1][3] = MFMA_B16(a1, b3, acc[1][3]);
                }
            }
        }
        __syncthreads();          // done reading win (phase ph)
        if (ph == 0) {
            #pragma unroll
            for (int k = 0; k < 7; ++k) {
                int s = tid + (k << 8);
                if (s < 1632) {
                    int c16 = s & 15;
                    int t2 = s >> 4;
                    int col = t2 % 34;
                    int rr = t2 / 34;
                    *(int4*)&win[(rr * 34 + col) * 132 + (c16 << 3)] = rv[k];
                }
            }
            __syncthreads();      // win holds phase 1
        }
    }

    // ---- handoff: ReLU(conv3) -> LDS bf16 [32][264] (alias over win) ----
    // (post-phase-1 barrier above = all waves done reading win)
    #pragma unroll
    for (int i = 0; i < 2; ++i)
        #pragma unroll
        for (int nt = 0; nt < 4; ++nt)
            #pragma unroll
            for (int r = 0; r < 4; ++r) {
                int p = i * 16 + quad * 4 + r;       // 0..31
                win[p * 264 + n0 + nt * 16 + m] = f2b(fmaxf(acc[i][nt][r], 0.f));
            }
    __syncthreads();   // handoff complete

    // ---- part 2: 1x1 matmul from LDS ----
    f32x4 acc2[2][4];
    #pragma unroll
    for (int i = 0; i < 2; ++i)
        #pragma unroll
        for (int t = 0; t < 4; ++t) acc2[i][t] = z;

    #pragma unroll
    for (int cch = 0; cch < 8; ++cch) {
        bf16x8 a0 = *(const bf16x8*)&win[m * 264 + (cch << 5) + (quad << 3)];
        bf16x8 a1 = *(const bf16x8*)&win[(m + 16) * 264 + (cch << 5) + (quad << 3)];
        int wbase = (cch * 256 + n0 + m) * 32 + (quad << 3);
        bf16x8 b0 = *(const bf16x8*)&wfB[wbase];
        bf16x8 b1 = *(const bf16x8*)&wfB[wbase + 16 * 32];
        bf16x8 b2 = *(const bf16x8*)&wfB[wbase + 32 * 32];
        bf16x8 b3 = *(const bf16x8*)&wfB[wbase + 48 * 32];
        acc2[0][0] = MFMA_B16(a0, b0, acc2[0][0]);
        acc2[0][1] = MFMA_B16(a0, b1, acc2[0][1]);
        acc2[0][2] = MFMA_B16(a0, b2, acc2[0][2]);
        acc2[0][3] = MFMA_B16(a0, b3, acc2[0][3]);
        acc2[1][0] = MFMA_B16(a1, b0, acc2[1][0]);
        acc2[1][1] = MFMA_B16(a1, b1, acc2[1][1]);
        acc2[1][2] = MFMA_B16(a1, b2, acc2[1][2]);
        acc2[1][3] = MFMA_B16(a1, b3, acc2[1][3]);
    }

    // ---- epilogue: fp32 LDS spill (16-px halves) -> coalesced IO ----
    float* winf = (float*)win;         // 16*260 floats = 16.6 KB <= 26.9 KB
    int rowbase = blk << 13;           // 32 px * 256
    #pragma unroll
    for (int half = 0; half < 2; ++half) {
        __syncthreads();   // winf free
        #pragma unroll
        for (int nt = 0; nt < 4; ++nt)
            #pragma unroll
            for (int r = 0; r < 4; ++r) {
                int pxl = quad * 4 + r;              // 0..15
                winf[pxl * 260 + n0 + nt * 16 + m] = acc2[half][nt][r];
            }
        __syncthreads();   // winf ready
        #pragma unroll
        for (int k = 0; k < 2; ++k) {
            int s = tid + k * 256;
            int pxl = s >> 5;          // 0..15
            int c8 = s & 31;           // 8-channel group
            int px = half * 16 + pxl;
            int idx = rowbase + (px << 8) + (c8 << 3);
            int4 rvv = *(const int4*)&in[idx];          // 8 bf16 residual
            const float* wp = &winf[pxl * 260 + (c8 << 3)];
            float v0 = wp[0] + b2f((unsigned short)((unsigned)rvv.x & 0xffffu));
            float v1 = wp[1] + b2f((unsigned short)((unsigned)rvv.x >> 16));
            float v2 = wp[2] + b2f((unsigned short)((unsigned)rvv.y & 0xffffu));
            float v3 = wp[3] + b2f((unsigned short)((unsigned)rvv.y >> 16));
            float v4 = wp[4] + b2f((unsigned short)((unsigned)rvv.z & 0xffffu));
            float v5 = wp[5] + b2f((unsigned short)((unsigned)rvv.z >> 16));
            float v6 = wp[6] + b2f((unsigned short)((unsigned)rvv.w & 0xffffu));
            float v7 = wp[7] + b2f((unsigned short)((unsigned)rvv.w >> 16));
            unsigned w0 = (unsigned)f2b(v0) | ((unsigned)f2b(v1) << 16);
            unsigned w1 = (unsigned)f2b(v2) | ((unsigned)f2b(v3) << 16);
            unsigned w2 = (unsigned)f2b(v4) | ((unsigned)f2b(v5) << 16);
            unsigned w3 = (unsigned)f2b(v6) | ((unsigned)f2b(v7) << 16);
            *(int4*)&outb[idx] = make_int4((int)w0, (int)w1, (int)w2, (int)w3);
            if (f32out) {
                *(float4*)&outf[idx]     = make_float4(v0, v1, v2, v3);
                *(float4*)&outf[idx + 4] = make_float4(v4, v5, v6, v7);
            }
        }
    }
}

// ======================================================================
// mdeconv1: ConvTranspose2d(256->256,k4,s2,p1)+bias+ReLU. R1 2-row
// structure + R4 tb-epilogue (full-line dwordx4 stores). grid = 1024.
// ======================================================================
__global__ void __launch_bounds__(256, 3)
mdeconv1_k(const unsigned short* __restrict__ in, const unsigned short* __restrict__ wf,
           const float* __restrict__ bias, unsigned short* __restrict__ out)
{
    int blk = blockIdx.x;
    int bb = blk >> 5;
    int rem = blk & 31;
    int pp = rem >> 4;
    int i = rem & 15;
    int oy_a = pp + 4 * i;
    int p = (oy_a + 1) & 1;
    int r0a = (oy_a + 1 - p) >> 1;
    int rbase = r0a - 1;
    int tid = threadIdx.x;
    int lane = tid & 63;
    int n0 = (tid >> 6) << 6;
    int m = lane & 15, quad = lane >> 4;
    __shared__ __align__(16) unsigned short win[3 * 34 * 264];   // 53.9 KB
    __shared__ __align__(16) unsigned short tb[16 * 264];        // 8.4 KB

    for (int s = tid; s < 3 * 34 * 32; s += 256) {
        int c8 = s & 31;
        int t2 = s >> 5;
        int col = t2 % 34;
        int rr = t2 / 34;
        int ih = rbase + rr, iw = col - 1;
        int4 v = make_int4(0, 0, 0, 0);
        if ((unsigned)ih < 32u && (unsigned)iw < 32u)
            v = *(const int4*)&in[((((bb << 5) + ih) << 5) + iw) * 256 + (c8 << 3)];
        *(int4*)&win[(rr * 34 + col) * 264 + (c8 << 3)] = v;
    }
    __syncthreads();

    for (int par = 0; par < 2; ++par) {
        f32x4 acc[2][2][4];
        f32x4 z = {0.f, 0.f, 0.f, 0.f};
        #pragma unroll
        for (int a = 0; a < 2; ++a)
            #pragma unroll
            for (int i2 = 0; i2 < 2; ++i2)
                #pragma unroll
                for (int t = 0; t < 4; ++t) acc[a][i2][t] = z;

        #pragma unroll
        for (int t = 0; t < 2; ++t) {
            int kh = p + 2 * t;
            #pragma unroll
            for (int u = 0; u < 2; ++u) {
                int kw = (1 - par) + 2 * u;
                int ixoff = par - u + 1;
                #pragma unroll
                for (int cch = 0; cch < 8; ++cch) {
                    const unsigned short* baA = &win[((1 - t) * 34 + m + ixoff) * 264 + (cch << 5) + (quad << 3)];
                    const unsigned short* baB = baA + 34 * 264;
                    bf16x8 a00 = *(const bf16x8*)baA;
                    bf16x8 a01 = *(const bf16x8*)(baA + 16 * 264);
                    bf16x8 a10 = *(const bf16x8*)baB;
                    bf16x8 a11 = *(const bf16x8*)(baB + 16 * 264);
                    int wbase = ((((kh << 2) + kw) * 8 + cch) * 256 + n0 + m) * 32 + (quad << 3);
                    bf16x8 b0 = *(const bf16x8*)&wf[wbase];
                    bf16x8 b1 = *(const bf16x8*)&wf[wbase + 16 * 32];
                    bf16x8 b2 = *(const bf16x8*)&wf[wbase + 32 * 32];
                    bf16x8 b3 = *(const bf16x8*)&wf[wbase + 48 * 32];
                    acc[0][0][0] = MFMA_B16(a00, b0, acc[0][0][0]);
                    acc[0][0][1] = MFMA_B16(a00, b1, acc[0][0][1]);
                    acc[0][0][2] = MFMA_B16(a00, b2, acc[0][0][2]);
                    acc[0][0][3] = MFMA_B16(a00, b3, acc[0][0][3]);
                    acc[0][1][0] = MFMA_B16(a01, b0, acc[0][1][0]);
                    acc[0][1][1] = MFMA_B16(a01, b1, acc[0][1][1]);
                    acc[0][1][2] = MFMA_B16(a01, b2, acc[0][1][2]);
                    acc[0][1][3] = MFMA_B16(a01, b3, acc[0][1][3]);
                    acc[1][0][0] = MFMA_B16(a10, b0, acc[1][0][0]);
                    acc[1][0][1] = MFMA_B16(a10, b1, acc[1][0][1]);
                    acc[1][0][2] = MFMA_B16(a10, b2, acc[1][0][2]);
                    acc[1][0][3] = MFMA_B16(a10, b3, acc[1][0][3]);
                    acc[1][1][0] = MFMA_B16(a11, b0, acc[1][1][0]);
                    acc[1][1][1] = MFMA_B16(a11, b1, acc[1][1][1]);
                    acc[1][1][2] = MFMA_B16(a11, b2, acc[1][1][2]);
                    acc[1][1][3] = MFMA_B16(a11, b3, acc[1][1][3]);
                }
            }
        }

        #pragma unroll
        for (int row = 0; row < 2; ++row) {
            int oy = oy_a + 2 * row;
            #pragma unroll
            for (int mt = 0; mt < 2; ++mt) {
                __syncthreads();
                #pragma unroll
                for (int nt = 0; nt < 4; ++nt) {
                    float bs = bias[n0 + nt * 16 + m];
                    #pragma unroll
                    for (int rr = 0; rr < 4; ++rr) {
                        float v = fmaxf(acc[row][mt][nt][rr] + bs, 0.f);
                        tb[(quad * 4 + rr) * 264 + n0 + nt * 16 + m] = f2b(v);
                    }
                }
                __syncthreads();
                #pragma unroll
                for (int k = 0; k < 2; ++k) {
                    int s = tid + k * 256;
                    int pxl = s >> 5;
                    int c8 = s & 31;
                    int ox = 2 * (mt * 16 + pxl) + par;
                    *(int4*)&out[((((bb << 6) + oy) << 6) + ox) * 256 + (c8 << 3)] =
                        *(const int4*)&tb[pxl * 264 + (c8 << 3)];
                }
            }
        }
    }
}

// ======================================================================
// vqm: MFMA VQ + exact fp32 gather/loss. grid = B*32. Deterministic
// loss partials to lpart[bh*4+wv].
// ======================================================================
__global__ void __launch_bounds__(256, 2)
vqm_k(const unsigned short* __restrict__ zeb, const float* __restrict__ zef,
      const unsigned short* __restrict__ embF, const float* __restrict__ embed,
      const float* __restrict__ nrm, unsigned short* __restrict__ zq,
      float* __restrict__ lpart)
{
    int bh = blockIdx.x;
    int tid = threadIdx.x;
    int lane = tid & 63;
    int wv = tid >> 6;
    int m = lane & 15, quad = lane >> 4;
    __shared__ __align__(16) unsigned short win[32 * 264];
    __shared__ float bvv[4][32];
    __shared__ int   bii[4][32];
    __shared__ int   bidx[32];
    int rowbase = bh << 13;
    for (int s = tid; s < 32 * 32; s += 256) {
        int c8 = s & 31, px = s >> 5;
        *(int4*)&win[px * 264 + (c8 << 3)] = *(const int4*)&zeb[rowbase + (px << 8) + (c8 << 3)];
    }
    __syncthreads();

    f32x4 acc[2][8];
    f32x4 z = {0.f, 0.f, 0.f, 0.f};
    #pragma unroll
    for (int i = 0; i < 2; ++i)
        #pragma unroll
        for (int j = 0; j < 8; ++j) acc[i][j] = z;

    #pragma unroll
    for (int cch = 0; cch < 8; ++cch) {
        bf16x8 a0 = *(const bf16x8*)&win[m * 264 + (cch << 5) + (quad << 3)];
        bf16x8 a1 = *(const bf16x8*)&win[(m + 16) * 264 + (cch << 5) + (quad << 3)];
        #pragma unroll
        for (int nt = 0; nt < 8; ++nt) {
            bf16x8 b = *(const bf16x8*)&embF[((cch << 9) + (wv << 7) + (nt << 4) + m) * 32 + (quad << 3)];
            acc[0][nt] = MFMA_B16(a0, b, acc[0][nt]);
            acc[1][nt] = MFMA_B16(a1, b, acc[1][nt]);
        }
    }

    float nv[8];
    #pragma unroll
    for (int nt = 0; nt < 8; ++nt) nv[nt] = nrm[(wv << 7) + (nt << 4) + m];

    #pragma unroll
    for (int mt = 0; mt < 2; ++mt)
        #pragma unroll
        for (int r = 0; r < 4; ++r) {
            float bv = 1e30f;
            int bi = 0x7fffffff;
            #pragma unroll
            for (int nt = 0; nt < 8; ++nt) {
                float d = nv[nt] - 2.f * acc[mt][nt][r];
                int n = (wv << 7) + (nt << 4) + m;
                if (d < bv || (d == bv && n < bi)) { bv = d; bi = n; }
            }
            #pragma unroll
            for (int off = 1; off < 16; off <<= 1) {
                float ov = __shfl_xor(bv, off);
                int oi = __shfl_xor(bi, off);
                if (ov < bv || (ov == bv && oi < bi)) { bv = ov; bi = oi; }
            }
            if (m == 0) {
                int px = mt * 16 + quad * 4 + r;
                bvv[wv][px] = bv;
                bii[wv][px] = bi;
            }
        }
    __syncthreads();
    if (tid < 32) {
        float bv = bvv[0][tid];
        int bi = bii[0][tid];
        #pragma unroll
        for (int w2 = 1; w2 < 4; ++w2) {
            float ov = bvv[w2][tid];
            int oi = bii[w2][tid];
            if (ov < bv || (ov == bv && oi < bi)) { bv = ov; bi = oi; }
        }
        bidx[tid] = bi;
    }
    __syncthreads();

    float lsum = 0.f;
    #pragma unroll
    for (int j = 0; j < 8; ++j) {
        int px = (wv << 3) + j;
        int bi = bidx[px];
        int pix = (bh << 5) + px;
        const float4 e = *(const float4*)&embed[bi * 256 + (lane << 2)];
        const float4 zv = *(const float4*)&zef[(pix << 8) + (lane << 2)];
        ushort4 eq;
        eq.x = f2b(e.x); eq.y = f2b(e.y); eq.z = f2b(e.z); eq.w = f2b(e.w);
        *(ushort4*)&zq[(pix << 8) + (lane << 2)] = eq;
        float dx = zv.x - e.x, dy = zv.y - e.y, dz = zv.z - e.z, dw = zv.w - e.w;
        lsum += dx * dx + dy * dy + dz * dz + dw * dw;
    }
    #pragma unroll
    for (int off = 1; off < 64; off <<= 1) lsum += __shfl_xor(lsum, off);
    if (lane == 0) lpart[(bh << 2) + wv] = lsum;
}

// ======================================================================
// mdec2a: deconv2 pass 1 — Y[B*64*64, 48] = X[.,256] x Wg[256,48]
// ======================================================================
__global__ void __launch_bounds__(256, 4)
mdec2a_k(const unsigned short* __restrict__ in, const unsigned short* __restrict__ wg,
         float* __restrict__ Y)
{
    int tid = threadIdx.x;
    int lane = tid & 63;
    int wv = tid >> 6;
    int m = lane & 15, quad = lane >> 4;
    __shared__ __align__(16) unsigned short win[64 * 264];
    int pxbase = blockIdx.x << 6;
    for (int s = tid; s < 64 * 32; s += 256) {
        int c8 = s & 31, px = s >> 5;
        *(int4*)&win[px * 264 + (c8 << 3)] = *(const int4*)&in[((pxbase + px) << 8) + (c8 << 3)];
    }
    __syncthreads();
    f32x4 acc[3];
    f32x4 z = {0.f, 0.f, 0.f, 0.f};
    acc[0] = z; acc[1] = z; acc[2] = z;
    #pragma unroll
    for (int cch = 0; cch < 8; ++cch) {
        bf16x8 a = *(const bf16x8*)&win[((wv << 4) + m) * 264 + (cch << 5) + (quad << 3)];
        #pragma unroll
        for (int nt = 0; nt < 3; ++nt) {
            bf16x8 b = *(const bf16x8*)&wg[(cch * 48 + nt * 16 + m) * 32 + (quad << 3)];
            acc[nt] = MFMA_B16(a, b, acc[nt]);
        }
    }
    #pragma unroll
    for (int nt = 0; nt < 3; ++nt)
        #pragma unroll
        for (int r = 0; r < 4; ++r) {
            int px = pxbase + (wv << 4) + quad * 4 + r;
            Y[px * 48 + nt * 16 + m] = acc[nt][r];
        }
}

// ======================================================================
// dec2b: deconv2 pass 2 — gather taps, +bias, sigmoid, NCHW out.
// ======================================================================
__global__ void dec2b_k(const float* __restrict__ Y, const float* __restrict__ bias,
                        float* __restrict__ out)
{
    int idx = blockIdx.x * 256 + threadIdx.x;    // < 524288
    int b = idx >> 14;
    int rem = idx & 16383;
    int oy = rem >> 7;
    int ox = rem & 127;
    int p = (oy + 1) & 1;
    int q = (ox + 1) & 1;
    float acc0 = bias[0], acc1 = bias[1], acc2 = bias[2];
    #pragma unroll
    for (int t = 0; t < 2; ++t) {
        int kh = p + 2 * t;
        int ih = (oy + 1 - kh) >> 1;
        if ((unsigned)ih >= 64u) continue;
        #pragma unroll
        for (int u = 0; u < 2; ++u) {
            int kw = q + 2 * u;
            int iw = (ox + 1 - kw) >> 1;
            if ((unsigned)iw >= 64u) continue;
            int base = ((((b << 6) + ih) << 6) + iw) * 48 + ((kh << 2) + kw) * 3;
            acc0 += Y[base];
            acc1 += Y[base + 1];
            acc2 += Y[base + 2];
        }
    }
    int obase = (b * 3 << 14) + (oy << 7) + ox;
    out[obase]           = 1.f / (1.f + expf(-acc0));
    out[obase + 16384]   = 1.f / (1.f + expf(-acc1));
    out[obase + 32768]   = 1.f / (1.f + expf(-acc2));
}

// ======================================================================
extern "C" void kernel_launch(void* const* d_in, const int* in_sizes, int n_in,
                              void* d_out, int out_size, void* d_ws, size_t ws_size,
                              hipStream_t stream)
{
    (void)in_sizes; (void)n_in; (void)out_size; (void)ws_size;
    const float* x      = (const float*)d_in[0];
    const float* embed  = (const float*)d_in[1];
    const float* e_w1   = (const float*)d_in[2];
    const float* e_w2   = (const float*)d_in[3];
    const float* e_r1a  = (const float*)d_in[4];
    const float* e_r1b  = (const float*)d_in[5];
    const float* e_r2a  = (const float*)d_in[6];
    const float* e_r2b  = (const float*)d_in[7];
    const float* d_r1a  = (const float*)d_in[8];
    const float* d_r1b  = (const float*)d_in[9];
    const float* d_r2a  = (const float*)d_in[10];
    const float* d_r2b  = (const float*)d_in[11];
    const float* dt1_w  = (const float*)d_in[12];
    const float* dt1_b  = (const float*)d_in[13];
    const float* dt2_w  = (const float*)d_in[14];
    const float* dt2_b  = (const float*)d_in[15];
    float* outp = (float*)d_out;

    // ---- workspace layout ----
    char* base = (char*)d_ws;
    size_t off = 0;
    auto alloc = [&](size_t bytes) { char* p = base + off; off += (bytes + 255) & ~size_t(255); return p; };
    unsigned short* A0b = (unsigned short*)alloc(67108864);  // (B,64,64,256) bf16
    float*          A1f = (float*)alloc(33554432);           // ze fp32; later Y
    unsigned short* L0  = (unsigned short*)alloc(16777216);
    unsigned short* L1  = (unsigned short*)alloc(16777216);
    unsigned short* L2  = (unsigned short*)alloc(16777216);  // (unused after R9 fusion; kept)
    unsigned short* Wf  = (unsigned short*)alloc(9437184);   // 10 frag-ordered weights
    unsigned short* Wg  = (unsigned short*)alloc(24576);     // deconv2 frag weights
    unsigned short* EmbF = (unsigned short*)alloc(262144);   // codebook frag bf16
    unsigned short* WgC = (unsigned short*)alloc(32768);     // conv1 frag weights
    float* Nrm  = (float*)alloc(2048);
    float* Lpart = (float*)alloc(16384);                     // 4096 loss partials
    float* Y = A1f;   // alias: ze dead after vqm_k
    (void)L2;

    // frag-weight segment offsets inside Wf (element counts)
    unsigned short* Wf_ew2  = Wf;
    unsigned short* Wf_er1a = Wf + 1048576;
    unsigned short* Wf_er1b = Wf + 1638400;
    unsigned short* Wf_er2a = Wf + 1703936;
    unsigned short* Wf_er2b = Wf + 2293760;
    unsigned short* Wf_dr1a = Wf + 2359296;
    unsigned short* Wf_dr1b = Wf + 2949120;
    unsigned short* Wf_dr2a = Wf + 3014656;
    unsigned short* Wf_dr2b = Wf + 3604480;
    unsigned short* Wf_dt1  = Wf + 3670016;

    PermfArgs pa;
    const float* srcs[10] = {e_w2, e_r1a, e_r1b, e_r2a, e_r2b, d_r1a, d_r1b, d_r2a, d_r2b, dt1_w};
    int kws[10] = {4, 3, 1, 3, 1, 3, 1, 3, 1, 4};
    int sos[10] = {4096, 2304, 256, 2304, 256, 2304, 256, 2304, 256, 16};
    int sis[10] = {16, 9, 1, 9, 1, 9, 1, 9, 1, 4096};
    int shs[10] = {4, 3, 0, 3, 0, 3, 0, 3, 0, 4};
    int sws[10] = {1, 1, 0, 1, 0, 1, 0, 1, 0, 1};
    int cums[11] = {0, 1048576, 1638400, 1703936, 2293760, 2359296,
                    2949120, 3014656, 3604480, 3670016, 4718592};
    for (int k = 0; k < 10; ++k) {
        pa.src[k] = srcs[k]; pa.kw[k] = kws[k]; pa.so[k] = sos[k];
        pa.si[k] = sis[k]; pa.sh[k] = shs[k]; pa.sw[k] = sws[k];
        pa.cum[k] = cums[k];
    }
    pa.cum[10] = cums[10];

    permf_all_k<<<18432, 256, 0, stream>>>(pa, Wf);
    misc_prep_k<<<752, 256, 0, stream>>>(dt2_w, Wg, embed, EmbF, e_w1, WgC, Nrm);

    // ---- encoder ----
    conv1m_k<<<32 * 64, 256, 0, stream>>>(x, WgC, A0b);
    mconv2_k<<<32 * 16, 256, 0, stream>>>(A0b, Wf_ew2, L1);                      // h
    res3_k<<<32 * 32, 256, 0, stream>>>(L1, Wf_er1a, Wf_er1b, L0, nullptr, 0);   // r1 -> L0
    res3_k<<<32 * 32, 256, 0, stream>>>(L0, Wf_er2a, Wf_er2b, L1, A1f, 1);       // ze: bf16->L1, fp32->A1f

    // ---- VQ ----
    vqm_k<<<32 * 32, 256, 0, stream>>>(L1, A1f, EmbF, embed, Nrm, L1, Lpart);

    // ---- decoder ----
    res3_k<<<32 * 32, 256, 0, stream>>>(L1, Wf_dr1a, Wf_dr1b, L0, nullptr, 0);   // d1 -> L0
    res3_k<<<32 * 32, 256, 0, stream>>>(L0, Wf_dr2a, Wf_dr2b, L1, nullptr, 0);   // d2 -> L1
    mdeconv1_k<<<32 * 32, 256, 0, stream>>>(L1, Wf_dt1, dt1_b, A0b);
    mdec2a_k<<<2048, 256, 0, stream>>>(A0b, Wg, Y);
    dec2b_k<<<2048, 256, 0, stream>>>(Y, dt2_b, outp);
    lossfin_k<<<1, 256, 0, stream>>>(Lpart, outp);
}

// Round 17
// 697.378 us; speedup vs baseline: 1.3086x; 1.0088x over previous
//
#include <hip/hip_runtime.h>

// ======================================================================
// VQ-VAE forward, all-MFMA. B=32, CIN=3, IMG=128, D=256, K=512.
// NHWC bf16 activations. Weights frag-ordered Wf[khkw][cch][n][32].
// MFMA 16x16x32 bf16: A[m=lane&15][k=quad*8+j], B[n][k], D col=lane&15,
// row=quad*4+reg.
// R4 tb-epilogue; R6 deterministic loss; R9 fused res-block; R11
// full-line res3 epilogue; R14 T14 async-STAGE (710->703.5).
// R16: producer-consumer XCD row-chunk swizzle. res3 input (16.8MB)
// fits aggregate L2 but identity row mapping put neighbor rows on
// different XCDs (2/3 of staged rows cross-XCD -> ~900cy HBM; FETCH
// 38MB vs 16.8 ideal). Bijective remap j=((r&7)<<2)|(r>>3) groups 4
// rows/XCD, applied to res3 + vqm (lpart by logical row keeps loss
// reduction order identical) + mconv2 output rows -> ~83% of neighbor
// reads XCD-local on the conv chain.
// ======================================================================

typedef __attribute__((ext_vector_type(8))) short bf16x8;
typedef __attribute__((ext_vector_type(4))) float f32x4;
#define MFMA_B16(a, b, c) __builtin_amdgcn_mfma_f32_16x16x32_bf16(a, b, c, 0, 0, 0)

__device__ inline unsigned short f2b(float f) {
    unsigned int u = __float_as_uint(f);
    unsigned int r = u + 0x7fffu + ((u >> 16) & 1u);
    return (unsigned short)(r >> 16);
}
__device__ inline float b2f(unsigned short u) {
    return __uint_as_float(((unsigned int)u) << 16);
}

// ======================================================================
// batched bf16 frag-order weight permute for the 10 conv/deconv weights.
// ======================================================================
struct PermfArgs {
    const float* src[10];
    int kw[10];
    int so[10], si[10], sh[10], sw[10];
    int cum[11];
};

__global__ void permf_all_k(PermfArgs a, unsigned short* __restrict__ dst)
{
    int gid = blockIdx.x * 256 + threadIdx.x;
    if (gid >= a.cum[10]) return;
    int seg = 0;
    while (seg < 9 && gid >= a.cum[seg + 1]) ++seg;
    int l = gid - a.cum[seg];
    int q = l & 31;
    int n = (l >> 5) & 255;
    int rest = l >> 13;
    int cch = rest & 7;
    int khkw = rest >> 3;
    int kh = khkw / a.kw[seg], kw = khkw % a.kw[seg];
    int ci = cch * 32 + q;
    dst[gid] = f2b(a.src[seg][n * a.so[seg] + ci * a.si[seg] + kh * a.sh[seg] + kw * a.sw[seg]]);
}

// ======================================================================
// misc prep: deconv2 frag weights, codebook frag, conv1 frag weights,
// codebook norms. 752 blocks x 256.
// ======================================================================
__global__ void misc_prep_k(const float* __restrict__ dt2_w, unsigned short* __restrict__ wg,
                            const float* __restrict__ embed, unsigned short* __restrict__ embF,
                            const float* __restrict__ e_w1, unsigned short* __restrict__ wgc,
                            float* __restrict__ nrm)
{
    int blk = blockIdx.x, tid = threadIdx.x;
    if (blk < 48) {
        int idx = blk * 256 + tid;        // < 12288
        int q = idx & 31;
        int n = (idx >> 5) % 48;
        int cch = idx / (48 * 32);
        int ci = cch * 32 + q;
        int oc = n % 3, khkw = n / 3;
        int kh = khkw >> 2, kw = khkw & 3;
        wg[idx] = f2b(dt2_w[ci * 48 + oc * 16 + kh * 4 + kw]);
    } else if (blk < 560) {
        int idx = (blk - 48) * 256 + tid; // < 131072
        int q = idx & 31;
        int n = (idx >> 5) & 511;
        int cch = idx >> 14;
        embF[idx] = f2b(embed[n * 256 + cch * 32 + q]);
    } else if (blk < 624) {
        int idx = (blk - 560) * 256 + tid;  // < 16384
        int q = idx & 31;
        int n = (idx >> 5) & 255;
        int kt = idx >> 13;
        int k = kt * 32 + q;
        float v = 0.f;
        if (k < 48) {
            int ci = k >> 4, kh = (k >> 2) & 3, kwv = k & 3;
            v = e_w1[n * 48 + ci * 16 + kh * 4 + kwv];
        }
        wgc[idx] = f2b(v);
    } else {
        int row = (blk - 624) * 4 + (tid >> 6);
        int lane = tid & 63;
        float s = 0.f;
        #pragma unroll
        for (int c = 0; c < 256; c += 64) {
            float v = embed[row * 256 + c + lane];
            s += v * v;
        }
        #pragma unroll
        for (int off = 1; off < 64; off <<= 1) s += __shfl_xor(s, off);
        if (lane == 0) nrm[row] = s;
    }
}

// ======================================================================
// lossfin: deterministic fixed-order reduction of 4096 wave-partials.
// ======================================================================
__global__ void lossfin_k(const float* __restrict__ lpart, float* __restrict__ out)
{
    __shared__ float red[256];
    int tid = threadIdx.x;
    float s = 0.f;
    #pragma unroll
    for (int i = 0; i < 16; ++i) s += lpart[tid * 16 + i];
    red[tid] = s;
    __syncthreads();
    for (int off = 128; off > 0; off >>= 1) {
        if (tid < off) red[tid] += red[tid + off];
        __syncthreads();
    }
    if (tid == 0) {
        float m = red[0] * (1.0f / 32768.0f);
        out[1572864] = m;
        out[1572865] = m;
    }
}

// ======================================================================
// conv1m: MFMA im2col conv1. x NCHW fp32 -> NHWC bf16 (B,64,64,256),
// k4 s2 p1, ReLU. grid = B*64.
// ======================================================================
__global__ void __launch_bounds__(256, 4)
conv1m_k(const float* __restrict__ x, const unsigned short* __restrict__ wgc,
         unsigned short* __restrict__ out)
{
    int bh = blockIdx.x;             // b*64 + oh
    int b = bh >> 6, oh = bh & 63;
    int tid = threadIdx.x;
    int lane = tid & 63, wv = tid >> 6;
    int m = lane & 15, quad = lane >> 4;
    __shared__ float xrow[3][4][130];
    __shared__ __align__(16) unsigned short imc[64 * 72];
    for (int s = tid; s < 1560; s += 256) {
        int col = s % 130;
        int t = s / 130;
        int r = t & 3;
        int c = t >> 2;
        int ih = 2 * oh - 1 + r, iw = col - 1;
        float v = 0.f;
        if ((unsigned)ih < 128u && (unsigned)iw < 128u)
            v = x[(((b * 3 + c) << 7) + ih) * 128 + iw];
        xrow[c][r][col] = v;
    }
    __syncthreads();
    for (int s = tid; s < 4096; s += 256) {
        int px = s >> 6, k = s & 63;
        float v = 0.f;
        if (k < 48) {
            int ci = k >> 4, kh = (k >> 2) & 3, kw = k & 3;
            v = xrow[ci][kh][2 * px + kw];
        }
        imc[px * 72 + k] = f2b(v);
    }
    __syncthreads();
    f32x4 acc[16];
    f32x4 z = {0.f, 0.f, 0.f, 0.f};
    #pragma unroll
    for (int i = 0; i < 16; ++i) acc[i] = z;
    bf16x8 a0 = *(const bf16x8*)&imc[((wv << 4) + m) * 72 + (quad << 3)];
    bf16x8 a1 = *(const bf16x8*)&imc[((wv << 4) + m) * 72 + 32 + (quad << 3)];
    #pragma unroll
    for (int nt = 0; nt < 16; ++nt) {
        bf16x8 b0 = *(const bf16x8*)&wgc[(nt * 16 + m) * 32 + (quad << 3)];
        bf16x8 b1 = *(const bf16x8*)&wgc[(256 + nt * 16 + m) * 32 + (quad << 3)];
        acc[nt] = MFMA_B16(a0, b0, acc[nt]);
        acc[nt] = MFMA_B16(a1, b1, acc[nt]);
    }
    #pragma unroll
    for (int nt = 0; nt < 16; ++nt)
        #pragma unroll
        for (int r = 0; r < 4; ++r) {
            int px = (wv << 4) + quad * 4 + r;
            out[(((bh << 6) + px) << 8) + nt * 16 + (lane & 15)] = f2b(fmaxf(acc[nt][r], 0.f));
        }
}

// ======================================================================
// mconv2: k4 s2 p1, (B,64,64,256)->(B,32,32,256), ReLU. M=64. grid B*16.
// R14 T14 async-STAGE. R16: output-row XCD swizzle j=((r&7)<<1)|(r>>3)
// so rows {4c..4c+3} are written on XCD c (aligns with res3's chunks).
// ======================================================================
__global__ void __launch_bounds__(256, 2)
mconv2_k(const unsigned short* __restrict__ in, const unsigned short* __restrict__ wf,
         unsigned short* __restrict__ out)
{
    int blk = blockIdx.x;
    int bb = blk >> 4;
    int r16 = blk & 15;
    int j = ((r16 & 7) << 1) | (r16 >> 3);   // R16 XCD swizzle (bijective)
    int tid = threadIdx.x;
    int lane = tid & 63;
    int n0 = (tid >> 6) << 6;
    int m = lane & 15, quad = lane >> 4;
    __shared__ __align__(16) unsigned short win[2 * 66 * 264];  // 68.1 KB
    f32x4 acc[2][2][4];
    f32x4 z = {0.f, 0.f, 0.f, 0.f};
    #pragma unroll
    for (int a = 0; a < 2; ++a)
        #pragma unroll
        for (int i = 0; i < 2; ++i)
            #pragma unroll
            for (int t = 0; t < 4; ++t) acc[a][i][t] = z;

    int4 rv[17];

    // ---- prologue: stage kh=0 ----
    #pragma unroll
    for (int k = 0; k < 17; ++k) {
        int s = tid + (k << 8);
        rv[k] = make_int4(0, 0, 0, 0);
        if (s < 4224) {
            int c32 = s & 31;
            int t2 = s >> 5;
            int col = t2 % 66;
            int rr = t2 / 66;
            int ih = 4 * j - 1 + 2 * rr, iw = col - 1;
            if ((unsigned)ih < 64u && (unsigned)iw < 64u)
                rv[k] = *(const int4*)&in[((((bb << 6) + ih) << 6) + iw) * 256 + (c32 << 3)];
        }
    }
    #pragma unroll
    for (int k = 0; k < 17; ++k) {
        int s = tid + (k << 8);
        if (s < 4224) {
            int c32 = s & 31;
            int t2 = s >> 5;
            int col = t2 % 66;
            int rr = t2 / 66;
            int cs = (col >> 1) + (col & 1) * 33;
            *(int4*)&win[(rr * 66 + cs) * 264 + (c32 << 3)] = rv[k];
        }
    }
    __syncthreads();

    for (int kh = 0; kh < 4; ++kh) {
        // ---- T14: issue kh+1 loads BEFORE compute ----
        if (kh < 3) {
            #pragma unroll
            for (int k = 0; k < 17; ++k) {
                int s = tid + (k << 8);
                rv[k] = make_int4(0, 0, 0, 0);
                if (s < 4224) {
                    int c32 = s & 31;
                    int t2 = s >> 5;
                    int col = t2 % 66;
                    int rr = t2 / 66;
                    int ih = 4 * j + kh + 2 * rr, iw = col - 1;   // kh+1 - 1 = kh
                    if ((unsigned)ih < 64u && (unsigned)iw < 64u)
                        rv[k] = *(const int4*)&in[((((bb << 6) + ih) << 6) + iw) * 256 + (c32 << 3)];
                }
            }
        }
        // ---- compute kh ----
        for (int kw = 0; kw < 4; ++kw) {
            int csoff = (kw >> 1) + (kw & 1) * 33;
            #pragma unroll
            for (int cch = 0; cch < 8; ++cch) {
                const unsigned short* ba = &win[(m + csoff) * 264 + (cch << 5) + (quad << 3)];
                bf16x8 a00 = *(const bf16x8*)ba;
                bf16x8 a01 = *(const bf16x8*)(ba + 16 * 264);
                bf16x8 a10 = *(const bf16x8*)(ba + 66 * 264);
                bf16x8 a11 = *(const bf16x8*)(ba + 82 * 264);
                int wbase = ((((kh << 2) + kw) * 8 + cch) * 256 + n0 + m) * 32 + (quad << 3);
                bf16x8 b0 = *(const bf16x8*)&wf[wbase];
                bf16x8 b1 = *(const bf16x8*)&wf[wbase + 16 * 32];
                bf16x8 b2 = *(const bf16x8*)&wf[wbase + 32 * 32];
                bf16x8 b3 = *(const bf16x8*)&wf[wbase + 48 * 32];
                acc[0][0][0] = MFMA_B16(a00, b0, acc[0][0][0]);
                acc[0][0][1] = MFMA_B16(a00, b1, acc[0][0][1]);
                acc[0][0][2] = MFMA_B16(a00, b2, acc[0][0][2]);
                acc[0][0][3] = MFMA_B16(a00, b3, acc[0][0][3]);
                acc[0][1][0] = MFMA_B16(a01, b0, acc[0][1][0]);
                acc[0][1][1] = MFMA_B16(a01, b1, acc[0][1][1]);
                acc[0][1][2] = MFMA_B16(a01, b2, acc[0][1][2]);
                acc[0][1][3] = MFMA_B16(a01, b3, acc[0][1][3]);
                acc[1][0][0] = MFMA_B16(a10, b0, acc[1][0][0]);
                acc[1][0][1] = MFMA_B16(a10, b1, acc[1][0][1]);
                acc[1][0][2] = MFMA_B16(a10, b2, acc[1][0][2]);
                acc[1][0][3] = MFMA_B16(a10, b3, acc[1][0][3]);
                acc[1][1][0] = MFMA_B16(a11, b0, acc[1][1][0]);
                acc[1][1][1] = MFMA_B16(a11, b1, acc[1][1][1]);
                acc[1][1][2] = MFMA_B16(a11, b2, acc[1][1][2]);
                acc[1][1][3] = MFMA_B16(a11, b3, acc[1][1][3]);
            }
        }
        __syncthreads();          // all waves done reading win
        if (kh < 3) {
            #pragma unroll
            for (int k = 0; k < 17; ++k) {
                int s = tid + (k << 8);
                if (s < 4224) {
                    int c32 = s & 31;
                    int t2 = s >> 5;
                    int col = t2 % 66;
                    int rr = t2 / 66;
                    int cs = (col >> 1) + (col & 1) * 33;
                    *(int4*)&win[(rr * 66 + cs) * 264 + (c32 << 3)] = rv[k];
                }
            }
            __syncthreads();      // win holds kh+1
        }
    }
    #pragma unroll
    for (int row = 0; row < 2; ++row) {
        int oh = 2 * j + row;
        #pragma unroll
        for (int mt = 0; mt < 2; ++mt)
            #pragma unroll
            for (int nt = 0; nt < 4; ++nt)
                #pragma unroll
                for (int r = 0; r < 4; ++r) {
                    int px = mt * 16 + quad * 4 + r;
                    int col = n0 + nt * 16 + m;
                    out[((((bb << 5) + oh) << 5) + px) * 256 + col] = f2b(fmaxf(acc[row][mt][nt][r], 0.f));
                }
    }
}

// ======================================================================
// res3: FUSED residual block, M=32. grid = B*32 = 1024, 4 blocks/CU.
// R14 T14 async-STAGE. R16: row XCD swizzle j=((r&7)<<2)|(r>>3) —
// rows {4c..4c+3} live on XCD c for BOTH producer and consumer res3
// instances -> interior neighbor rows are L2-local.
// ======================================================================
__global__ void __launch_bounds__(256, 4)
res3_k(const unsigned short* __restrict__ in, const unsigned short* __restrict__ wfA,
       const unsigned short* __restrict__ wfB, unsigned short* __restrict__ outb,
       float* __restrict__ outf, int f32out)
{
    int blk = blockIdx.x;
    int bb = blk >> 5;
    int r32 = blk & 31;
    int j = ((r32 & 7) << 2) | (r32 >> 3);   // R16 XCD swizzle (bijective)
    int tid = threadIdx.x;
    int lane = tid & 63;
    int n0 = (tid >> 6) << 6;
    int m = lane & 15, quad = lane >> 4;
    __shared__ __align__(16) unsigned short win[3 * 34 * 132];  // 26.9 KB
    f32x4 acc[2][4];
    f32x4 z = {0.f, 0.f, 0.f, 0.f};
    #pragma unroll
    for (int i = 0; i < 2; ++i)
        #pragma unroll
        for (int t = 0; t < 4; ++t) acc[i][t] = z;

    int4 rv[7];

    // ---- prologue: stage phase c0=0 ----
    #pragma unroll
    for (int k = 0; k < 7; ++k) {
        int s = tid + (k << 8);
        rv[k] = make_int4(0, 0, 0, 0);
        if (s < 1632) {
            int c16 = s & 15;
            int t2 = s >> 4;
            int col = t2 % 34;
            int rr = t2 / 34;
            int ih = j - 1 + rr, iw = col - 1;
            if ((unsigned)ih < 32u && (unsigned)iw < 32u)
                rv[k] = *(const int4*)&in[((((bb << 5) + ih) << 5) + iw) * 256 + (c16 << 3)];
        }
    }
    #pragma unroll
    for (int k = 0; k < 7; ++k) {
        int s = tid + (k << 8);
        if (s < 1632) {
            int c16 = s & 15;
            int t2 = s >> 4;
            int col = t2 % 34;
            int rr = t2 / 34;
            *(int4*)&win[(rr * 34 + col) * 132 + (c16 << 3)] = rv[k];
        }
    }
    __syncthreads();

    // ---- part 1: 3x3 conv, 2 channel phases, T14 split ----
    for (int ph = 0; ph < 2; ++ph) {
        if (ph == 0) {
            #pragma unroll
            for (int k = 0; k < 7; ++k) {
                int s = tid + (k << 8);
                rv[k] = make_int4(0, 0, 0, 0);
                if (s < 1632) {
                    int c16 = s & 15;
                    int t2 = s >> 4;
                    int col = t2 % 34;
                    int rr = t2 / 34;
                    int ih = j - 1 + rr, iw = col - 1;
                    if ((unsigned)ih < 32u && (unsigned)iw < 32u)
                        rv[k] = *(const int4*)&in[((((bb << 5) + ih) << 5) + iw) * 256 + 128 + (c16 << 3)];
                }
            }
        }
        for (int kh = 0; kh < 3; ++kh) {
            #pragma unroll
            for (int kw = 0; kw < 3; ++kw) {
                #pragma unroll
                for (int cch = 0; cch < 4; ++cch) {
                    const unsigned short* ba = &win[(kh * 34 + m + kw) * 132 + (cch << 5) + (quad << 3)];
                    bf16x8 a0 = *(const bf16x8*)ba;
                    bf16x8 a1 = *(const bf16x8*)(ba + 16 * 132);
                    int cg = ph * 4 + cch;
                    int wbase = (((kh * 3 + kw) * 8 + cg) * 256 + n0 + m) * 32 + (quad << 3);
                    bf16x8 b0 = *(const bf16x8*)&wfA[wbase];
                    bf16x8 b1 = *(const bf16x8*)&wfA[wbase + 16 * 32];
                    bf16x8 b2 = *(const bf16x8*)&wfA[wbase + 32 * 32];
                    bf16x8 b3 = *(const bf16x8*)&wfA[wbase + 48 * 32];
                    acc[0][0] = MFMA_B16(a0, b0, acc[0][0]);
                    acc[0][1] = MFMA_B16(a0, b1, acc[0][1]);
                    acc[0][2] = MFMA_B16(a0, b2, acc[0][2]);
                    acc[0][3] = MFMA_B16(a0, b3, acc[0][3]);
                    acc[1][0] = MFMA_B16(a1, b0, acc[1][0]);
                    acc[1][1] = MFMA_B16(a1, b1, acc[1][1]);
                    acc[1][2] = MFMA_B16(a1, b2, acc[1][2]);
                    acc[1][3] = MFMA_B16(a1, b3, acc[1][3]);
                }
            }
        }
        __syncthreads();          // done reading win (phase ph)
        if (ph == 0) {
            #pragma unroll
            for (int k = 0; k < 7; ++k) {
                int s = tid + (k << 8);
                if (s < 1632) {
                    int c16 = s & 15;
                    int t2 = s >> 4;
                    int col = t2 % 34;
                    int rr = t2 / 34;
                    *(int4*)&win[(rr * 34 + col) * 132 + (c16 << 3)] = rv[k];
                }
            }
            __syncthreads();      // win holds phase 1
        }
    }

    // ---- handoff: ReLU(conv3) -> LDS bf16 [32][264] (alias over win) ----
    #pragma unroll
    for (int i = 0; i < 2; ++i)
        #pragma unroll
        for (int nt = 0; nt < 4; ++nt)
            #pragma unroll
            for (int r = 0; r < 4; ++r) {
                int p = i * 16 + quad * 4 + r;       // 0..31
                win[p * 264 + n0 + nt * 16 + m] = f2b(fmaxf(acc[i][nt][r], 0.f));
            }
    __syncthreads();   // handoff complete

    // ---- part 2: 1x1 matmul from LDS ----
    f32x4 acc2[2][4];
    #pragma unroll
    for (int i = 0; i < 2; ++i)
        #pragma unroll
        for (int t = 0; t < 4; ++t) acc2[i][t] = z;

    #pragma unroll
    for (int cch = 0; cch < 8; ++cch) {
        bf16x8 a0 = *(const bf16x8*)&win[m * 264 + (cch << 5) + (quad << 3)];
        bf16x8 a1 = *(const bf16x8*)&win[(m + 16) * 264 + (cch << 5) + (quad << 3)];
        int wbase = (cch * 256 + n0 + m) * 32 + (quad << 3);
        bf16x8 b0 = *(const bf16x8*)&wfB[wbase];
        bf16x8 b1 = *(const bf16x8*)&wfB[wbase + 16 * 32];
        bf16x8 b2 = *(const bf16x8*)&wfB[wbase + 32 * 32];
        bf16x8 b3 = *(const bf16x8*)&wfB[wbase + 48 * 32];
        acc2[0][0] = MFMA_B16(a0, b0, acc2[0][0]);
        acc2[0][1] = MFMA_B16(a0, b1, acc2[0][1]);
        acc2[0][2] = MFMA_B16(a0, b2, acc2[0][2]);
        acc2[0][3] = MFMA_B16(a0, b3, acc2[0][3]);
        acc2[1][0] = MFMA_B16(a1, b0, acc2[1][0]);
        acc2[1][1] = MFMA_B16(a1, b1, acc2[1][1]);
        acc2[1][2] = MFMA_B16(a1, b2, acc2[1][2]);
        acc2[1][3] = MFMA_B16(a1, b3, acc2[1][3]);
    }

    // ---- epilogue: fp32 LDS spill (16-px halves) -> coalesced IO ----
    float* winf = (float*)win;         // 16*260 floats = 16.6 KB <= 26.9 KB
    int rowbase = ((bb << 5) + j) << 13;   // swizzled row j, 32 px * 256
    #pragma unroll
    for (int half = 0; half < 2; ++half) {
        __syncthreads();   // winf free
        #pragma unroll
        for (int nt = 0; nt < 4; ++nt)
            #pragma unroll
            for (int r = 0; r < 4; ++r) {
                int pxl = quad * 4 + r;              // 0..15
                winf[pxl * 260 + n0 + nt * 16 + m] = acc2[half][nt][r];
            }
        __syncthreads();   // winf ready
        #pragma unroll
        for (int k = 0; k < 2; ++k) {
            int s = tid + k * 256;
            int pxl = s >> 5;          // 0..15
            int c8 = s & 31;           // 8-channel group
            int px = half * 16 + pxl;
            int idx = rowbase + (px << 8) + (c8 << 3);
            int4 rvv = *(const int4*)&in[idx];          // 8 bf16 residual
            const float* wp = &winf[pxl * 260 + (c8 << 3)];
            float v0 = wp[0] + b2f((unsigned short)((unsigned)rvv.x & 0xffffu));
            float v1 = wp[1] + b2f((unsigned short)((unsigned)rvv.x >> 16));
            float v2 = wp[2] + b2f((unsigned short)((unsigned)rvv.y & 0xffffu));
            float v3 = wp[3] + b2f((unsigned short)((unsigned)rvv.y >> 16));
            float v4 = wp[4] + b2f((unsigned short)((unsigned)rvv.z & 0xffffu));
            float v5 = wp[5] + b2f((unsigned short)((unsigned)rvv.z >> 16));
            float v6 = wp[6] + b2f((unsigned short)((unsigned)rvv.w & 0xffffu));
            float v7 = wp[7] + b2f((unsigned short)((unsigned)rvv.w >> 16));
            unsigned w0 = (unsigned)f2b(v0) | ((unsigned)f2b(v1) << 16);
            unsigned w1 = (unsigned)f2b(v2) | ((unsigned)f2b(v3) << 16);
            unsigned w2 = (unsigned)f2b(v4) | ((unsigned)f2b(v5) << 16);
            unsigned w3 = (unsigned)f2b(v6) | ((unsigned)f2b(v7) << 16);
            *(int4*)&outb[idx] = make_int4((int)w0, (int)w1, (int)w2, (int)w3);
            if (f32out) {
                *(float4*)&outf[idx]     = make_float4(v0, v1, v2, v3);
                *(float4*)&outf[idx + 4] = make_float4(v4, v5, v6, v7);
            }
        }
    }
}

// ======================================================================
// mdeconv1: ConvTranspose2d(256->256,k4,s2,p1)+bias+ReLU. R1 2-row
// structure + R4 tb-epilogue (full-line dwordx4 stores). grid = 1024.
// ======================================================================
__global__ void __launch_bounds__(256, 3)
mdeconv1_k(const unsigned short* __restrict__ in, const unsigned short* __restrict__ wf,
           const float* __restrict__ bias, unsigned short* __restrict__ out)
{
    int blk = blockIdx.x;
    int bb = blk >> 5;
    int rem = blk & 31;
    int pp = rem >> 4;
    int i = rem & 15;
    int oy_a = pp + 4 * i;
    int p = (oy_a + 1) & 1;
    int r0a = (oy_a + 1 - p) >> 1;
    int rbase = r0a - 1;
    int tid = threadIdx.x;
    int lane = tid & 63;
    int n0 = (tid >> 6) << 6;
    int m = lane & 15, quad = lane >> 4;
    __shared__ __align__(16) unsigned short win[3 * 34 * 264];   // 53.9 KB
    __shared__ __align__(16) unsigned short tb[16 * 264];        // 8.4 KB

    for (int s = tid; s < 3 * 34 * 32; s += 256) {
        int c8 = s & 31;
        int t2 = s >> 5;
        int col = t2 % 34;
        int rr = t2 / 34;
        int ih = rbase + rr, iw = col - 1;
        int4 v = make_int4(0, 0, 0, 0);
        if ((unsigned)ih < 32u && (unsigned)iw < 32u)
            v = *(const int4*)&in[((((bb << 5) + ih) << 5) + iw) * 256 + (c8 << 3)];
        *(int4*)&win[(rr * 34 + col) * 264 + (c8 << 3)] = v;
    }
    __syncthreads();

    for (int par = 0; par < 2; ++par) {
        f32x4 acc[2][2][4];
        f32x4 z = {0.f, 0.f, 0.f, 0.f};
        #pragma unroll
        for (int a = 0; a < 2; ++a)
            #pragma unroll
            for (int i2 = 0; i2 < 2; ++i2)
                #pragma unroll
                for (int t = 0; t < 4; ++t) acc[a][i2][t] = z;

        #pragma unroll
        for (int t = 0; t < 2; ++t) {
            int kh = p + 2 * t;
            #pragma unroll
            for (int u = 0; u < 2; ++u) {
                int kw = (1 - par) + 2 * u;
                int ixoff = par - u + 1;
                #pragma unroll
                for (int cch = 0; cch < 8; ++cch) {
                    const unsigned short* baA = &win[((1 - t) * 34 + m + ixoff) * 264 + (cch << 5) + (quad << 3)];
                    const unsigned short* baB = baA + 34 * 264;
                    bf16x8 a00 = *(const bf16x8*)baA;
                    bf16x8 a01 = *(const bf16x8*)(baA + 16 * 264);
                    bf16x8 a10 = *(const bf16x8*)baB;
                    bf16x8 a11 = *(const bf16x8*)(baB + 16 * 264);
                    int wbase = ((((kh << 2) + kw) * 8 + cch) * 256 + n0 + m) * 32 + (quad << 3);
                    bf16x8 b0 = *(const bf16x8*)&wf[wbase];
                    bf16x8 b1 = *(const bf16x8*)&wf[wbase + 16 * 32];
                    bf16x8 b2 = *(const bf16x8*)&wf[wbase + 32 * 32];
                    bf16x8 b3 = *(const bf16x8*)&wf[wbase + 48 * 32];
                    acc[0][0][0] = MFMA_B16(a00, b0, acc[0][0][0]);
                    acc[0][0][1] = MFMA_B16(a00, b1, acc[0][0][1]);
                    acc[0][0][2] = MFMA_B16(a00, b2, acc[0][0][2]);
                    acc[0][0][3] = MFMA_B16(a00, b3, acc[0][0][3]);
                    acc[0][1][0] = MFMA_B16(a01, b0, acc[0][1][0]);
                    acc[0][1][1] = MFMA_B16(a01, b1, acc[0][1][1]);
                    acc[0][1][2] = MFMA_B16(a01, b2, acc[0][1][2]);
                    acc[0][1][3] = MFMA_B16(a01, b3, acc[0][1][3]);
                    acc[1][0][0] = MFMA_B16(a10, b0, acc[1][0][0]);
                    acc[1][0][1] = MFMA_B16(a10, b1, acc[1][0][1]);
                    acc[1][0][2] = MFMA_B16(a10, b2, acc[1][0][2]);
                    acc[1][0][3] = MFMA_B16(a10, b3, acc[1][0][3]);
                    acc[1][1][0] = MFMA_B16(a11, b0, acc[1][1][0]);
                    acc[1][1][1] = MFMA_B16(a11, b1, acc[1][1][1]);
                    acc[1][1][2] = MFMA_B16(a11, b2, acc[1][1][2]);
                    acc[1][1][3] = MFMA_B16(a11, b3, acc[1][1][3]);
                }
            }
        }

        #pragma unroll
        for (int row = 0; row < 2; ++row) {
            int oy = oy_a + 2 * row;
            #pragma unroll
            for (int mt = 0; mt < 2; ++mt) {
                __syncthreads();
                #pragma unroll
                for (int nt = 0; nt < 4; ++nt) {
                    float bs = bias[n0 + nt * 16 + m];
                    #pragma unroll
                    for (int rr = 0; rr < 4; ++rr) {
                        float v = fmaxf(acc[row][mt][nt][rr] + bs, 0.f);
                        tb[(quad * 4 + rr) * 264 + n0 + nt * 16 + m] = f2b(v);
                    }
                }
                __syncthreads();
                #pragma unroll
                for (int k = 0; k < 2; ++k) {
                    int s = tid + k * 256;
                    int pxl = s >> 5;
                    int c8 = s & 31;
                    int ox = 2 * (mt * 16 + pxl) + par;
                    *(int4*)&out[((((bb << 6) + oy) << 6) + ox) * 256 + (c8 << 3)] =
                        *(const int4*)&tb[pxl * 264 + (c8 << 3)];
                }
            }
        }
    }
}

// ======================================================================
// vqm: MFMA VQ + exact fp32 gather/loss. grid = B*32. R16: row XCD
// swizzle matching res3; lpart indexed by LOGICAL row (identical
// reduction order to identity mapping -> loss bit-identical).
// ======================================================================
__global__ void __launch_bounds__(256, 2)
vqm_k(const unsigned short* __restrict__ zeb, const float* __restrict__ zef,
      const unsigned short* __restrict__ embF, const float* __restrict__ embed,
      const float* __restrict__ nrm, unsigned short* __restrict__ zq,
      float* __restrict__ lpart)
{
    int bh = blockIdx.x;
    int bbv = bh >> 5;
    int rw = bh & 31;
    int jrow = ((rw & 7) << 2) | (rw >> 3);   // R16 XCD swizzle (bijective)
    int lrow = (bbv << 5) + jrow;             // logical row id
    int tid = threadIdx.x;
    int lane = tid & 63;
    int wv = tid >> 6;
    int m = lane & 15, quad = lane >> 4;
    __shared__ __align__(16) unsigned short win[32 * 264];
    __shared__ float bvv[4][32];
    __shared__ int   bii[4][32];
    __shared__ int   bidx[32];
    int rowbase = lrow << 13;
    for (int s = tid; s < 32 * 32; s += 256) {
        int c8 = s & 31, px = s >> 5;
        *(int4*)&win[px * 264 + (c8 << 3)] = *(const int4*)&zeb[rowbase + (px << 8) + (c8 << 3)];
    }
    __syncthreads();

    f32x4 acc[2][8];
    f32x4 z = {0.f, 0.f, 0.f, 0.f};
    #pragma unroll
    for (int i = 0; i < 2; ++i)
        #pragma unroll
        for (int jj = 0; jj < 8; ++jj) acc[i][jj] = z;

    #pragma unroll
    for (int cch = 0; cch < 8; ++cch) {
        bf16x8 a0 = *(const bf16x8*)&win[m * 264 + (cch << 5) + (quad << 3)];
        bf16x8 a1 = *(const bf16x8*)&win[(m + 16) * 264 + (cch << 5) + (quad << 3)];
        #pragma unroll
        for (int nt = 0; nt < 8; ++nt) {
            bf16x8 b = *(const bf16x8*)&embF[((cch << 9) + (wv << 7) + (nt << 4) + m) * 32 + (quad << 3)];
            acc[0][nt] = MFMA_B16(a0, b, acc[0][nt]);
            acc[1][nt] = MFMA_B16(a1, b, acc[1][nt]);
        }
    }

    float nv[8];
    #pragma unroll
    for (int nt = 0; nt < 8; ++nt) nv[nt] = nrm[(wv << 7) + (nt << 4) + m];

    #pragma unroll
    for (int mt = 0; mt < 2; ++mt)
        #pragma unroll
        for (int r = 0; r < 4; ++r) {
            float bv = 1e30f;
            int bi = 0x7fffffff;
            #pragma unroll
            for (int nt = 0; nt < 8; ++nt) {
                float d = nv[nt] - 2.f * acc[mt][nt][r];
                int n = (wv << 7) + (nt << 4) + m;
                if (d < bv || (d == bv && n < bi)) { bv = d; bi = n; }
            }
            #pragma unroll
            for (int off = 1; off < 16; off <<= 1) {
                float ov = __shfl_xor(bv, off);
                int oi = __shfl_xor(bi, off);
                if (ov < bv || (ov == bv && oi < bi)) { bv = ov; bi = oi; }
            }
            if (m == 0) {
                int px = mt * 16 + quad * 4 + r;
                bvv[wv][px] = bv;
                bii[wv][px] = bi;
            }
        }
    __syncthreads();
    if (tid < 32) {
        float bv = bvv[0][tid];
        int bi = bii[0][tid];
        #pragma unroll
        for (int w2 = 1; w2 < 4; ++w2) {
            float ov = bvv[w2][tid];
            int oi = bii[w2][tid];
            if (ov < bv || (ov == bv && oi < bi)) { bv = ov; bi = oi; }
        }
        bidx[tid] = bi;
    }
    __syncthreads();

    float lsum = 0.f;
    #pragma unroll
    for (int jj = 0; jj < 8; ++jj) {
        int px = (wv << 3) + jj;
        int bi = bidx[px];
        int pix = (lrow << 5) + px;
        const float4 e = *(const float4*)&embed[bi * 256 + (lane << 2)];
        const float4 zv = *(const float4*)&zef[(pix << 8) + (lane << 2)];
        ushort4 eq;
        eq.x = f2b(e.x); eq.y = f2b(e.y); eq.z = f2b(e.z); eq.w = f2b(e.w);
        *(ushort4*)&zq[(pix << 8) + (lane << 2)] = eq;
        float dx = zv.x - e.x, dy = zv.y - e.y, dz = zv.z - e.z, dw = zv.w - e.w;
        lsum += dx * dx + dy * dy + dz * dz + dw * dw;
    }
    #pragma unroll
    for (int off = 1; off < 64; off <<= 1) lsum += __shfl_xor(lsum, off);
    if (lane == 0) lpart[(lrow << 2) + wv] = lsum;   // logical-row index: order-invariant
}

// ======================================================================
// mdec2a: deconv2 pass 1 — Y[B*64*64, 48] = X[.,256] x Wg[256,48]
// ======================================================================
__global__ void __launch_bounds__(256, 4)
mdec2a_k(const unsigned short* __restrict__ in, const unsigned short* __restrict__ wg,
         float* __restrict__ Y)
{
    int tid = threadIdx.x;
    int lane = tid & 63;
    int wv = tid >> 6;
    int m = lane & 15, quad = lane >> 4;
    __shared__ __align__(16) unsigned short win[64 * 264];
    int pxbase = blockIdx.x << 6;
    for (int s = tid; s < 64 * 32; s += 256) {
        int c8 = s & 31, px = s >> 5;
        *(int4*)&win[px * 264 + (c8 << 3)] = *(const int4*)&in[((pxbase + px) << 8) + (c8 << 3)];
    }
    __syncthreads();
    f32x4 acc[3];
    f32x4 z = {0.f, 0.f, 0.f, 0.f};
    acc[0] = z; acc[1] = z; acc[2] = z;
    #pragma unroll
    for (int cch = 0; cch < 8; ++cch) {
        bf16x8 a = *(const bf16x8*)&win[((wv << 4) + m) * 264 + (cch << 5) + (quad << 3)];
        #pragma unroll
        for (int nt = 0; nt < 3; ++nt) {
            bf16x8 b = *(const bf16x8*)&wg[(cch * 48 + nt * 16 + m) * 32 + (quad << 3)];
            acc[nt] = MFMA_B16(a, b, acc[nt]);
        }
    }
    #pragma unroll
    for (int nt = 0; nt < 3; ++nt)
        #pragma unroll
        for (int r = 0; r < 4; ++r) {
            int px = pxbase + (wv << 4) + quad * 4 + r;
            Y[px * 48 + nt * 16 + m] = acc[nt][r];
        }
}

// ======================================================================
// dec2b: deconv2 pass 2 — gather taps, +bias, sigmoid, NCHW out.
// ======================================================================
__global__ void dec2b_k(const float* __restrict__ Y, const float* __restrict__ bias,
                        float* __restrict__ out)
{
    int idx = blockIdx.x * 256 + threadIdx.x;    // < 524288
    int b = idx >> 14;
    int rem = idx & 16383;
    int oy = rem >> 7;
    int ox = rem & 127;
    int p = (oy + 1) & 1;
    int q = (ox + 1) & 1;
    float acc0 = bias[0], acc1 = bias[1], acc2 = bias[2];
    #pragma unroll
    for (int t = 0; t < 2; ++t) {
        int kh = p + 2 * t;
        int ih = (oy + 1 - kh) >> 1;
        if ((unsigned)ih >= 64u) continue;
        #pragma unroll
        for (int u = 0; u < 2; ++u) {
            int kw = q + 2 * u;
            int iw = (ox + 1 - kw) >> 1;
            if ((unsigned)iw >= 64u) continue;
            int base = ((((b << 6) + ih) << 6) + iw) * 48 + ((kh << 2) + kw) * 3;
            acc0 += Y[base];
            acc1 += Y[base + 1];
            acc2 += Y[base + 2];
        }
    }
    int obase = (b * 3 << 14) + (oy << 7) + ox;
    out[obase]           = 1.f / (1.f + expf(-acc0));
    out[obase + 16384]   = 1.f / (1.f + expf(-acc1));
    out[obase + 32768]   = 1.f / (1.f + expf(-acc2));
}

// ======================================================================
extern "C" void kernel_launch(void* const* d_in, const int* in_sizes, int n_in,
                              void* d_out, int out_size, void* d_ws, size_t ws_size,
                              hipStream_t stream)
{
    (void)in_sizes; (void)n_in; (void)out_size; (void)ws_size;
    const float* x      = (const float*)d_in[0];
    const float* embed  = (const float*)d_in[1];
    const float* e_w1   = (const float*)d_in[2];
    const float* e_w2   = (const float*)d_in[3];
    const float* e_r1a  = (const float*)d_in[4];
    const float* e_r1b  = (const float*)d_in[5];
    const float* e_r2a  = (const float*)d_in[6];
    const float* e_r2b  = (const float*)d_in[7];
    const float* d_r1a  = (const float*)d_in[8];
    const float* d_r1b  = (const float*)d_in[9];
    const float* d_r2a  = (const float*)d_in[10];
    const float* d_r2b  = (const float*)d_in[11];
    const float* dt1_w  = (const float*)d_in[12];
    const float* dt1_b  = (const float*)d_in[13];
    const float* dt2_w  = (const float*)d_in[14];
    const float* dt2_b  = (const float*)d_in[15];
    float* outp = (float*)d_out;

    // ---- workspace layout ----
    char* base = (char*)d_ws;
    size_t off = 0;
    auto alloc = [&](size_t bytes) { char* p = base + off; off += (bytes + 255) & ~size_t(255); return p; };
    unsigned short* A0b = (unsigned short*)alloc(67108864);  // (B,64,64,256) bf16
    float*          A1f = (float*)alloc(33554432);           // ze fp32; later Y
    unsigned short* L0  = (unsigned short*)alloc(16777216);
    unsigned short* L1  = (unsigned short*)alloc(16777216);
    unsigned short* L2  = (unsigned short*)alloc(16777216);  // (unused after R9 fusion; kept)
    unsigned short* Wf  = (unsigned short*)alloc(9437184);   // 10 frag-ordered weights
    unsigned short* Wg  = (unsigned short*)alloc(24576);     // deconv2 frag weights
    unsigned short* EmbF = (unsigned short*)alloc(262144);   // codebook frag bf16
    unsigned short* WgC = (unsigned short*)alloc(32768);     // conv1 frag weights
    float* Nrm  = (float*)alloc(2048);
    float* Lpart = (float*)alloc(16384);                     // 4096 loss partials
    float* Y = A1f;   // alias: ze dead after vqm_k
    (void)L2;

    // frag-weight segment offsets inside Wf (element counts)
    unsigned short* Wf_ew2  = Wf;
    unsigned short* Wf_er1a = Wf + 1048576;
    unsigned short* Wf_er1b = Wf + 1638400;
    unsigned short* Wf_er2a = Wf + 1703936;
    unsigned short* Wf_er2b = Wf + 2293760;
    unsigned short* Wf_dr1a = Wf + 2359296;
    unsigned short* Wf_dr1b = Wf + 2949120;
    unsigned short* Wf_dr2a = Wf + 3014656;
    unsigned short* Wf_dr2b = Wf + 3604480;
    unsigned short* Wf_dt1  = Wf + 3670016;

    PermfArgs pa;
    const float* srcs[10] = {e_w2, e_r1a, e_r1b, e_r2a, e_r2b, d_r1a, d_r1b, d_r2a, d_r2b, dt1_w};
    int kws[10] = {4, 3, 1, 3, 1, 3, 1, 3, 1, 4};
    int sos[10] = {4096, 2304, 256, 2304, 256, 2304, 256, 2304, 256, 16};
    int sis[10] = {16, 9, 1, 9, 1, 9, 1, 9, 1, 4096};
    int shs[10] = {4, 3, 0, 3, 0, 3, 0, 3, 0, 4};
    int sws[10] = {1, 1, 0, 1, 0, 1, 0, 1, 0, 1};
    int cums[11] = {0, 1048576, 1638400, 1703936, 2293760, 2359296,
                    2949120, 3014656, 3604480, 3670016, 4718592};
    for (int k = 0; k < 10; ++k) {
        pa.src[k] = srcs[k]; pa.kw[k] = kws[k]; pa.so[k] = sos[k];
        pa.si[k] = sis[k]; pa.sh[k] = shs[k]; pa.sw[k] = sws[k];
        pa.cum[k] = cums[k];
    }
    pa.cum[10] = cums[10];

    permf_all_k<<<18432, 256, 0, stream>>>(pa, Wf);
    misc_prep_k<<<752, 256, 0, stream>>>(dt2_w, Wg, embed, EmbF, e_w1, WgC, Nrm);

    // ---- encoder ----
    conv1m_k<<<32 * 64, 256, 0, stream>>>(x, WgC, A0b);
    mconv2_k<<<32 * 16, 256, 0, stream>>>(A0b, Wf_ew2, L1);                      // h
    res3_k<<<32 * 32, 256, 0, stream>>>(L1, Wf_er1a, Wf_er1b, L0, nullptr, 0);   // r1 -> L0
    res3_k<<<32 * 32, 256, 0, stream>>>(L0, Wf_er2a, Wf_er2b, L1, A1f, 1);       // ze: bf16->L1, fp32->A1f

    // ---- VQ ----
    vqm_k<<<32 * 32, 256, 0, stream>>>(L1, A1f, EmbF, embed, Nrm, L1, Lpart);

    // ---- decoder ----
    res3_k<<<32 * 32, 256, 0, stream>>>(L1, Wf_dr1a, Wf_dr1b, L0, nullptr, 0);   // d1 -> L0
    res3_k<<<32 * 32, 256, 0, stream>>>(L0, Wf_dr2a, Wf_dr2b, L1, nullptr, 0);   // d2 -> L1
    mdeconv1_k<<<32 * 32, 256, 0, stream>>>(L1, Wf_dt1, dt1_b, A0b);
    mdec2a_k<<<2048, 256, 0, stream>>>(A0b, Wg, Y);
    dec2b_k<<<2048, 256, 0, stream>>>(Y, dt2_b, outp);
    lossfin_k<<<1, 256, 0, stream>>>(Lpart, outp);
}

// Round 18
// 694.089 us; speedup vs baseline: 1.3148x; 1.0047x over previous
//
#include <hip/hip_runtime.h>

// ======================================================================
// VQ-VAE forward, all-MFMA. B=32, CIN=3, IMG=128, D=256, K=512.
// NHWC bf16 activations. Weights frag-ordered Wf[khkw][cch][n][32].
// MFMA 16x16x32 bf16: A[m=lane&15][k=quad*8+j], B[n][k], D col=lane&15,
// row=quad*4+reg.
// R4 tb-epilogue; R6 deterministic loss; R9 fused res-block; R11
// full-line res3 epilogue; R14 T14 async-STAGE; R16 XCD row-chunk
// swizzle (res3 FETCH 38->25MB CONFIRMED; 703.5->697.4).
// R17: COMPLETE the XCD-local chain. conv1m writes rows 8c..8c+7 on
// XCD c (oh=((s&7)<<3)|(s>>3)); mdeconv1 block remap i=((rem&7)<<1)|
// (rem>>4), pp=(rem>>3)&1 -> XCD rem&7 = i>>1 aligns its L1 reads
// (R16 had misaligned them) AND chunks its A0b output; mdec2a row
// remap matches. All remaps bijective.
// ======================================================================

typedef __attribute__((ext_vector_type(8))) short bf16x8;
typedef __attribute__((ext_vector_type(4))) float f32x4;
#define MFMA_B16(a, b, c) __builtin_amdgcn_mfma_f32_16x16x32_bf16(a, b, c, 0, 0, 0)

__device__ inline unsigned short f2b(float f) {
    unsigned int u = __float_as_uint(f);
    unsigned int r = u + 0x7fffu + ((u >> 16) & 1u);
    return (unsigned short)(r >> 16);
}
__device__ inline float b2f(unsigned short u) {
    return __uint_as_float(((unsigned int)u) << 16);
}

// ======================================================================
// batched bf16 frag-order weight permute for the 10 conv/deconv weights.
// ======================================================================
struct PermfArgs {
    const float* src[10];
    int kw[10];
    int so[10], si[10], sh[10], sw[10];
    int cum[11];
};

__global__ void permf_all_k(PermfArgs a, unsigned short* __restrict__ dst)
{
    int gid = blockIdx.x * 256 + threadIdx.x;
    if (gid >= a.cum[10]) return;
    int seg = 0;
    while (seg < 9 && gid >= a.cum[seg + 1]) ++seg;
    int l = gid - a.cum[seg];
    int q = l & 31;
    int n = (l >> 5) & 255;
    int rest = l >> 13;
    int cch = rest & 7;
    int khkw = rest >> 3;
    int kh = khkw / a.kw[seg], kw = khkw % a.kw[seg];
    int ci = cch * 32 + q;
    dst[gid] = f2b(a.src[seg][n * a.so[seg] + ci * a.si[seg] + kh * a.sh[seg] + kw * a.sw[seg]]);
}

// ======================================================================
// misc prep: deconv2 frag weights, codebook frag, conv1 frag weights,
// codebook norms. 752 blocks x 256.
// ======================================================================
__global__ void misc_prep_k(const float* __restrict__ dt2_w, unsigned short* __restrict__ wg,
                            const float* __restrict__ embed, unsigned short* __restrict__ embF,
                            const float* __restrict__ e_w1, unsigned short* __restrict__ wgc,
                            float* __restrict__ nrm)
{
    int blk = blockIdx.x, tid = threadIdx.x;
    if (blk < 48) {
        int idx = blk * 256 + tid;        // < 12288
        int q = idx & 31;
        int n = (idx >> 5) % 48;
        int cch = idx / (48 * 32);
        int ci = cch * 32 + q;
        int oc = n % 3, khkw = n / 3;
        int kh = khkw >> 2, kw = khkw & 3;
        wg[idx] = f2b(dt2_w[ci * 48 + oc * 16 + kh * 4 + kw]);
    } else if (blk < 560) {
        int idx = (blk - 48) * 256 + tid; // < 131072
        int q = idx & 31;
        int n = (idx >> 5) & 511;
        int cch = idx >> 14;
        embF[idx] = f2b(embed[n * 256 + cch * 32 + q]);
    } else if (blk < 624) {
        int idx = (blk - 560) * 256 + tid;  // < 16384
        int q = idx & 31;
        int n = (idx >> 5) & 255;
        int kt = idx >> 13;
        int k = kt * 32 + q;
        float v = 0.f;
        if (k < 48) {
            int ci = k >> 4, kh = (k >> 2) & 3, kwv = k & 3;
            v = e_w1[n * 48 + ci * 16 + kh * 4 + kwv];
        }
        wgc[idx] = f2b(v);
    } else {
        int row = (blk - 624) * 4 + (tid >> 6);
        int lane = tid & 63;
        float s = 0.f;
        #pragma unroll
        for (int c = 0; c < 256; c += 64) {
            float v = embed[row * 256 + c + lane];
            s += v * v;
        }
        #pragma unroll
        for (int off = 1; off < 64; off <<= 1) s += __shfl_xor(s, off);
        if (lane == 0) nrm[row] = s;
    }
}

// ======================================================================
// lossfin: deterministic fixed-order reduction of 4096 wave-partials.
// ======================================================================
__global__ void lossfin_k(const float* __restrict__ lpart, float* __restrict__ out)
{
    __shared__ float red[256];
    int tid = threadIdx.x;
    float s = 0.f;
    #pragma unroll
    for (int i = 0; i < 16; ++i) s += lpart[tid * 16 + i];
    red[tid] = s;
    __syncthreads();
    for (int off = 128; off > 0; off >>= 1) {
        if (tid < off) red[tid] += red[tid + off];
        __syncthreads();
    }
    if (tid == 0) {
        float m = red[0] * (1.0f / 32768.0f);
        out[1572864] = m;
        out[1572865] = m;
    }
}

// ======================================================================
// conv1m: MFMA im2col conv1. x NCHW fp32 -> NHWC bf16 (B,64,64,256),
// k4 s2 p1, ReLU. grid = B*64. R17: output rows 8c..8c+7 on XCD c via
// oh = ((s&7)<<3)|(s>>3) (bijective; XCD = bh%8 = s&7 = oh>>3).
// ======================================================================
__global__ void __launch_bounds__(256, 4)
conv1m_k(const float* __restrict__ x, const unsigned short* __restrict__ wgc,
         unsigned short* __restrict__ out)
{
    int bh = blockIdx.x;             // b*64 + s
    int b = bh >> 6;
    int s6 = bh & 63;
    int oh = ((s6 & 7) << 3) | (s6 >> 3);   // R17 XCD chunking (bijective)
    int bhrow = (b << 6) + oh;
    int tid = threadIdx.x;
    int lane = tid & 63, wv = tid >> 6;
    int m = lane & 15, quad = lane >> 4;
    __shared__ float xrow[3][4][130];
    __shared__ __align__(16) unsigned short imc[64 * 72];
    for (int s = tid; s < 1560; s += 256) {
        int col = s % 130;
        int t = s / 130;
        int r = t & 3;
        int c = t >> 2;
        int ih = 2 * oh - 1 + r, iw = col - 1;
        float v = 0.f;
        if ((unsigned)ih < 128u && (unsigned)iw < 128u)
            v = x[(((b * 3 + c) << 7) + ih) * 128 + iw];
        xrow[c][r][col] = v;
    }
    __syncthreads();
    for (int s = tid; s < 4096; s += 256) {
        int px = s >> 6, k = s & 63;
        float v = 0.f;
        if (k < 48) {
            int ci = k >> 4, kh = (k >> 2) & 3, kw = k & 3;
            v = xrow[ci][kh][2 * px + kw];
        }
        imc[px * 72 + k] = f2b(v);
    }
    __syncthreads();
    f32x4 acc[16];
    f32x4 z = {0.f, 0.f, 0.f, 0.f};
    #pragma unroll
    for (int i = 0; i < 16; ++i) acc[i] = z;
    bf16x8 a0 = *(const bf16x8*)&imc[((wv << 4) + m) * 72 + (quad << 3)];
    bf16x8 a1 = *(const bf16x8*)&imc[((wv << 4) + m) * 72 + 32 + (quad << 3)];
    #pragma unroll
    for (int nt = 0; nt < 16; ++nt) {
        bf16x8 b0 = *(const bf16x8*)&wgc[(nt * 16 + m) * 32 + (quad << 3)];
        bf16x8 b1 = *(const bf16x8*)&wgc[(256 + nt * 16 + m) * 32 + (quad << 3)];
        acc[nt] = MFMA_B16(a0, b0, acc[nt]);
        acc[nt] = MFMA_B16(a1, b1, acc[nt]);
    }
    #pragma unroll
    for (int nt = 0; nt < 16; ++nt)
        #pragma unroll
        for (int r = 0; r < 4; ++r) {
            int px = (wv << 4) + quad * 4 + r;
            out[(((bhrow << 6) + px) << 8) + nt * 16 + (lane & 15)] = f2b(fmaxf(acc[nt][r], 0.f));
        }
}

// ======================================================================
// mconv2: k4 s2 p1, (B,64,64,256)->(B,32,32,256), ReLU. M=64. grid B*16.
// R14 T14 async-STAGE. R16 swizzle j=((r16&7)<<1)|(r16>>3): XCD=r16&7=
// j>>1 -> reads A0b rows 4j-1..4j+6 in chunk 8*(j>>1) (R17-aligned),
// writes L1 rows 4c..4c+3 on XCD c (res3-aligned).
// ======================================================================
__global__ void __launch_bounds__(256, 2)
mconv2_k(const unsigned short* __restrict__ in, const unsigned short* __restrict__ wf,
         unsigned short* __restrict__ out)
{
    int blk = blockIdx.x;
    int bb = blk >> 4;
    int r16 = blk & 15;
    int j = ((r16 & 7) << 1) | (r16 >> 3);   // R16 XCD swizzle (bijective)
    int tid = threadIdx.x;
    int lane = tid & 63;
    int n0 = (tid >> 6) << 6;
    int m = lane & 15, quad = lane >> 4;
    __shared__ __align__(16) unsigned short win[2 * 66 * 264];  // 68.1 KB
    f32x4 acc[2][2][4];
    f32x4 z = {0.f, 0.f, 0.f, 0.f};
    #pragma unroll
    for (int a = 0; a < 2; ++a)
        #pragma unroll
        for (int i = 0; i < 2; ++i)
            #pragma unroll
            for (int t = 0; t < 4; ++t) acc[a][i][t] = z;

    int4 rv[17];

    // ---- prologue: stage kh=0 ----
    #pragma unroll
    for (int k = 0; k < 17; ++k) {
        int s = tid + (k << 8);
        rv[k] = make_int4(0, 0, 0, 0);
        if (s < 4224) {
            int c32 = s & 31;
            int t2 = s >> 5;
            int col = t2 % 66;
            int rr = t2 / 66;
            int ih = 4 * j - 1 + 2 * rr, iw = col - 1;
            if ((unsigned)ih < 64u && (unsigned)iw < 64u)
                rv[k] = *(const int4*)&in[((((bb << 6) + ih) << 6) + iw) * 256 + (c32 << 3)];
        }
    }
    #pragma unroll
    for (int k = 0; k < 17; ++k) {
        int s = tid + (k << 8);
        if (s < 4224) {
            int c32 = s & 31;
            int t2 = s >> 5;
            int col = t2 % 66;
            int rr = t2 / 66;
            int cs = (col >> 1) + (col & 1) * 33;
            *(int4*)&win[(rr * 66 + cs) * 264 + (c32 << 3)] = rv[k];
        }
    }
    __syncthreads();

    for (int kh = 0; kh < 4; ++kh) {
        // ---- T14: issue kh+1 loads BEFORE compute ----
        if (kh < 3) {
            #pragma unroll
            for (int k = 0; k < 17; ++k) {
                int s = tid + (k << 8);
                rv[k] = make_int4(0, 0, 0, 0);
                if (s < 4224) {
                    int c32 = s & 31;
                    int t2 = s >> 5;
                    int col = t2 % 66;
                    int rr = t2 / 66;
                    int ih = 4 * j + kh + 2 * rr, iw = col - 1;   // kh+1 - 1 = kh
                    if ((unsigned)ih < 64u && (unsigned)iw < 64u)
                        rv[k] = *(const int4*)&in[((((bb << 6) + ih) << 6) + iw) * 256 + (c32 << 3)];
                }
            }
        }
        // ---- compute kh ----
        for (int kw = 0; kw < 4; ++kw) {
            int csoff = (kw >> 1) + (kw & 1) * 33;
            #pragma unroll
            for (int cch = 0; cch < 8; ++cch) {
                const unsigned short* ba = &win[(m + csoff) * 264 + (cch << 5) + (quad << 3)];
                bf16x8 a00 = *(const bf16x8*)ba;
                bf16x8 a01 = *(const bf16x8*)(ba + 16 * 264);
                bf16x8 a10 = *(const bf16x8*)(ba + 66 * 264);
                bf16x8 a11 = *(const bf16x8*)(ba + 82 * 264);
                int wbase = ((((kh << 2) + kw) * 8 + cch) * 256 + n0 + m) * 32 + (quad << 3);
                bf16x8 b0 = *(const bf16x8*)&wf[wbase];
                bf16x8 b1 = *(const bf16x8*)&wf[wbase + 16 * 32];
                bf16x8 b2 = *(const bf16x8*)&wf[wbase + 32 * 32];
                bf16x8 b3 = *(const bf16x8*)&wf[wbase + 48 * 32];
                acc[0][0][0] = MFMA_B16(a00, b0, acc[0][0][0]);
                acc[0][0][1] = MFMA_B16(a00, b1, acc[0][0][1]);
                acc[0][0][2] = MFMA_B16(a00, b2, acc[0][0][2]);
                acc[0][0][3] = MFMA_B16(a00, b3, acc[0][0][3]);
                acc[0][1][0] = MFMA_B16(a01, b0, acc[0][1][0]);
                acc[0][1][1] = MFMA_B16(a01, b1, acc[0][1][1]);
                acc[0][1][2] = MFMA_B16(a01, b2, acc[0][1][2]);
                acc[0][1][3] = MFMA_B16(a01, b3, acc[0][1][3]);
                acc[1][0][0] = MFMA_B16(a10, b0, acc[1][0][0]);
                acc[1][0][1] = MFMA_B16(a10, b1, acc[1][0][1]);
                acc[1][0][2] = MFMA_B16(a10, b2, acc[1][0][2]);
                acc[1][0][3] = MFMA_B16(a10, b3, acc[1][0][3]);
                acc[1][1][0] = MFMA_B16(a11, b0, acc[1][1][0]);
                acc[1][1][1] = MFMA_B16(a11, b1, acc[1][1][1]);
                acc[1][1][2] = MFMA_B16(a11, b2, acc[1][1][2]);
                acc[1][1][3] = MFMA_B16(a11, b3, acc[1][1][3]);
            }
        }
        __syncthreads();          // all waves done reading win
        if (kh < 3) {
            #pragma unroll
            for (int k = 0; k < 17; ++k) {
                int s = tid + (k << 8);
                if (s < 4224) {
                    int c32 = s & 31;
                    int t2 = s >> 5;
                    int col = t2 % 66;
                    int rr = t2 / 66;
                    int cs = (col >> 1) + (col & 1) * 33;
                    *(int4*)&win[(rr * 66 + cs) * 264 + (c32 << 3)] = rv[k];
                }
            }
            __syncthreads();      // win holds kh+1
        }
    }
    #pragma unroll
    for (int row = 0; row < 2; ++row) {
        int oh = 2 * j + row;
        #pragma unroll
        for (int mt = 0; mt < 2; ++mt)
            #pragma unroll
            for (int nt = 0; nt < 4; ++nt)
                #pragma unroll
                for (int r = 0; r < 4; ++r) {
                    int px = mt * 16 + quad * 4 + r;
                    int col = n0 + nt * 16 + m;
                    out[((((bb << 5) + oh) << 5) + px) * 256 + col] = f2b(fmaxf(acc[row][mt][nt][r], 0.f));
                }
    }
}

// ======================================================================
// res3: FUSED residual block, M=32. grid = B*32 = 1024, 4 blocks/CU.
// R14 T14 async-STAGE. R16 row XCD swizzle j=((r32&7)<<2)|(r32>>3).
// ======================================================================
__global__ void __launch_bounds__(256, 4)
res3_k(const unsigned short* __restrict__ in, const unsigned short* __restrict__ wfA,
       const unsigned short* __restrict__ wfB, unsigned short* __restrict__ outb,
       float* __restrict__ outf, int f32out)
{
    int blk = blockIdx.x;
    int bb = blk >> 5;
    int r32 = blk & 31;
    int j = ((r32 & 7) << 2) | (r32 >> 3);   // R16 XCD swizzle (bijective)
    int tid = threadIdx.x;
    int lane = tid & 63;
    int n0 = (tid >> 6) << 6;
    int m = lane & 15, quad = lane >> 4;
    __shared__ __align__(16) unsigned short win[3 * 34 * 132];  // 26.9 KB
    f32x4 acc[2][4];
    f32x4 z = {0.f, 0.f, 0.f, 0.f};
    #pragma unroll
    for (int i = 0; i < 2; ++i)
        #pragma unroll
        for (int t = 0; t < 4; ++t) acc[i][t] = z;

    int4 rv[7];

    // ---- prologue: stage phase c0=0 ----
    #pragma unroll
    for (int k = 0; k < 7; ++k) {
        int s = tid + (k << 8);
        rv[k] = make_int4(0, 0, 0, 0);
        if (s < 1632) {
            int c16 = s & 15;
            int t2 = s >> 4;
            int col = t2 % 34;
            int rr = t2 / 34;
            int ih = j - 1 + rr, iw = col - 1;
            if ((unsigned)ih < 32u && (unsigned)iw < 32u)
                rv[k] = *(const int4*)&in[((((bb << 5) + ih) << 5) + iw) * 256 + (c16 << 3)];
        }
    }
    #pragma unroll
    for (int k = 0; k < 7; ++k) {
        int s = tid + (k << 8);
        if (s < 1632) {
            int c16 = s & 15;
            int t2 = s >> 4;
            int col = t2 % 34;
            int rr = t2 / 34;
            *(int4*)&win[(rr * 34 + col) * 132 + (c16 << 3)] = rv[k];
        }
    }
    __syncthreads();

    // ---- part 1: 3x3 conv, 2 channel phases, T14 split ----
    for (int ph = 0; ph < 2; ++ph) {
        if (ph == 0) {
            #pragma unroll
            for (int k = 0; k < 7; ++k) {
                int s = tid + (k << 8);
                rv[k] = make_int4(0, 0, 0, 0);
                if (s < 1632) {
                    int c16 = s & 15;
                    int t2 = s >> 4;
                    int col = t2 % 34;
                    int rr = t2 / 34;
                    int ih = j - 1 + rr, iw = col - 1;
                    if ((unsigned)ih < 32u && (unsigned)iw < 32u)
                        rv[k] = *(const int4*)&in[((((bb << 5) + ih) << 5) + iw) * 256 + 128 + (c16 << 3)];
                }
            }
        }
        for (int kh = 0; kh < 3; ++kh) {
            #pragma unroll
            for (int kw = 0; kw < 3; ++kw) {
                #pragma unroll
                for (int cch = 0; cch < 4; ++cch) {
                    const unsigned short* ba = &win[(kh * 34 + m + kw) * 132 + (cch << 5) + (quad << 3)];
                    bf16x8 a0 = *(const bf16x8*)ba;
                    bf16x8 a1 = *(const bf16x8*)(ba + 16 * 132);
                    int cg = ph * 4 + cch;
                    int wbase = (((kh * 3 + kw) * 8 + cg) * 256 + n0 + m) * 32 + (quad << 3);
                    bf16x8 b0 = *(const bf16x8*)&wfA[wbase];
                    bf16x8 b1 = *(const bf16x8*)&wfA[wbase + 16 * 32];
                    bf16x8 b2 = *(const bf16x8*)&wfA[wbase + 32 * 32];
                    bf16x8 b3 = *(const bf16x8*)&wfA[wbase + 48 * 32];
                    acc[0][0] = MFMA_B16(a0, b0, acc[0][0]);
                    acc[0][1] = MFMA_B16(a0, b1, acc[0][1]);
                    acc[0][2] = MFMA_B16(a0, b2, acc[0][2]);
                    acc[0][3] = MFMA_B16(a0, b3, acc[0][3]);
                    acc[1][0] = MFMA_B16(a1, b0, acc[1][0]);
                    acc[1][1] = MFMA_B16(a1, b1, acc[1][1]);
                    acc[1][2] = MFMA_B16(a1, b2, acc[1][2]);
                    acc[1][3] = MFMA_B16(a1, b3, acc[1][3]);
                }
            }
        }
        __syncthreads();          // done reading win (phase ph)
        if (ph == 0) {
            #pragma unroll
            for (int k = 0; k < 7; ++k) {
                int s = tid + (k << 8);
                if (s < 1632) {
                    int c16 = s & 15;
                    int t2 = s >> 4;
                    int col = t2 % 34;
                    int rr = t2 / 34;
                    *(int4*)&win[(rr * 34 + col) * 132 + (c16 << 3)] = rv[k];
                }
            }
            __syncthreads();      // win holds phase 1
        }
    }

    // ---- handoff: ReLU(conv3) -> LDS bf16 [32][264] (alias over win) ----
    #pragma unroll
    for (int i = 0; i < 2; ++i)
        #pragma unroll
        for (int nt = 0; nt < 4; ++nt)
            #pragma unroll
            for (int r = 0; r < 4; ++r) {
                int p = i * 16 + quad * 4 + r;       // 0..31
                win[p * 264 + n0 + nt * 16 + m] = f2b(fmaxf(acc[i][nt][r], 0.f));
            }
    __syncthreads();   // handoff complete

    // ---- part 2: 1x1 matmul from LDS ----
    f32x4 acc2[2][4];
    #pragma unroll
    for (int i = 0; i < 2; ++i)
        #pragma unroll
        for (int t = 0; t < 4; ++t) acc2[i][t] = z;

    #pragma unroll
    for (int cch = 0; cch < 8; ++cch) {
        bf16x8 a0 = *(const bf16x8*)&win[m * 264 + (cch << 5) + (quad << 3)];
        bf16x8 a1 = *(const bf16x8*)&win[(m + 16) * 264 + (cch << 5) + (quad << 3)];
        int wbase = (cch * 256 + n0 + m) * 32 + (quad << 3);
        bf16x8 b0 = *(const bf16x8*)&wfB[wbase];
        bf16x8 b1 = *(const bf16x8*)&wfB[wbase + 16 * 32];
        bf16x8 b2 = *(const bf16x8*)&wfB[wbase + 32 * 32];
        bf16x8 b3 = *(const bf16x8*)&wfB[wbase + 48 * 32];
        acc2[0][0] = MFMA_B16(a0, b0, acc2[0][0]);
        acc2[0][1] = MFMA_B16(a0, b1, acc2[0][1]);
        acc2[0][2] = MFMA_B16(a0, b2, acc2[0][2]);
        acc2[0][3] = MFMA_B16(a0, b3, acc2[0][3]);
        acc2[1][0] = MFMA_B16(a1, b0, acc2[1][0]);
        acc2[1][1] = MFMA_B16(a1, b1, acc2[1][1]);
        acc2[1][2] = MFMA_B16(a1, b2, acc2[1][2]);
        acc2[1][3] = MFMA_B16(a1, b3, acc2[1][3]);
    }

    // ---- epilogue: fp32 LDS spill (16-px halves) -> coalesced IO ----
    float* winf = (float*)win;         // 16*260 floats = 16.6 KB <= 26.9 KB
    int rowbase = ((bb << 5) + j) << 13;   // swizzled row j, 32 px * 256
    #pragma unroll
    for (int half = 0; half < 2; ++half) {
        __syncthreads();   // winf free
        #pragma unroll
        for (int nt = 0; nt < 4; ++nt)
            #pragma unroll
            for (int r = 0; r < 4; ++r) {
                int pxl = quad * 4 + r;              // 0..15
                winf[pxl * 260 + n0 + nt * 16 + m] = acc2[half][nt][r];
            }
        __syncthreads();   // winf ready
        #pragma unroll
        for (int k = 0; k < 2; ++k) {
            int s = tid + k * 256;
            int pxl = s >> 5;          // 0..15
            int c8 = s & 31;           // 8-channel group
            int px = half * 16 + pxl;
            int idx = rowbase + (px << 8) + (c8 << 3);
            int4 rvv = *(const int4*)&in[idx];          // 8 bf16 residual
            const float* wp = &winf[pxl * 260 + (c8 << 3)];
            float v0 = wp[0] + b2f((unsigned short)((unsigned)rvv.x & 0xffffu));
            float v1 = wp[1] + b2f((unsigned short)((unsigned)rvv.x >> 16));
            float v2 = wp[2] + b2f((unsigned short)((unsigned)rvv.y & 0xffffu));
            float v3 = wp[3] + b2f((unsigned short)((unsigned)rvv.y >> 16));
            float v4 = wp[4] + b2f((unsigned short)((unsigned)rvv.z & 0xffffu));
            float v5 = wp[5] + b2f((unsigned short)((unsigned)rvv.z >> 16));
            float v6 = wp[6] + b2f((unsigned short)((unsigned)rvv.w & 0xffffu));
            float v7 = wp[7] + b2f((unsigned short)((unsigned)rvv.w >> 16));
            unsigned w0 = (unsigned)f2b(v0) | ((unsigned)f2b(v1) << 16);
            unsigned w1 = (unsigned)f2b(v2) | ((unsigned)f2b(v3) << 16);
            unsigned w2 = (unsigned)f2b(v4) | ((unsigned)f2b(v5) << 16);
            unsigned w3 = (unsigned)f2b(v6) | ((unsigned)f2b(v7) << 16);
            *(int4*)&outb[idx] = make_int4((int)w0, (int)w1, (int)w2, (int)w3);
            if (f32out) {
                *(float4*)&outf[idx]     = make_float4(v0, v1, v2, v3);
                *(float4*)&outf[idx + 4] = make_float4(v4, v5, v6, v7);
            }
        }
    }
}

// ======================================================================
// mdeconv1: ConvTranspose2d(256->256,k4,s2,p1)+bias+ReLU. R1 2-row
// structure + R4 tb-epilogue. grid = 1024. R17: block remap
// i=((rem&7)<<1)|(rem>>4), pp=(rem>>3)&1 -> XCD rem&7 = i>>1 matches
// the L1 input chunk (rows ~2i in chunk i/2) AND writes A0b rows
// 8c..8c+7 on XCD c (mdec2a-aligned).
// ======================================================================
__global__ void __launch_bounds__(256, 3)
mdeconv1_k(const unsigned short* __restrict__ in, const unsigned short* __restrict__ wf,
           const float* __restrict__ bias, unsigned short* __restrict__ out)
{
    int blk = blockIdx.x;
    int bb = blk >> 5;
    int rem = blk & 31;
    int i  = ((rem & 7) << 1) | (rem >> 4);   // R17 remap (bijective)
    int pp = (rem >> 3) & 1;
    int oy_a = pp + 4 * i;
    int p = (oy_a + 1) & 1;
    int r0a = (oy_a + 1 - p) >> 1;
    int rbase = r0a - 1;
    int tid = threadIdx.x;
    int lane = tid & 63;
    int n0 = (tid >> 6) << 6;
    int m = lane & 15, quad = lane >> 4;
    __shared__ __align__(16) unsigned short win[3 * 34 * 264];   // 53.9 KB
    __shared__ __align__(16) unsigned short tb[16 * 264];        // 8.4 KB

    for (int s = tid; s < 3 * 34 * 32; s += 256) {
        int c8 = s & 31;
        int t2 = s >> 5;
        int col = t2 % 34;
        int rr = t2 / 34;
        int ih = rbase + rr, iw = col - 1;
        int4 v = make_int4(0, 0, 0, 0);
        if ((unsigned)ih < 32u && (unsigned)iw < 32u)
            v = *(const int4*)&in[((((bb << 5) + ih) << 5) + iw) * 256 + (c8 << 3)];
        *(int4*)&win[(rr * 34 + col) * 264 + (c8 << 3)] = v;
    }
    __syncthreads();

    for (int par = 0; par < 2; ++par) {
        f32x4 acc[2][2][4];
        f32x4 z = {0.f, 0.f, 0.f, 0.f};
        #pragma unroll
        for (int a = 0; a < 2; ++a)
            #pragma unroll
            for (int i2 = 0; i2 < 2; ++i2)
                #pragma unroll
                for (int t = 0; t < 4; ++t) acc[a][i2][t] = z;

        #pragma unroll
        for (int t = 0; t < 2; ++t) {
            int kh = p + 2 * t;
            #pragma unroll
            for (int u = 0; u < 2; ++u) {
                int kw = (1 - par) + 2 * u;
                int ixoff = par - u + 1;
                #pragma unroll
                for (int cch = 0; cch < 8; ++cch) {
                    const unsigned short* baA = &win[((1 - t) * 34 + m + ixoff) * 264 + (cch << 5) + (quad << 3)];
                    const unsigned short* baB = baA + 34 * 264;
                    bf16x8 a00 = *(const bf16x8*)baA;
                    bf16x8 a01 = *(const bf16x8*)(baA + 16 * 264);
                    bf16x8 a10 = *(const bf16x8*)baB;
                    bf16x8 a11 = *(const bf16x8*)(baB + 16 * 264);
                    int wbase = ((((kh << 2) + kw) * 8 + cch) * 256 + n0 + m) * 32 + (quad << 3);
                    bf16x8 b0 = *(const bf16x8*)&wf[wbase];
                    bf16x8 b1 = *(const bf16x8*)&wf[wbase + 16 * 32];
                    bf16x8 b2 = *(const bf16x8*)&wf[wbase + 32 * 32];
                    bf16x8 b3 = *(const bf16x8*)&wf[wbase + 48 * 32];
                    acc[0][0][0] = MFMA_B16(a00, b0, acc[0][0][0]);
                    acc[0][0][1] = MFMA_B16(a00, b1, acc[0][0][1]);
                    acc[0][0][2] = MFMA_B16(a00, b2, acc[0][0][2]);
                    acc[0][0][3] = MFMA_B16(a00, b3, acc[0][0][3]);
                    acc[0][1][0] = MFMA_B16(a01, b0, acc[0][1][0]);
                    acc[0][1][1] = MFMA_B16(a01, b1, acc[0][1][1]);
                    acc[0][1][2] = MFMA_B16(a01, b2, acc[0][1][2]);
                    acc[0][1][3] = MFMA_B16(a01, b3, acc[0][1][3]);
                    acc[1][0][0] = MFMA_B16(a10, b0, acc[1][0][0]);
                    acc[1][0][1] = MFMA_B16(a10, b1, acc[1][0][1]);
                    acc[1][0][2] = MFMA_B16(a10, b2, acc[1][0][2]);
                    acc[1][0][3] = MFMA_B16(a10, b3, acc[1][0][3]);
                    acc[1][1][0] = MFMA_B16(a11, b0, acc[1][1][0]);
                    acc[1][1][1] = MFMA_B16(a11, b1, acc[1][1][1]);
                    acc[1][1][2] = MFMA_B16(a11, b2, acc[1][1][2]);
                    acc[1][1][3] = MFMA_B16(a11, b3, acc[1][1][3]);
                }
            }
        }

        #pragma unroll
        for (int row = 0; row < 2; ++row) {
            int oy = oy_a + 2 * row;
            #pragma unroll
            for (int mt = 0; mt < 2; ++mt) {
                __syncthreads();
                #pragma unroll
                for (int nt = 0; nt < 4; ++nt) {
                    float bs = bias[n0 + nt * 16 + m];
                    #pragma unroll
                    for (int rr = 0; rr < 4; ++rr) {
                        float v = fmaxf(acc[row][mt][nt][rr] + bs, 0.f);
                        tb[(quad * 4 + rr) * 264 + n0 + nt * 16 + m] = f2b(v);
                    }
                }
                __syncthreads();
                #pragma unroll
                for (int k = 0; k < 2; ++k) {
                    int s = tid + k * 256;
                    int pxl = s >> 5;
                    int c8 = s & 31;
                    int ox = 2 * (mt * 16 + pxl) + par;
                    *(int4*)&out[((((bb << 6) + oy) << 6) + ox) * 256 + (c8 << 3)] =
                        *(const int4*)&tb[pxl * 264 + (c8 << 3)];
                }
            }
        }
    }
}

// ======================================================================
// vqm: MFMA VQ + exact fp32 gather/loss. grid = B*32. R16 row swizzle;
// lpart by LOGICAL row (loss reduction order identical).
// ======================================================================
__global__ void __launch_bounds__(256, 2)
vqm_k(const unsigned short* __restrict__ zeb, const float* __restrict__ zef,
      const unsigned short* __restrict__ embF, const float* __restrict__ embed,
      const float* __restrict__ nrm, unsigned short* __restrict__ zq,
      float* __restrict__ lpart)
{
    int bh = blockIdx.x;
    int bbv = bh >> 5;
    int rw = bh & 31;
    int jrow = ((rw & 7) << 2) | (rw >> 3);   // R16 XCD swizzle (bijective)
    int lrow = (bbv << 5) + jrow;             // logical row id
    int tid = threadIdx.x;
    int lane = tid & 63;
    int wv = tid >> 6;
    int m = lane & 15, quad = lane >> 4;
    __shared__ __align__(16) unsigned short win[32 * 264];
    __shared__ float bvv[4][32];
    __shared__ int   bii[4][32];
    __shared__ int   bidx[32];
    int rowbase = lrow << 13;
    for (int s = tid; s < 32 * 32; s += 256) {
        int c8 = s & 31, px = s >> 5;
        *(int4*)&win[px * 264 + (c8 << 3)] = *(const int4*)&zeb[rowbase + (px << 8) + (c8 << 3)];
    }
    __syncthreads();

    f32x4 acc[2][8];
    f32x4 z = {0.f, 0.f, 0.f, 0.f};
    #pragma unroll
    for (int i = 0; i < 2; ++i)
        #pragma unroll
        for (int jj = 0; jj < 8; ++jj) acc[i][jj] = z;

    #pragma unroll
    for (int cch = 0; cch < 8; ++cch) {
        bf16x8 a0 = *(const bf16x8*)&win[m * 264 + (cch << 5) + (quad << 3)];
        bf16x8 a1 = *(const bf16x8*)&win[(m + 16) * 264 + (cch << 5) + (quad << 3)];
        #pragma unroll
        for (int nt = 0; nt < 8; ++nt) {
            bf16x8 b = *(const bf16x8*)&embF[((cch << 9) + (wv << 7) + (nt << 4) + m) * 32 + (quad << 3)];
            acc[0][nt] = MFMA_B16(a0, b, acc[0][nt]);
            acc[1][nt] = MFMA_B16(a1, b, acc[1][nt]);
        }
    }

    float nv[8];
    #pragma unroll
    for (int nt = 0; nt < 8; ++nt) nv[nt] = nrm[(wv << 7) + (nt << 4) + m];

    #pragma unroll
    for (int mt = 0; mt < 2; ++mt)
        #pragma unroll
        for (int r = 0; r < 4; ++r) {
            float bv = 1e30f;
            int bi = 0x7fffffff;
            #pragma unroll
            for (int nt = 0; nt < 8; ++nt) {
                float d = nv[nt] - 2.f * acc[mt][nt][r];
                int n = (wv << 7) + (nt << 4) + m;
                if (d < bv || (d == bv && n < bi)) { bv = d; bi = n; }
            }
            #pragma unroll
            for (int off = 1; off < 16; off <<= 1) {
                float ov = __shfl_xor(bv, off);
                int oi = __shfl_xor(bi, off);
                if (ov < bv || (ov == bv && oi < bi)) { bv = ov; bi = oi; }
            }
            if (m == 0) {
                int px = mt * 16 + quad * 4 + r;
                bvv[wv][px] = bv;
                bii[wv][px] = bi;
            }
        }
    __syncthreads();
    if (tid < 32) {
        float bv = bvv[0][tid];
        int bi = bii[0][tid];
        #pragma unroll
        for (int w2 = 1; w2 < 4; ++w2) {
            float ov = bvv[w2][tid];
            int oi = bii[w2][tid];
            if (ov < bv || (ov == bv && oi < bi)) { bv = ov; bi = oi; }
        }
        bidx[tid] = bi;
    }
    __syncthreads();

    float lsum = 0.f;
    #pragma unroll
    for (int jj = 0; jj < 8; ++jj) {
        int px = (wv << 3) + jj;
        int bi = bidx[px];
        int pix = (lrow << 5) + px;
        const float4 e = *(const float4*)&embed[bi * 256 + (lane << 2)];
        const float4 zv = *(const float4*)&zef[(pix << 8) + (lane << 2)];
        ushort4 eq;
        eq.x = f2b(e.x); eq.y = f2b(e.y); eq.z = f2b(e.z); eq.w = f2b(e.w);
        *(ushort4*)&zq[(pix << 8) + (lane << 2)] = eq;
        float dx = zv.x - e.x, dy = zv.y - e.y, dz = zv.z - e.z, dw = zv.w - e.w;
        lsum += dx * dx + dy * dy + dz * dz + dw * dw;
    }
    #pragma unroll
    for (int off = 1; off < 64; off <<= 1) lsum += __shfl_xor(lsum, off);
    if (lane == 0) lpart[(lrow << 2) + wv] = lsum;   // logical-row index: order-invariant
}

// ======================================================================
// mdec2a: deconv2 pass 1 — Y[B*64*64, 48] = X[.,256] x Wg[256,48].
// R17: row remap matches mdeconv1's A0b chunks (rows 8c..8c+7 on c).
// ======================================================================
__global__ void __launch_bounds__(256, 4)
mdec2a_k(const unsigned short* __restrict__ in, const unsigned short* __restrict__ wg,
         float* __restrict__ Y)
{
    int tid = threadIdx.x;
    int lane = tid & 63;
    int wv = tid >> 6;
    int m = lane & 15, quad = lane >> 4;
    __shared__ __align__(16) unsigned short win[64 * 264];
    int blk = blockIdx.x;
    int bb6 = blk >> 6;
    int s6 = blk & 63;
    int rrow = ((s6 & 7) << 3) | (s6 >> 3);   // R17 remap (bijective); XCD = s6&7 = rrow>>3
    int pxbase = ((bb6 << 6) + rrow) << 6;
    for (int s = tid; s < 64 * 32; s += 256) {
        int c8 = s & 31, px = s >> 5;
        *(int4*)&win[px * 264 + (c8 << 3)] = *(const int4*)&in[((pxbase + px) << 8) + (c8 << 3)];
    }
    __syncthreads();
    f32x4 acc[3];
    f32x4 z = {0.f, 0.f, 0.f, 0.f};
    acc[0] = z; acc[1] = z; acc[2] = z;
    #pragma unroll
    for (int cch = 0; cch < 8; ++cch) {
        bf16x8 a = *(const bf16x8*)&win[((wv << 4) + m) * 264 + (cch << 5) + (quad << 3)];
        #pragma unroll
        for (int nt = 0; nt < 3; ++nt) {
            bf16x8 b = *(const bf16x8*)&wg[(cch * 48 + nt * 16 + m) * 32 + (quad << 3)];
            acc[nt] = MFMA_B16(a, b, acc[nt]);
        }
    }
    #pragma unroll
    for (int nt = 0; nt < 3; ++nt)
        #pragma unroll
        for (int r = 0; r < 4; ++r) {
            int px = pxbase + (wv << 4) + quad * 4 + r;
            Y[px * 48 + nt * 16 + m] = acc[nt][r];
        }
}

// ======================================================================
// dec2b: deconv2 pass 2 — gather taps, +bias, sigmoid, NCHW out.
// ======================================================================
__global__ void dec2b_k(const float* __restrict__ Y, const float* __restrict__ bias,
                        float* __restrict__ out)
{
    int idx = blockIdx.x * 256 + threadIdx.x;    // < 524288
    int b = idx >> 14;
    int rem = idx & 16383;
    int oy = rem >> 7;
    int ox = rem & 127;
    int p = (oy + 1) & 1;
    int q = (ox + 1) & 1;
    float acc0 = bias[0], acc1 = bias[1], acc2 = bias[2];
    #pragma unroll
    for (int t = 0; t < 2; ++t) {
        int kh = p + 2 * t;
        int ih = (oy + 1 - kh) >> 1;
        if ((unsigned)ih >= 64u) continue;
        #pragma unroll
        for (int u = 0; u < 2; ++u) {
            int kw = q + 2 * u;
            int iw = (ox + 1 - kw) >> 1;
            if ((unsigned)iw >= 64u) continue;
            int base = ((((b << 6) + ih) << 6) + iw) * 48 + ((kh << 2) + kw) * 3;
            acc0 += Y[base];
            acc1 += Y[base + 1];
            acc2 += Y[base + 2];
        }
    }
    int obase = (b * 3 << 14) + (oy << 7) + ox;
    out[obase]           = 1.f / (1.f + expf(-acc0));
    out[obase + 16384]   = 1.f / (1.f + expf(-acc1));
    out[obase + 32768]   = 1.f / (1.f + expf(-acc2));
}

// ======================================================================
extern "C" void kernel_launch(void* const* d_in, const int* in_sizes, int n_in,
                              void* d_out, int out_size, void* d_ws, size_t ws_size,
                              hipStream_t stream)
{
    (void)in_sizes; (void)n_in; (void)out_size; (void)ws_size;
    const float* x      = (const float*)d_in[0];
    const float* embed  = (const float*)d_in[1];
    const float* e_w1   = (const float*)d_in[2];
    const float* e_w2   = (const float*)d_in[3];
    const float* e_r1a  = (const float*)d_in[4];
    const float* e_r1b  = (const float*)d_in[5];
    const float* e_r2a  = (const float*)d_in[6];
    const float* e_r2b  = (const float*)d_in[7];
    const float* d_r1a  = (const float*)d_in[8];
    const float* d_r1b  = (const float*)d_in[9];
    const float* d_r2a  = (const float*)d_in[10];
    const float* d_r2b  = (const float*)d_in[11];
    const float* dt1_w  = (const float*)d_in[12];
    const float* dt1_b  = (const float*)d_in[13];
    const float* dt2_w  = (const float*)d_in[14];
    const float* dt2_b  = (const float*)d_in[15];
    float* outp = (float*)d_out;

    // ---- workspace layout ----
    char* base = (char*)d_ws;
    size_t off = 0;
    auto alloc = [&](size_t bytes) { char* p = base + off; off += (bytes + 255) & ~size_t(255); return p; };
    unsigned short* A0b = (unsigned short*)alloc(67108864);  // (B,64,64,256) bf16
    float*          A1f = (float*)alloc(33554432);           // ze fp32; later Y
    unsigned short* L0  = (unsigned short*)alloc(16777216);
    unsigned short* L1  = (unsigned short*)alloc(16777216);
    unsigned short* L2  = (unsigned short*)alloc(16777216);  // (unused after R9 fusion; kept)
    unsigned short* Wf  = (unsigned short*)alloc(9437184);   // 10 frag-ordered weights
    unsigned short* Wg  = (unsigned short*)alloc(24576);     // deconv2 frag weights
    unsigned short* EmbF = (unsigned short*)alloc(262144);   // codebook frag bf16
    unsigned short* WgC = (unsigned short*)alloc(32768);     // conv1 frag weights
    float* Nrm  = (float*)alloc(2048);
    float* Lpart = (float*)alloc(16384);                     // 4096 loss partials
    float* Y = A1f;   // alias: ze dead after vqm_k
    (void)L2;

    // frag-weight segment offsets inside Wf (element counts)
    unsigned short* Wf_ew2  = Wf;
    unsigned short* Wf_er1a = Wf + 1048576;
    unsigned short* Wf_er1b = Wf + 1638400;
    unsigned short* Wf_er2a = Wf + 1703936;
    unsigned short* Wf_er2b = Wf + 2293760;
    unsigned short* Wf_dr1a = Wf + 2359296;
    unsigned short* Wf_dr1b = Wf + 2949120;
    unsigned short* Wf_dr2a = Wf + 3014656;
    unsigned short* Wf_dr2b = Wf + 3604480;
    unsigned short* Wf_dt1  = Wf + 3670016;

    PermfArgs pa;
    const float* srcs[10] = {e_w2, e_r1a, e_r1b, e_r2a, e_r2b, d_r1a, d_r1b, d_r2a, d_r2b, dt1_w};
    int kws[10] = {4, 3, 1, 3, 1, 3, 1, 3, 1, 4};
    int sos[10] = {4096, 2304, 256, 2304, 256, 2304, 256, 2304, 256, 16};
    int sis[10] = {16, 9, 1, 9, 1, 9, 1, 9, 1, 4096};
    int shs[10] = {4, 3, 0, 3, 0, 3, 0, 3, 0, 4};
    int sws[10] = {1, 1, 0, 1, 0, 1, 0, 1, 0, 1};
    int cums[11] = {0, 1048576, 1638400, 1703936, 2293760, 2359296,
                    2949120, 3014656, 3604480, 3670016, 4718592};
    for (int k = 0; k < 10; ++k) {
        pa.src[k] = srcs[k]; pa.kw[k] = kws[k]; pa.so[k] = sos[k];
        pa.si[k] = sis[k]; pa.sh[k] = shs[k]; pa.sw[k] = sws[k];
        pa.cum[k] = cums[k];
    }
    pa.cum[10] = cums[10];

    permf_all_k<<<18432, 256, 0, stream>>>(pa, Wf);
    misc_prep_k<<<752, 256, 0, stream>>>(dt2_w, Wg, embed, EmbF, e_w1, WgC, Nrm);

    // ---- encoder ----
    conv1m_k<<<32 * 64, 256, 0, stream>>>(x, WgC, A0b);
    mconv2_k<<<32 * 16, 256, 0, stream>>>(A0b, Wf_ew2, L1);                      // h
    res3_k<<<32 * 32, 256, 0, stream>>>(L1, Wf_er1a, Wf_er1b, L0, nullptr, 0);   // r1 -> L0
    res3_k<<<32 * 32, 256, 0, stream>>>(L0, Wf_er2a, Wf_er2b, L1, A1f, 1);       // ze: bf16->L1, fp32->A1f

    // ---- VQ ----
    vqm_k<<<32 * 32, 256, 0, stream>>>(L1, A1f, EmbF, embed, Nrm, L1, Lpart);

    // ---- decoder ----
    res3_k<<<32 * 32, 256, 0, stream>>>(L1, Wf_dr1a, Wf_dr1b, L0, nullptr, 0);   // d1 -> L0
    res3_k<<<32 * 32, 256, 0, stream>>>(L0, Wf_dr2a, Wf_dr2b, L1, nullptr, 0);   // d2 -> L1
    mdeconv1_k<<<32 * 32, 256, 0, stream>>>(L1, Wf_dt1, dt1_b, A0b);
    mdec2a_k<<<2048, 256, 0, stream>>>(A0b, Wg, Y);
    dec2b_k<<<2048, 256, 0, stream>>>(Y, dt2_b, outp);
    lossfin_k<<<1, 256, 0, stream>>>(Lpart, outp);
}